// Round 1
// baseline (7616.961 us; speedup 1.0000x reference)
//
#include <hip/hip_runtime.h>
#include <cfloat>

// =====================================================================
// VQ-VAE forward, fp32 throughout (round 1: correctness + decent perf).
// Precision rationale: argmin over 8192 codes flips with bf16-level noise
// -> everything up to classes[] must be fp32. Decoder could be bf16 later.
//
// conv_transpose (transpose_kernel=False) => flipped kernel:
//   out[4i+r, 4j+u, o] = sum_c in[i,j,c] * w[3-r, 3-u, c, o]
// Encoder convs: SAME pad = (1,1), in[2y+dy-1, 2x+dx-1].
// =====================================================================

#define B_ 256

// ---------------- conv1: x(256,64,64,1) -> h1(256,32,32,32) NHWC ----------------
__global__ __launch_bounds__(256) void k_conv1(const float* __restrict__ x,
                                               const float* __restrict__ w,
                                               const float* __restrict__ bias,
                                               float* __restrict__ out) {
  int b = blockIdx.x >> 5;          // 8192 blocks: (b, y)
  int y = blockIdx.x & 31;
  int t = threadIdx.x;
  int c = t & 31;
  int xg = t >> 5;                  // 0..7, 4 x-positions each
  float acc[4] = {0.f, 0.f, 0.f, 0.f};
  for (int dy = 0; dy < 4; ++dy) {
    int iy = 2 * y + dy - 1;
    if (iy < 0 || iy >= 64) continue;
    const float* xrow = x + ((size_t)b * 64 + iy) * 64;
    for (int dx = 0; dx < 4; ++dx) {
      float wv = w[(dy * 4 + dx) * 32 + c];
#pragma unroll
      for (int i = 0; i < 4; ++i) {
        int ix = 8 * xg + 2 * i + dx - 1;
        float v = (ix >= 0 && ix < 64) ? xrow[ix] : 0.f;
        acc[i] = fmaf(v, wv, acc[i]);
      }
    }
  }
  float bv = bias[c];
  float* orow = out + (((size_t)b * 32 + y) * 32) * 32;
#pragma unroll
  for (int i = 0; i < 4; ++i) {
    float v = acc[i] + bv;
    orow[(4 * xg + i) * 32 + c] = v > 0.f ? v : 0.f;
  }
}

// ---------------- conv2: h1(256,32,32,32) -> h2(256,16,16,64) ----------------
// block = (b, ypair); weights staged per-dy slice in LDS (32KB);
// inputs via wave-uniform scalar loads (xg uniform per wave).
__global__ __launch_bounds__(256) void k_conv2(const float* __restrict__ h1,
                                               const float* __restrict__ w,
                                               const float* __restrict__ bias,
                                               const float* __restrict__ zeros,
                                               float* __restrict__ out) {
  __shared__ float ws[8192];        // one dy slice: [dx][ci][co] 4*32*64
  int b  = blockIdx.x >> 3;         // 2048 blocks
  int yp = blockIdx.x & 7;
  int t = threadIdx.x;
  int c = t & 63;
  int xg = __builtin_amdgcn_readfirstlane((int)(threadIdx.x >> 6)); // 0..3
  float acc[2][4] = {};
  for (int dy = 0; dy < 4; ++dy) {
    __syncthreads();
#pragma unroll
    for (int j = 0; j < 32; ++j) ws[t + j * 256] = w[dy * 8192 + t + j * 256];
    __syncthreads();
    for (int dx = 0; dx < 4; ++dx) {
      const float* hp[2][4];
#pragma unroll
      for (int yy = 0; yy < 2; ++yy) {
        int iy = 4 * yp + 2 * yy + dy - 1;
        bool oky = (iy >= 0 && iy < 32);
#pragma unroll
        for (int i = 0; i < 4; ++i) {
          int ix = 8 * xg + 2 * i + dx - 1;
          bool ok = oky && (ix >= 0 && ix < 32);
          hp[yy][i] = ok ? (h1 + (((size_t)b * 32 + iy) * 32 + ix) * 32) : zeros;
        }
      }
#pragma unroll 8
      for (int ci = 0; ci < 32; ++ci) {
        float wv = ws[(dx * 32 + ci) * 64 + c];
#pragma unroll
        for (int yy = 0; yy < 2; ++yy)
#pragma unroll
          for (int i = 0; i < 4; ++i)
            acc[yy][i] = fmaf(hp[yy][i][ci], wv, acc[yy][i]);
      }
    }
  }
  float bv = bias[c];
#pragma unroll
  for (int yy = 0; yy < 2; ++yy)
#pragma unroll
    for (int i = 0; i < 4; ++i) {
      float v = acc[yy][i] + bv;
      int yo = 2 * yp + yy, xo = 4 * xg + i;
      out[(((size_t)b * 16 + yo) * 16 + xo) * 64 + c] = v > 0.f ? v : 0.f;
    }
}

// ---------------- conv3: h2(256,16,16,64) -> h3(256,8,8,128) ----------------
__global__ __launch_bounds__(256) void k_conv3(const float* __restrict__ h2,
                                               const float* __restrict__ w,
                                               const float* __restrict__ bias,
                                               const float* __restrict__ zeros,
                                               float* __restrict__ out) {
  __shared__ float ws[8192];        // one (dy,dx) slice: [ci][co] 64*128
  int b  = blockIdx.x >> 2;         // 1024 blocks
  int yp = blockIdx.x & 3;
  int t = threadIdx.x;
  int c = t & 127;
  int xg = __builtin_amdgcn_readfirstlane((int)(threadIdx.x >> 7)); // 0..1
  float acc[2][4] = {};
  for (int dydx = 0; dydx < 16; ++dydx) {
    int dy = dydx >> 2, dx = dydx & 3;
    __syncthreads();
#pragma unroll
    for (int j = 0; j < 32; ++j) ws[t + j * 256] = w[dydx * 8192 + t + j * 256];
    __syncthreads();
    const float* hp[2][4];
#pragma unroll
    for (int yy = 0; yy < 2; ++yy) {
      int iy = 4 * yp + 2 * yy + dy - 1;
      bool oky = (iy >= 0 && iy < 16);
#pragma unroll
      for (int i = 0; i < 4; ++i) {
        int ix = 8 * xg + 2 * i + dx - 1;
        bool ok = oky && (ix >= 0 && ix < 16);
        hp[yy][i] = ok ? (h2 + (((size_t)b * 16 + iy) * 16 + ix) * 64) : zeros;
      }
    }
#pragma unroll 8
    for (int ci = 0; ci < 64; ++ci) {
      float wv = ws[ci * 128 + c];
#pragma unroll
      for (int yy = 0; yy < 2; ++yy)
#pragma unroll
        for (int i = 0; i < 4; ++i)
          acc[yy][i] = fmaf(hp[yy][i][ci], wv, acc[yy][i]);
    }
  }
  float bv = bias[c];
#pragma unroll
  for (int yy = 0; yy < 2; ++yy)
#pragma unroll
    for (int i = 0; i < 4; ++i) {
      float v = acc[yy][i] + bv;
      int yo = 2 * yp + yy, xo = 4 * xg + i;
      out[(((size_t)b * 8 + yo) * 8 + xo) * 128 + c] = v > 0.f ? v : 0.f;
    }
}

// ---------------- generic GEMM: C = A(MxK) * B(KxN), row-major ----------------
// 16m x 128n tile; A rows via wave-uniform s_loads; B tile in LDS.
// gridDim.z = S k-split slabs; S==1 -> fused bias(+relu) epilogue,
// S>1 -> writes partial C[s][m][n].
__global__ __launch_bounds__(256) void k_gemm(const float* __restrict__ A,
                                              const float* __restrict__ Bm,
                                              float* __restrict__ C,
                                              const float* __restrict__ bias,
                                              int M, int N, int K, int bmask) {
  __shared__ float Bs[32 * 128];    // 16KB
  int S = gridDim.z;
  int Kc = K / S;
  int k0base = blockIdx.z * Kc;
  int m0 = blockIdx.x * 16;
  int n0 = blockIdx.y * 128;
  int t = threadIdx.x;
  int n2 = (t & 63) * 2;
  int mg = __builtin_amdgcn_readfirstlane((int)(threadIdx.x >> 6)); // 0..3
  const float* pa[4];
#pragma unroll
  for (int r = 0; r < 4; ++r) pa[r] = A + (size_t)(m0 + mg * 4 + r) * K;
  float2 acc[4] = {};
  for (int k0 = k0base; k0 < k0base + Kc; k0 += 32) {
    __syncthreads();
#pragma unroll
    for (int j = 0; j < 16; ++j) {
      int idx = t + j * 256;
      int row = idx >> 7, col = idx & 127;
      Bs[idx] = Bm[(size_t)(k0 + row) * N + n0 + col];
    }
    __syncthreads();
#pragma unroll
    for (int kk = 0; kk < 32; ++kk) {
      float2 bv = *(const float2*)&Bs[kk * 128 + n2];
#pragma unroll
      for (int r = 0; r < 4; ++r) {
        float av = pa[r][k0 + kk];
        acc[r].x = fmaf(av, bv.x, acc[r].x);
        acc[r].y = fmaf(av, bv.y, acc[r].y);
      }
    }
  }
  if (S == 1) {
    float b0 = bias[(n0 + n2) & bmask];
    float b1 = bias[(n0 + n2 + 1) & bmask];
#pragma unroll
    for (int r = 0; r < 4; ++r) {
      int m = m0 + mg * 4 + r;
      float2 o = acc[r];
      o.x += b0; o.y += b1;
      o.x = o.x > 0.f ? o.x : 0.f;
      o.y = o.y > 0.f ? o.y : 0.f;
      *(float2*)&C[(size_t)m * N + n0 + n2] = o;
    }
  } else {
    float* Cp = C + (size_t)blockIdx.z * M * N;
#pragma unroll
    for (int r = 0; r < 4; ++r) {
      int m = m0 + mg * 4 + r;
      *(float2*)&Cp[(size_t)m * N + n0 + n2] = acc[r];
    }
  }
}

// sum k-split partials + bias + relu
__global__ __launch_bounds__(256) void k_sumrelu(const float* __restrict__ part,
                                                 const float* __restrict__ bias,
                                                 float* __restrict__ out,
                                                 int MN, int nmask, int S) {
  int idx = blockIdx.x * 256 + threadIdx.x;
  float s = 0.f;
  for (int z = 0; z < S; ++z) s += part[(size_t)z * MN + idx];
  s += bias[idx & nmask];
  out[idx] = s > 0.f ? s : 0.f;
}

// ---------------- VQ ----------------
__global__ __launch_bounds__(256) void k_norm2(const float* __restrict__ e,
                                               float* __restrict__ n2) {
  int k = blockIdx.x * 256 + threadIdx.x;
  const float4* p = (const float4*)(e + (size_t)k * 64);
  float s0 = 0, s1 = 0, s2 = 0, s3 = 0;
#pragma unroll
  for (int j = 0; j < 16; ++j) {
    float4 v = p[j];
    s0 = fmaf(v.x, v.x, s0); s1 = fmaf(v.y, v.y, s1);
    s2 = fmaf(v.z, v.z, s2); s3 = fmaf(v.w, v.w, s3);
  }
  n2[k] = (s0 + s1) + (s2 + s3);
}

// argmin_k ( ||e_k||^2 - 2 p.e_k ) for 16 rows per block; ties -> smallest k
__global__ __launch_bounds__(256) void k_vq(const float* __restrict__ pred,
                                            const float* __restrict__ embeds,
                                            const float* __restrict__ n2,
                                            int* __restrict__ classes) {
  __shared__ float ps[16 * 64];
  __shared__ float rd[256];
  __shared__ int   rk[256];
  int m0 = blockIdx.x * 16;
  int t = threadIdx.x;
#pragma unroll
  for (int j = 0; j < 4; ++j) ps[t + j * 256] = pred[(size_t)m0 * 64 + t + j * 256];
  __syncthreads();
  float bd[16]; int bk[16];
#pragma unroll
  for (int m = 0; m < 16; ++m) { bd[m] = FLT_MAX; bk[m] = 0; }
  for (int kb = 0; kb < 32; ++kb) {
    int k = kb * 256 + t;
    const float4* ep = (const float4*)(embeds + (size_t)k * 64);
    float4 ev[16];
#pragma unroll
    for (int j = 0; j < 16; ++j) ev[j] = ep[j];
    float nv = n2[k];
#pragma unroll
    for (int m = 0; m < 16; ++m) {
      const float4* pp = (const float4*)(ps + m * 64);
      float d0 = 0, d1 = 0, d2 = 0, d3 = 0;
#pragma unroll
      for (int j = 0; j < 16; ++j) {
        float4 p4 = pp[j]; float4 e4 = ev[j];
        d0 = fmaf(p4.x, e4.x, d0); d1 = fmaf(p4.y, e4.y, d1);
        d2 = fmaf(p4.z, e4.z, d2); d3 = fmaf(p4.w, e4.w, d3);
      }
      float dot = (d0 + d1) + (d2 + d3);
      float d = fmaf(-2.f, dot, nv);
      if (d < bd[m]) { bd[m] = d; bk[m] = k; }
    }
  }
  for (int m = 0; m < 16; ++m) {
    __syncthreads();
    rd[t] = bd[m]; rk[t] = bk[m];
    __syncthreads();
    for (int off = 128; off > 0; off >>= 1) {
      if (t < off) {
        float dv = rd[t + off]; int kv = rk[t + off];
        if (dv < rd[t] || (dv == rd[t] && kv < rk[t])) { rd[t] = dv; rk[t] = kv; }
      }
      __syncthreads();
    }
    if (t == 0) classes[m0 + m] = rk[0];
  }
}

__global__ __launch_bounds__(256) void k_gather(const int* __restrict__ classes,
                                                const float* __restrict__ embeds,
                                                float* __restrict__ out) {
  int idx = blockIdx.x * 256 + threadIdx.x;
  int m = idx >> 6, e = idx & 63;
  out[idx] = embeds[(size_t)classes[m] * 64 + e];
}

// ---------------- decoder weight permutes (spatial flip + GEMM layout) -------
// W1p[c][(r*4+u)*256+o] = dec_w1[3-r][3-u][c][o]   (512 x 4096)
__global__ __launch_bounds__(256) void k_permW1(const float* __restrict__ w,
                                                float* __restrict__ wp) {
  int idx = blockIdx.x * 256 + threadIdx.x; // 2,097,152
  int cc = idx >> 12, n = idx & 4095;
  int ru = n >> 8, o = n & 255, r = ru >> 2, u = ru & 3;
  wp[idx] = w[((size_t)((3 - r) * 4 + (3 - u)) * 512 + cc) * 256 + o];
}
// W2p[c][(r*4+u)*128+o] = dec_w2[3-r][3-u][c][o]   (256 x 2048)
__global__ __launch_bounds__(256) void k_permW2(const float* __restrict__ w,
                                                float* __restrict__ wp) {
  int idx = blockIdx.x * 256 + threadIdx.x; // 524,288
  int cc = idx >> 11, n = idx & 2047;
  int ru = n >> 7, o = n & 127, r = ru >> 2, u = ru & 3;
  wp[idx] = w[((size_t)((3 - r) * 4 + (3 - u)) * 256 + cc) * 128 + o];
}

// ---------------- dec3: d2buf(permuted) -> out(256,64,64), +bias, no relu ----
// d2buf row m2=(b,i,j) cols (r*4+u)*128+o ; out[b,4y+R,4x+U] uses w3[3-R][3-U][c]
__global__ __launch_bounds__(256) void k_dec3(const float* __restrict__ d2buf,
                                              const float* __restrict__ w3,
                                              const float* __restrict__ b3,
                                              float* __restrict__ out) {
  __shared__ float sx[16 * 129];
  __shared__ float wT[128 * 16];
  int b = blockIdx.x >> 4;          // 4096 blocks: (b, y_in)
  int y = blockIdx.x & 15;
  int t = threadIdx.x;
#pragma unroll
  for (int j = 0; j < 8; ++j) {
    int idx = t + j * 256;          // 2048
    int xx = idx >> 7, c = idx & 127;
    size_t m2 = ((size_t)b * 4 + (y >> 2)) * 4 + (xx >> 2);
    sx[xx * 129 + c] = d2buf[m2 * 2048 + ((y & 3) * 4 + (xx & 3)) * 128 + c];
  }
#pragma unroll
  for (int j = 0; j < 8; ++j) {
    int idx = t + j * 256;
    int c = idx >> 4, ru = idx & 15;
    int R = ru >> 2, U = ru & 3;
    wT[c * 16 + ru] = w3[((3 - R) * 4 + (3 - U)) * 128 + c];
  }
  __syncthreads();
  int xx = t >> 4, ru = t & 15;
  float a0 = 0, a1 = 0, a2 = 0, a3 = 0;
#pragma unroll 8
  for (int c = 0; c < 128; c += 4) {
    a0 = fmaf(sx[xx * 129 + c + 0], wT[(c + 0) * 16 + ru], a0);
    a1 = fmaf(sx[xx * 129 + c + 1], wT[(c + 1) * 16 + ru], a1);
    a2 = fmaf(sx[xx * 129 + c + 2], wT[(c + 2) * 16 + ru], a2);
    a3 = fmaf(sx[xx * 129 + c + 3], wT[(c + 3) * 16 + ru], a3);
  }
  float acc = (a0 + a1) + (a2 + a3) + b3[0];
  int R = ru >> 2, U = ru & 3;
  out[((size_t)b * 64 + 4 * y + R) * 64 + 4 * xx + U] = acc;
}

// =====================================================================
extern "C" void kernel_launch(void* const* d_in, const int* in_sizes, int n_in,
                              void* d_out, int out_size, void* d_ws, size_t ws_size,
                              hipStream_t stream) {
  const float* x        = (const float*)d_in[0];
  const float* enc_w1   = (const float*)d_in[1];
  const float* enc_b1   = (const float*)d_in[2];
  const float* enc_w2   = (const float*)d_in[3];
  const float* enc_b2   = (const float*)d_in[4];
  const float* enc_w3   = (const float*)d_in[5];
  const float* enc_b3   = (const float*)d_in[6];
  const float* fc_w     = (const float*)d_in[7];
  const float* fc_b     = (const float*)d_in[8];
  const float* ffc_w    = (const float*)d_in[9];
  const float* ffc_b    = (const float*)d_in[10];
  const float* embeds   = (const float*)d_in[11];
  const float* dec_fc_w = (const float*)d_in[12];
  const float* dec_fc_b = (const float*)d_in[13];
  const float* dec_w1   = (const float*)d_in[14];
  const float* dec_b1   = (const float*)d_in[15];
  const float* dec_w2   = (const float*)d_in[16];
  const float* dec_b2   = (const float*)d_in[17];
  const float* dec_w3   = (const float*)d_in[18];
  const float* dec_b3   = (const float*)d_in[19];
  float* outp = (float*)d_out;

  // workspace layout (bytes, 256-aligned); d2buf aliases h1, dfcpart aliases fcpart
  char* ws = (char*)d_ws;
  size_t off = 0;
  auto alloc = [&](size_t bytes) { size_t r = off; off = (off + bytes + 255) & ~(size_t)255; return r; };
  float* h1        = (float*)(ws + alloc(8388608ull * 4));   // 256*32*32*32
  float* h2        = (float*)(ws + alloc(4194304ull * 4));   // 256*16*16*64
  float* h3        = (float*)(ws + alloc(2097152ull * 4));   // 256*8*8*128
  float* fcpart    = (float*)(ws + alloc(8ull * 131072 * 4));
  float* hfc       = (float*)(ws + alloc(131072ull * 4));
  float* pred      = (float*)(ws + alloc(524288ull * 4));    // 256*2048
  float* n2buf     = (float*)(ws + alloc(8192ull * 4));
  int*   classes   = (int*)  (ws + alloc(8192ull * 4));
  float* collected = (float*)(ws + alloc(524288ull * 4));
  float* hdfc      = (float*)(ws + alloc(131072ull * 4));
  float* W1p       = (float*)(ws + alloc(2097152ull * 4));   // 512*4096
  float* d1out     = (float*)(ws + alloc(1048576ull * 4));   // 256*4096
  float* W2p       = (float*)(ws + alloc(524288ull * 4));    // 256*2048
  float* zeros     = (float*)(ws + alloc(1024));
  float* d2buf     = h1;        // 4096*2048, h1 dead after conv2
  float* dfcpart   = fcpart;    // fc epilogue done before dec_fc gemm
  (void)ws_size; (void)in_sizes; (void)n_in; (void)out_size;

  hipMemsetAsync(zeros, 0, 1024, stream);

  k_conv1<<<8192, 256, 0, stream>>>(x, enc_w1, enc_b1, h1);
  k_conv2<<<2048, 256, 0, stream>>>(h1, enc_w2, enc_b2, zeros, h2);
  k_conv3<<<1024, 256, 0, stream>>>(h2, enc_w3, enc_b3, zeros, h3);

  // fc: (256x8192)@(8192x512), k-split 8
  k_gemm<<<dim3(16, 4, 8), 256, 0, stream>>>(h3, fc_w, fcpart, zeros, 256, 512, 8192, 0);
  k_sumrelu<<<512, 256, 0, stream>>>(fcpart, fc_b, hfc, 131072, 511, 8);
  // ffc: (256x512)@(512x2048) + bias + relu
  k_gemm<<<dim3(16, 16, 1), 256, 0, stream>>>(hfc, ffc_w, pred, ffc_b, 256, 2048, 512, 2047);

  k_norm2<<<32, 256, 0, stream>>>(embeds, n2buf);
  k_vq<<<512, 256, 0, stream>>>(pred, embeds, n2buf, classes);
  k_gather<<<2048, 256, 0, stream>>>(classes, embeds, collected);

  // dec_fc: (256x2048)@(2048x512), k-split 8
  k_gemm<<<dim3(16, 4, 8), 256, 0, stream>>>(collected, dec_fc_w, dfcpart, zeros, 256, 512, 2048, 0);
  k_sumrelu<<<512, 256, 0, stream>>>(dfcpart, dec_fc_b, hdfc, 131072, 511, 8);

  k_permW1<<<8192, 256, 0, stream>>>(dec_w1, W1p);
  k_permW2<<<2048, 256, 0, stream>>>(dec_w2, W2p);
  // dec1: (256x512)@(512x4096) -> d1out rows (b) cols (i*4+j)*256+c == (4096x256) row-major
  k_gemm<<<dim3(16, 32, 1), 256, 0, stream>>>(hdfc, W1p, d1out, dec_b1, 256, 4096, 512, 255);
  // dec2: (4096x256)@(256x2048) -> d2buf rows (b,i,j) cols (r*4+u)*128+o
  k_gemm<<<dim3(256, 16, 1), 256, 0, stream>>>(d1out, W2p, d2buf, dec_b2, 4096, 2048, 256, 127);
  // dec3 -> final output (no relu)
  k_dec3<<<4096, 256, 0, stream>>>(d2buf, dec_w3, dec_b3, outp);
}

// Round 3
// 782.881 us; speedup vs baseline: 9.7294x; 9.7294x over previous
//
#include <hip/hip_runtime.h>
#include <cfloat>

// =====================================================================
// VQ-VAE forward, fp32 throughout.
// R3: fix R2's row-count bug — pred has B*L = 8192 rows (not 4096).
// k_vq2 grid 128x8, pbd/pbk stride 8192, k_vqfinal 32 blocks.
//
// conv_transpose (transpose_kernel=False) => flipped kernel:
//   out[4i+r, 4j+u, o] = sum_c in[i,j,c] * w[3-r, 3-u, c, o]
// Encoder convs: SAME pad = (1,1), in[2y+dy-1, 2x+dx-1].
// =====================================================================

// ---------------- conv1: x(256,64,64,1) -> h1(256,32,32,32) NHWC ----------------
__global__ __launch_bounds__(256) void k_conv1(const float* __restrict__ x,
                                               const float* __restrict__ w,
                                               const float* __restrict__ bias,
                                               float* __restrict__ out) {
  int b = blockIdx.x >> 5;          // 8192 blocks: (b, y)
  int y = blockIdx.x & 31;
  int t = threadIdx.x;
  int c = t & 31;
  int xg = t >> 5;                  // 0..7, 4 x-positions each
  float acc[4] = {0.f, 0.f, 0.f, 0.f};
  for (int dy = 0; dy < 4; ++dy) {
    int iy = 2 * y + dy - 1;
    if (iy < 0 || iy >= 64) continue;
    const float* xrow = x + ((size_t)b * 64 + iy) * 64;
    for (int dx = 0; dx < 4; ++dx) {
      float wv = w[(dy * 4 + dx) * 32 + c];
#pragma unroll
      for (int i = 0; i < 4; ++i) {
        int ix = 8 * xg + 2 * i + dx - 1;
        float v = (ix >= 0 && ix < 64) ? xrow[ix] : 0.f;
        acc[i] = fmaf(v, wv, acc[i]);
      }
    }
  }
  float bv = bias[c];
  float* orow = out + (((size_t)b * 32 + y) * 32) * 32;
#pragma unroll
  for (int i = 0; i < 4; ++i) {
    float v = acc[i] + bv;
    orow[(4 * xg + i) * 32 + c] = v > 0.f ? v : 0.f;
  }
}

// ---------------- conv2: h1(256,32,32,32) -> h2(256,16,16,64) ----------------
__global__ __launch_bounds__(256) void k_conv2(const float* __restrict__ h1,
                                               const float* __restrict__ w,
                                               const float* __restrict__ bias,
                                               const float* __restrict__ zeros,
                                               float* __restrict__ out) {
  __shared__ float ws[8192];        // one dy slice: [dx][ci][co] 4*32*64
  int b  = blockIdx.x >> 3;         // 2048 blocks
  int yp = blockIdx.x & 7;
  int t = threadIdx.x;
  int c = t & 63;
  int xg = __builtin_amdgcn_readfirstlane((int)(threadIdx.x >> 6)); // 0..3
  float acc[2][4] = {};
  for (int dy = 0; dy < 4; ++dy) {
    __syncthreads();
#pragma unroll
    for (int j = 0; j < 32; ++j) ws[t + j * 256] = w[dy * 8192 + t + j * 256];
    __syncthreads();
    for (int dx = 0; dx < 4; ++dx) {
      const float* hp[2][4];
#pragma unroll
      for (int yy = 0; yy < 2; ++yy) {
        int iy = 4 * yp + 2 * yy + dy - 1;
        bool oky = (iy >= 0 && iy < 32);
#pragma unroll
        for (int i = 0; i < 4; ++i) {
          int ix = 8 * xg + 2 * i + dx - 1;
          bool ok = oky && (ix >= 0 && ix < 32);
          hp[yy][i] = ok ? (h1 + (((size_t)b * 32 + iy) * 32 + ix) * 32) : zeros;
        }
      }
#pragma unroll 8
      for (int ci = 0; ci < 32; ++ci) {
        float wv = ws[(dx * 32 + ci) * 64 + c];
#pragma unroll
        for (int yy = 0; yy < 2; ++yy)
#pragma unroll
          for (int i = 0; i < 4; ++i)
            acc[yy][i] = fmaf(hp[yy][i][ci], wv, acc[yy][i]);
      }
    }
  }
  float bv = bias[c];
#pragma unroll
  for (int yy = 0; yy < 2; ++yy)
#pragma unroll
    for (int i = 0; i < 4; ++i) {
      float v = acc[yy][i] + bv;
      int yo = 2 * yp + yy, xo = 4 * xg + i;
      out[(((size_t)b * 16 + yo) * 16 + xo) * 64 + c] = v > 0.f ? v : 0.f;
    }
}

// ---------------- conv3: h2(256,16,16,64) -> h3(256,8,8,128) ----------------
__global__ __launch_bounds__(256) void k_conv3(const float* __restrict__ h2,
                                               const float* __restrict__ w,
                                               const float* __restrict__ bias,
                                               const float* __restrict__ zeros,
                                               float* __restrict__ out) {
  __shared__ float ws[8192];        // one (dy,dx) slice: [ci][co] 64*128
  int b  = blockIdx.x >> 2;         // 1024 blocks
  int yp = blockIdx.x & 3;
  int t = threadIdx.x;
  int c = t & 127;
  int xg = __builtin_amdgcn_readfirstlane((int)(threadIdx.x >> 7)); // 0..1
  float acc[2][4] = {};
  for (int dydx = 0; dydx < 16; ++dydx) {
    int dy = dydx >> 2, dx = dydx & 3;
    __syncthreads();
#pragma unroll
    for (int j = 0; j < 32; ++j) ws[t + j * 256] = w[dydx * 8192 + t + j * 256];
    __syncthreads();
    const float* hp[2][4];
#pragma unroll
    for (int yy = 0; yy < 2; ++yy) {
      int iy = 4 * yp + 2 * yy + dy - 1;
      bool oky = (iy >= 0 && iy < 16);
#pragma unroll
      for (int i = 0; i < 4; ++i) {
        int ix = 8 * xg + 2 * i + dx - 1;
        bool ok = oky && (ix >= 0 && ix < 16);
        hp[yy][i] = ok ? (h2 + (((size_t)b * 16 + iy) * 16 + ix) * 64) : zeros;
      }
    }
#pragma unroll 8
    for (int ci = 0; ci < 64; ++ci) {
      float wv = ws[ci * 128 + c];
#pragma unroll
      for (int yy = 0; yy < 2; ++yy)
#pragma unroll
        for (int i = 0; i < 4; ++i)
          acc[yy][i] = fmaf(hp[yy][i][ci], wv, acc[yy][i]);
    }
  }
  float bv = bias[c];
#pragma unroll
  for (int yy = 0; yy < 2; ++yy)
#pragma unroll
    for (int i = 0; i < 4; ++i) {
      float v = acc[yy][i] + bv;
      int yo = 2 * yp + yy, xo = 4 * xg + i;
      out[(((size_t)b * 8 + yo) * 8 + xo) * 128 + c] = v > 0.f ? v : 0.f;
    }
}

// ---------------- generic GEMM: C = A(MxK) * B(KxN), row-major ----------------
__global__ __launch_bounds__(256) void k_gemm(const float* __restrict__ A,
                                              const float* __restrict__ Bm,
                                              float* __restrict__ C,
                                              const float* __restrict__ bias,
                                              int M, int N, int K, int bmask) {
  __shared__ float Bs[32 * 128];    // 16KB
  int S = gridDim.z;
  int Kc = K / S;
  int k0base = blockIdx.z * Kc;
  int m0 = blockIdx.x * 16;
  int n0 = blockIdx.y * 128;
  int t = threadIdx.x;
  int n2 = (t & 63) * 2;
  int mg = __builtin_amdgcn_readfirstlane((int)(threadIdx.x >> 6)); // 0..3
  const float* pa[4];
#pragma unroll
  for (int r = 0; r < 4; ++r) pa[r] = A + (size_t)(m0 + mg * 4 + r) * K;
  float2 acc[4] = {};
  for (int k0 = k0base; k0 < k0base + Kc; k0 += 32) {
    __syncthreads();
#pragma unroll
    for (int j = 0; j < 16; ++j) {
      int idx = t + j * 256;
      int row = idx >> 7, col = idx & 127;
      Bs[idx] = Bm[(size_t)(k0 + row) * N + n0 + col];
    }
    __syncthreads();
#pragma unroll
    for (int kk = 0; kk < 32; ++kk) {
      float2 bv = *(const float2*)&Bs[kk * 128 + n2];
#pragma unroll
      for (int r = 0; r < 4; ++r) {
        float av = pa[r][k0 + kk];
        acc[r].x = fmaf(av, bv.x, acc[r].x);
        acc[r].y = fmaf(av, bv.y, acc[r].y);
      }
    }
  }
  if (S == 1) {
    float b0 = bias[(n0 + n2) & bmask];
    float b1 = bias[(n0 + n2 + 1) & bmask];
#pragma unroll
    for (int r = 0; r < 4; ++r) {
      int m = m0 + mg * 4 + r;
      float2 o = acc[r];
      o.x += b0; o.y += b1;
      o.x = o.x > 0.f ? o.x : 0.f;
      o.y = o.y > 0.f ? o.y : 0.f;
      *(float2*)&C[(size_t)m * N + n0 + n2] = o;
    }
  } else {
    float* Cp = C + (size_t)blockIdx.z * M * N;
#pragma unroll
    for (int r = 0; r < 4; ++r) {
      int m = m0 + mg * 4 + r;
      *(float2*)&Cp[(size_t)m * N + n0 + n2] = acc[r];
    }
  }
}

// sum k-split partials + bias + relu
__global__ __launch_bounds__(256) void k_sumrelu(const float* __restrict__ part,
                                                 const float* __restrict__ bias,
                                                 float* __restrict__ out,
                                                 int MN, int nmask, int S) {
  int idx = blockIdx.x * 256 + threadIdx.x;
  float s = 0.f;
  for (int z = 0; z < S; ++z) s += part[(size_t)z * MN + idx];
  s += bias[idx & nmask];
  out[idx] = s > 0.f ? s : 0.f;
}

// ---------------- VQ ----------------
__global__ __launch_bounds__(256) void k_norm2(const float* __restrict__ e,
                                               float* __restrict__ n2) {
  int k = blockIdx.x * 256 + threadIdx.x;
  const float4* p = (const float4*)(e + (size_t)k * 64);
  float s0 = 0, s1 = 0, s2 = 0, s3 = 0;
#pragma unroll
  for (int j = 0; j < 16; ++j) {
    float4 v = p[j];
    s0 = fmaf(v.x, v.x, s0); s1 = fmaf(v.y, v.y, s1);
    s2 = fmaf(v.z, v.z, s2); s3 = fmaf(v.w, v.w, s3);
  }
  n2[k] = (s0 + s1) + (s2 + s3);
}

// k_vq2: LDS-tiled distance GEMM + fused argmin.
// grid (128 m-tiles, 8 k-splits), block 256. pred has 8192 rows (B*L).
// Block: pred tile 64x64, embeds tile 128x64 (k-range 1024 = 8 tiles).
// Thread: mg=t>>5 owns 8 m rows, kg=t&31 owns 4 k cols (k = kg+32c).
// LDS strides 66 -> staged writes and compute reads both <=2-way bank
// aliased = conflict-free. pred reads are half-wave broadcast.
__global__ __launch_bounds__(256) void k_vq2(const float* __restrict__ pred,
                                             const float* __restrict__ embeds,
                                             const float* __restrict__ n2,
                                             float* __restrict__ pbd,
                                             int* __restrict__ pbk) {
  __shared__ float ps[64 * 66];     // 16.9 KB
  __shared__ float es[128 * 66];    // 33.8 KB
  __shared__ float rdb[256];
  __shared__ int   rkb[256];
  int m0 = blockIdx.x * 64;
  int z  = blockIdx.y;
  int t = threadIdx.x;
  int mg = t >> 5, kg = t & 31;
  // stage pred tile (coalesced float2; lanes cover a row contiguously)
#pragma unroll
  for (int p = 0; p < 8; ++p) {
    int m = p * 8 + mg;
    float2 v = *(const float2*)&pred[(size_t)(m0 + m) * 64 + kg * 2];
    *(float2*)&ps[m * 66 + kg * 2] = v;
  }
  float bd[8]; int bk[8];
#pragma unroll
  for (int r = 0; r < 8; ++r) { bd[r] = FLT_MAX; bk[r] = 0; }
  for (int kt = 0; kt < 1024; kt += 128) {
    int kt0 = z * 1024 + kt;
    __syncthreads();
#pragma unroll
    for (int p = 0; p < 16; ++p) {
      int k = p * 8 + mg;
      float2 v = *(const float2*)&embeds[(size_t)(kt0 + k) * 64 + kg * 2];
      *(float2*)&es[k * 66 + kg * 2] = v;
    }
    __syncthreads();
    float acc[8][4] = {};
#pragma unroll 4
    for (int e = 0; e < 64; e += 2) {
      float2 pv[8], ev[4];
#pragma unroll
      for (int r = 0; r < 8; ++r) pv[r] = *(const float2*)&ps[(mg * 8 + r) * 66 + e];
#pragma unroll
      for (int c = 0; c < 4; ++c) ev[c] = *(const float2*)&es[(kg + 32 * c) * 66 + e];
#pragma unroll
      for (int r = 0; r < 8; ++r)
#pragma unroll
        for (int c = 0; c < 4; ++c) {
          acc[r][c] = fmaf(pv[r].x, ev[c].x, acc[r][c]);
          acc[r][c] = fmaf(pv[r].y, ev[c].y, acc[r][c]);
        }
    }
#pragma unroll
    for (int c = 0; c < 4; ++c) {
      int k = kt0 + kg + 32 * c;
      float nv = n2[k];
#pragma unroll
      for (int r = 0; r < 8; ++r) {
        float d = fmaf(-2.f, acc[r][c], nv);
        if (d < bd[r] || (d == bd[r] && k < bk[r])) { bd[r] = d; bk[r] = k; }
      }
    }
  }
  // reduce over the 32 kg-threads of each mg group; lexicographic (d,k)
  for (int r = 0; r < 8; ++r) {
    __syncthreads();
    rdb[t] = bd[r]; rkb[t] = bk[r];
    __syncthreads();
    for (int off = 16; off > 0; off >>= 1) {
      if (kg < off) {
        float dv = rdb[t + off]; int kv = rkb[t + off];
        if (dv < rdb[t] || (dv == rdb[t] && kv < rkb[t])) { rdb[t] = dv; rkb[t] = kv; }
      }
      __syncthreads();
    }
    if (kg == 0) {
      int m = m0 + mg * 8 + r;
      pbd[(size_t)z * 8192 + m] = rdb[t];
      pbk[(size_t)z * 8192 + m] = rkb[t];
    }
  }
}

// reduce the 8 k-split candidates per row -> classes (8192 rows)
__global__ __launch_bounds__(256) void k_vqfinal(const float* __restrict__ pbd,
                                                 const int* __restrict__ pbk,
                                                 int* __restrict__ classes) {
  int m = blockIdx.x * 256 + threadIdx.x;   // 32 blocks
  float bd = pbd[m]; int bk = pbk[m];
#pragma unroll
  for (int z = 1; z < 8; ++z) {
    float d = pbd[(size_t)z * 8192 + m]; int k = pbk[(size_t)z * 8192 + m];
    if (d < bd || (d == bd && k < bk)) { bd = d; bk = k; }
  }
  classes[m] = bk;
}

__global__ __launch_bounds__(256) void k_gather(const int* __restrict__ classes,
                                                const float* __restrict__ embeds,
                                                float* __restrict__ out) {
  int idx = blockIdx.x * 256 + threadIdx.x;
  int m = idx >> 6, e = idx & 63;
  out[idx] = embeds[(size_t)classes[m] * 64 + e];
}

// ---------------- decoder weight permutes (spatial flip + GEMM layout) -------
__global__ __launch_bounds__(256) void k_permW1(const float* __restrict__ w,
                                                float* __restrict__ wp) {
  int idx = blockIdx.x * 256 + threadIdx.x; // 2,097,152
  int cc = idx >> 12, n = idx & 4095;
  int ru = n >> 8, o = n & 255, r = ru >> 2, u = ru & 3;
  wp[idx] = w[((size_t)((3 - r) * 4 + (3 - u)) * 512 + cc) * 256 + o];
}
__global__ __launch_bounds__(256) void k_permW2(const float* __restrict__ w,
                                                float* __restrict__ wp) {
  int idx = blockIdx.x * 256 + threadIdx.x; // 524,288
  int cc = idx >> 11, n = idx & 2047;
  int ru = n >> 7, o = n & 127, r = ru >> 2, u = ru & 3;
  wp[idx] = w[((size_t)((3 - r) * 4 + (3 - u)) * 256 + cc) * 128 + o];
}

// ---------------- dec3: d2buf(permuted) -> out(256,64,64), +bias, no relu ----
__global__ __launch_bounds__(256) void k_dec3(const float* __restrict__ d2buf,
                                              const float* __restrict__ w3,
                                              const float* __restrict__ b3,
                                              float* __restrict__ out) {
  __shared__ float sx[16 * 129];
  __shared__ float wT[128 * 16];
  int b = blockIdx.x >> 4;          // 4096 blocks: (b, y_in)
  int y = blockIdx.x & 15;
  int t = threadIdx.x;
#pragma unroll
  for (int j = 0; j < 8; ++j) {
    int idx = t + j * 256;          // 2048
    int xx = idx >> 7, c = idx & 127;
    size_t m2 = ((size_t)b * 4 + (y >> 2)) * 4 + (xx >> 2);
    sx[xx * 129 + c] = d2buf[m2 * 2048 + ((y & 3) * 4 + (xx & 3)) * 128 + c];
  }
#pragma unroll
  for (int j = 0; j < 8; ++j) {
    int idx = t + j * 256;
    int c = idx >> 4, ru = idx & 15;
    int R = ru >> 2, U = ru & 3;
    wT[c * 16 + ru] = w3[((3 - R) * 4 + (3 - U)) * 128 + c];
  }
  __syncthreads();
  int xx = t >> 4, ru = t & 15;
  float a0 = 0, a1 = 0, a2 = 0, a3 = 0;
#pragma unroll 8
  for (int c = 0; c < 128; c += 4) {
    a0 = fmaf(sx[xx * 129 + c + 0], wT[(c + 0) * 16 + ru], a0);
    a1 = fmaf(sx[xx * 129 + c + 1], wT[(c + 1) * 16 + ru], a1);
    a2 = fmaf(sx[xx * 129 + c + 2], wT[(c + 2) * 16 + ru], a2);
    a3 = fmaf(sx[xx * 129 + c + 3], wT[(c + 3) * 16 + ru], a3);
  }
  float acc = (a0 + a1) + (a2 + a3) + b3[0];
  int R = ru >> 2, U = ru & 3;
  out[((size_t)b * 64 + 4 * y + R) * 64 + 4 * xx + U] = acc;
}

// =====================================================================
extern "C" void kernel_launch(void* const* d_in, const int* in_sizes, int n_in,
                              void* d_out, int out_size, void* d_ws, size_t ws_size,
                              hipStream_t stream) {
  const float* x        = (const float*)d_in[0];
  const float* enc_w1   = (const float*)d_in[1];
  const float* enc_b1   = (const float*)d_in[2];
  const float* enc_w2   = (const float*)d_in[3];
  const float* enc_b2   = (const float*)d_in[4];
  const float* enc_w3   = (const float*)d_in[5];
  const float* enc_b3   = (const float*)d_in[6];
  const float* fc_w     = (const float*)d_in[7];
  const float* fc_b     = (const float*)d_in[8];
  const float* ffc_w    = (const float*)d_in[9];
  const float* ffc_b    = (const float*)d_in[10];
  const float* embeds   = (const float*)d_in[11];
  const float* dec_fc_w = (const float*)d_in[12];
  const float* dec_fc_b = (const float*)d_in[13];
  const float* dec_w1   = (const float*)d_in[14];
  const float* dec_b1   = (const float*)d_in[15];
  const float* dec_w2   = (const float*)d_in[16];
  const float* dec_b2   = (const float*)d_in[17];
  const float* dec_w3   = (const float*)d_in[18];
  const float* dec_b3   = (const float*)d_in[19];
  float* outp = (float*)d_out;

  char* ws = (char*)d_ws;
  size_t off = 0;
  auto alloc = [&](size_t bytes) { size_t r = off; off = (off + bytes + 255) & ~(size_t)255; return r; };
  float* h1        = (float*)(ws + alloc(8388608ull * 4));   // 256*32*32*32
  float* h2        = (float*)(ws + alloc(4194304ull * 4));   // 256*16*16*64
  float* h3        = (float*)(ws + alloc(2097152ull * 4));   // 256*8*8*128
  float* fcpart    = (float*)(ws + alloc(8ull * 131072 * 4));
  float* hfc       = (float*)(ws + alloc(131072ull * 4));
  float* pred      = (float*)(ws + alloc(524288ull * 4));    // 8192 x 64
  float* n2buf     = (float*)(ws + alloc(8192ull * 4));
  int*   classes   = (int*)  (ws + alloc(8192ull * 4));
  float* collected = (float*)(ws + alloc(524288ull * 4));
  float* hdfc      = (float*)(ws + alloc(131072ull * 4));
  float* W1p       = (float*)(ws + alloc(2097152ull * 4));   // 512*4096
  float* d1out     = (float*)(ws + alloc(1048576ull * 4));   // 256*4096
  float* W2p       = (float*)(ws + alloc(524288ull * 4));    // 256*2048
  float* pbd       = (float*)(ws + alloc(65536ull * 4));     // 8*8192
  int*   pbk       = (int*)  (ws + alloc(65536ull * 4));
  float* zeros     = (float*)(ws + alloc(1024));
  float* d2buf     = h1;        // 4096*2048, h1 dead after conv2
  float* dfcpart   = fcpart;    // fc epilogue done before dec_fc gemm
  (void)ws_size; (void)in_sizes; (void)n_in; (void)out_size;

  hipMemsetAsync(zeros, 0, 1024, stream);

  k_conv1<<<8192, 256, 0, stream>>>(x, enc_w1, enc_b1, h1);
  k_conv2<<<2048, 256, 0, stream>>>(h1, enc_w2, enc_b2, zeros, h2);
  k_conv3<<<1024, 256, 0, stream>>>(h2, enc_w3, enc_b3, zeros, h3);

  // fc: (256x8192)@(8192x512), k-split 8
  k_gemm<<<dim3(16, 4, 8), 256, 0, stream>>>(h3, fc_w, fcpart, zeros, 256, 512, 8192, 0);
  k_sumrelu<<<512, 256, 0, stream>>>(fcpart, fc_b, hfc, 131072, 511, 8);
  // ffc: (256x512)@(512x2048) + bias + relu
  k_gemm<<<dim3(16, 16, 1), 256, 0, stream>>>(hfc, ffc_w, pred, ffc_b, 256, 2048, 512, 2047);

  k_norm2<<<32, 256, 0, stream>>>(embeds, n2buf);
  k_vq2<<<dim3(128, 8), 256, 0, stream>>>(pred, embeds, n2buf, pbd, pbk);
  k_vqfinal<<<32, 256, 0, stream>>>(pbd, pbk, classes);
  k_gather<<<2048, 256, 0, stream>>>(classes, embeds, collected);

  // dec_fc: (256x2048)@(2048x512), k-split 8
  k_gemm<<<dim3(16, 4, 8), 256, 0, stream>>>(collected, dec_fc_w, dfcpart, zeros, 256, 512, 2048, 0);
  k_sumrelu<<<512, 256, 0, stream>>>(dfcpart, dec_fc_b, hdfc, 131072, 511, 8);

  k_permW1<<<8192, 256, 0, stream>>>(dec_w1, W1p);
  k_permW2<<<2048, 256, 0, stream>>>(dec_w2, W2p);
  // dec1: (256x512)@(512x4096) -> d1out rows (b) cols (i*4+j)*256+c
  k_gemm<<<dim3(16, 32, 1), 256, 0, stream>>>(hdfc, W1p, d1out, dec_b1, 256, 4096, 512, 255);
  // dec2: (4096x256)@(256x2048) -> d2buf rows (b,i,j) cols (r*4+u)*128+o
  k_gemm<<<dim3(256, 16, 1), 256, 0, stream>>>(d1out, W2p, d2buf, dec_b2, 4096, 2048, 256, 127);
  // dec3 -> final output (no relu)
  k_dec3<<<4096, 256, 0, stream>>>(d2buf, dec_w3, dec_b3, outp);
}

// Round 4
// 752.344 us; speedup vs baseline: 10.1243x; 1.0406x over previous
//
#include <hip/hip_runtime.h>
#include <cfloat>

// =====================================================================
// VQ-VAE forward.
// R4: VQ via bf16 MFMA with 3-term split (hi/mid/lo, 6 products) ->
// fp32-accurate distances at MFMA rate. Everything else unchanged fp32.
//
// conv_transpose (transpose_kernel=False) => flipped kernel:
//   out[4i+r, 4j+u, o] = sum_c in[i,j,c] * w[3-r, 3-u, c, o]
// Encoder convs: SAME pad = (1,1), in[2y+dy-1, 2x+dx-1].
// =====================================================================

typedef short bf16x8 __attribute__((ext_vector_type(8)));
typedef float f32x4 __attribute__((ext_vector_type(4)));
#define MFMA16(a, b, c) __builtin_amdgcn_mfma_f32_16x16x32_bf16(a, b, c, 0, 0, 0)

__device__ inline unsigned short f2bf(float x) {  // RNE, inputs finite
  unsigned u = __float_as_uint(x);
  u += 0x7fffu + ((u >> 16) & 1u);
  return (unsigned short)(u >> 16);
}
__device__ inline float bf2f(unsigned short h) {
  return __uint_as_float(((unsigned)h) << 16);
}

// ---------------- conv1: x(256,64,64,1) -> h1(256,32,32,32) NHWC ----------------
__global__ __launch_bounds__(256) void k_conv1(const float* __restrict__ x,
                                               const float* __restrict__ w,
                                               const float* __restrict__ bias,
                                               float* __restrict__ out) {
  int b = blockIdx.x >> 5;          // 8192 blocks: (b, y)
  int y = blockIdx.x & 31;
  int t = threadIdx.x;
  int c = t & 31;
  int xg = t >> 5;                  // 0..7, 4 x-positions each
  float acc[4] = {0.f, 0.f, 0.f, 0.f};
  for (int dy = 0; dy < 4; ++dy) {
    int iy = 2 * y + dy - 1;
    if (iy < 0 || iy >= 64) continue;
    const float* xrow = x + ((size_t)b * 64 + iy) * 64;
    for (int dx = 0; dx < 4; ++dx) {
      float wv = w[(dy * 4 + dx) * 32 + c];
#pragma unroll
      for (int i = 0; i < 4; ++i) {
        int ix = 8 * xg + 2 * i + dx - 1;
        float v = (ix >= 0 && ix < 64) ? xrow[ix] : 0.f;
        acc[i] = fmaf(v, wv, acc[i]);
      }
    }
  }
  float bv = bias[c];
  float* orow = out + (((size_t)b * 32 + y) * 32) * 32;
#pragma unroll
  for (int i = 0; i < 4; ++i) {
    float v = acc[i] + bv;
    orow[(4 * xg + i) * 32 + c] = v > 0.f ? v : 0.f;
  }
}

// ---------------- conv2: h1(256,32,32,32) -> h2(256,16,16,64) ----------------
__global__ __launch_bounds__(256) void k_conv2(const float* __restrict__ h1,
                                               const float* __restrict__ w,
                                               const float* __restrict__ bias,
                                               const float* __restrict__ zeros,
                                               float* __restrict__ out) {
  __shared__ float ws[8192];        // one dy slice: [dx][ci][co] 4*32*64
  int b  = blockIdx.x >> 3;         // 2048 blocks
  int yp = blockIdx.x & 7;
  int t = threadIdx.x;
  int c = t & 63;
  int xg = __builtin_amdgcn_readfirstlane((int)(threadIdx.x >> 6)); // 0..3
  float acc[2][4] = {};
  for (int dy = 0; dy < 4; ++dy) {
    __syncthreads();
#pragma unroll
    for (int j = 0; j < 32; ++j) ws[t + j * 256] = w[dy * 8192 + t + j * 256];
    __syncthreads();
    for (int dx = 0; dx < 4; ++dx) {
      const float* hp[2][4];
#pragma unroll
      for (int yy = 0; yy < 2; ++yy) {
        int iy = 4 * yp + 2 * yy + dy - 1;
        bool oky = (iy >= 0 && iy < 32);
#pragma unroll
        for (int i = 0; i < 4; ++i) {
          int ix = 8 * xg + 2 * i + dx - 1;
          bool ok = oky && (ix >= 0 && ix < 32);
          hp[yy][i] = ok ? (h1 + (((size_t)b * 32 + iy) * 32 + ix) * 32) : zeros;
        }
      }
#pragma unroll 8
      for (int ci = 0; ci < 32; ++ci) {
        float wv = ws[(dx * 32 + ci) * 64 + c];
#pragma unroll
        for (int yy = 0; yy < 2; ++yy)
#pragma unroll
          for (int i = 0; i < 4; ++i)
            acc[yy][i] = fmaf(hp[yy][i][ci], wv, acc[yy][i]);
      }
    }
  }
  float bv = bias[c];
#pragma unroll
  for (int yy = 0; yy < 2; ++yy)
#pragma unroll
    for (int i = 0; i < 4; ++i) {
      float v = acc[yy][i] + bv;
      int yo = 2 * yp + yy, xo = 4 * xg + i;
      out[(((size_t)b * 16 + yo) * 16 + xo) * 64 + c] = v > 0.f ? v : 0.f;
    }
}

// ---------------- conv3: h2(256,16,16,64) -> h3(256,8,8,128) ----------------
__global__ __launch_bounds__(256) void k_conv3(const float* __restrict__ h2,
                                               const float* __restrict__ w,
                                               const float* __restrict__ bias,
                                               const float* __restrict__ zeros,
                                               float* __restrict__ out) {
  __shared__ float ws[8192];        // one (dy,dx) slice: [ci][co] 64*128
  int b  = blockIdx.x >> 2;         // 1024 blocks
  int yp = blockIdx.x & 3;
  int t = threadIdx.x;
  int c = t & 127;
  int xg = __builtin_amdgcn_readfirstlane((int)(threadIdx.x >> 7)); // 0..1
  float acc[2][4] = {};
  for (int dydx = 0; dydx < 16; ++dydx) {
    int dy = dydx >> 2, dx = dydx & 3;
    __syncthreads();
#pragma unroll
    for (int j = 0; j < 32; ++j) ws[t + j * 256] = w[dydx * 8192 + t + j * 256];
    __syncthreads();
    const float* hp[2][4];
#pragma unroll
    for (int yy = 0; yy < 2; ++yy) {
      int iy = 4 * yp + 2 * yy + dy - 1;
      bool oky = (iy >= 0 && iy < 16);
#pragma unroll
      for (int i = 0; i < 4; ++i) {
        int ix = 8 * xg + 2 * i + dx - 1;
        bool ok = oky && (ix >= 0 && ix < 16);
        hp[yy][i] = ok ? (h2 + (((size_t)b * 16 + iy) * 16 + ix) * 64) : zeros;
      }
    }
#pragma unroll 8
    for (int ci = 0; ci < 64; ++ci) {
      float wv = ws[ci * 128 + c];
#pragma unroll
      for (int yy = 0; yy < 2; ++yy)
#pragma unroll
        for (int i = 0; i < 4; ++i)
          acc[yy][i] = fmaf(hp[yy][i][ci], wv, acc[yy][i]);
    }
  }
  float bv = bias[c];
#pragma unroll
  for (int yy = 0; yy < 2; ++yy)
#pragma unroll
    for (int i = 0; i < 4; ++i) {
      float v = acc[yy][i] + bv;
      int yo = 2 * yp + yy, xo = 4 * xg + i;
      out[(((size_t)b * 8 + yo) * 8 + xo) * 128 + c] = v > 0.f ? v : 0.f;
    }
}

// ---------------- generic GEMM: C = A(MxK) * B(KxN), row-major ----------------
__global__ __launch_bounds__(256) void k_gemm(const float* __restrict__ A,
                                              const float* __restrict__ Bm,
                                              float* __restrict__ C,
                                              const float* __restrict__ bias,
                                              int M, int N, int K, int bmask) {
  __shared__ float Bs[32 * 128];    // 16KB
  int S = gridDim.z;
  int Kc = K / S;
  int k0base = blockIdx.z * Kc;
  int m0 = blockIdx.x * 16;
  int n0 = blockIdx.y * 128;
  int t = threadIdx.x;
  int n2 = (t & 63) * 2;
  int mg = __builtin_amdgcn_readfirstlane((int)(threadIdx.x >> 6)); // 0..3
  const float* pa[4];
#pragma unroll
  for (int r = 0; r < 4; ++r) pa[r] = A + (size_t)(m0 + mg * 4 + r) * K;
  float2 acc[4] = {};
  for (int k0 = k0base; k0 < k0base + Kc; k0 += 32) {
    __syncthreads();
#pragma unroll
    for (int j = 0; j < 16; ++j) {
      int idx = t + j * 256;
      int row = idx >> 7, col = idx & 127;
      Bs[idx] = Bm[(size_t)(k0 + row) * N + n0 + col];
    }
    __syncthreads();
#pragma unroll
    for (int kk = 0; kk < 32; ++kk) {
      float2 bv = *(const float2*)&Bs[kk * 128 + n2];
#pragma unroll
      for (int r = 0; r < 4; ++r) {
        float av = pa[r][k0 + kk];
        acc[r].x = fmaf(av, bv.x, acc[r].x);
        acc[r].y = fmaf(av, bv.y, acc[r].y);
      }
    }
  }
  if (S == 1) {
    float b0 = bias[(n0 + n2) & bmask];
    float b1 = bias[(n0 + n2 + 1) & bmask];
#pragma unroll
    for (int r = 0; r < 4; ++r) {
      int m = m0 + mg * 4 + r;
      float2 o = acc[r];
      o.x += b0; o.y += b1;
      o.x = o.x > 0.f ? o.x : 0.f;
      o.y = o.y > 0.f ? o.y : 0.f;
      *(float2*)&C[(size_t)m * N + n0 + n2] = o;
    }
  } else {
    float* Cp = C + (size_t)blockIdx.z * M * N;
#pragma unroll
    for (int r = 0; r < 4; ++r) {
      int m = m0 + mg * 4 + r;
      *(float2*)&Cp[(size_t)m * N + n0 + n2] = acc[r];
    }
  }
}

// sum k-split partials + bias + relu
__global__ __launch_bounds__(256) void k_sumrelu(const float* __restrict__ part,
                                                 const float* __restrict__ bias,
                                                 float* __restrict__ out,
                                                 int MN, int nmask, int S) {
  int idx = blockIdx.x * 256 + threadIdx.x;
  float s = 0.f;
  for (int z = 0; z < S; ++z) s += part[(size_t)z * MN + idx];
  s += bias[idx & nmask];
  out[idx] = s > 0.f ? s : 0.f;
}

// ---------------- VQ ----------------
__global__ __launch_bounds__(256) void k_norm2(const float* __restrict__ e,
                                               float* __restrict__ n2) {
  int k = blockIdx.x * 256 + threadIdx.x;
  const float4* p = (const float4*)(e + (size_t)k * 64);
  float s0 = 0, s1 = 0, s2 = 0, s3 = 0;
#pragma unroll
  for (int j = 0; j < 16; ++j) {
    float4 v = p[j];
    s0 = fmaf(v.x, v.x, s0); s1 = fmaf(v.y, v.y, s1);
    s2 = fmaf(v.z, v.z, s2); s3 = fmaf(v.w, v.w, s3);
  }
  n2[k] = (s0 + s1) + (s2 + s3);
}

// fp32 -> 3-term bf16 split (hi + mid + lo captures ~24 mantissa bits)
__global__ __launch_bounds__(256) void k_split3(const float* __restrict__ in,
                                                unsigned short* __restrict__ h,
                                                unsigned short* __restrict__ m,
                                                unsigned short* __restrict__ l,
                                                int n) {
  int i = blockIdx.x * 256 + threadIdx.x;
  if (i >= n) return;
  float x = in[i];
  unsigned short hb = f2bf(x);
  float r1 = x - bf2f(hb);
  unsigned short mb = f2bf(r1);
  float r2 = r1 - bf2f(mb);
  unsigned short lb = f2bf(r2);
  h[i] = hb; m[i] = mb; l[i] = lb;
}

// k_vqmfma: argmin_k(||e_k||^2 - 2 p.e_k) via 6-product split-bf16 MFMA.
// grid (32 code-blocks, 16 m-splits), block 256 = 4 waves.
// Wave owns 64 codes: B frags (3 splits x 2 ksteps x 4 ntiles) resident in
// 96 VGPRs, loaded once. Streams 32 m-tiles (16 rows) of pred: 6 global
// 16B loads + 48 MFMA + argmin epilogue each. fp32 accuracy: error ~1e-8
// << fp32-VALU rounding -> argmin identical to the R3 fp32 version.
// MFMA layouts (gfx950 16x16x32): A[m=lane&15][k=quad*8+j],
// B[k=quad*8+j][n=lane&15], D row=quad*4+reg col=lane&15.
__global__ __launch_bounds__(256) void k_vqmfma(
    const unsigned short* __restrict__ pH, const unsigned short* __restrict__ pM,
    const unsigned short* __restrict__ pL, const unsigned short* __restrict__ eH,
    const unsigned short* __restrict__ eM, const unsigned short* __restrict__ eL,
    const float* __restrict__ n2, float* __restrict__ pbd, int* __restrict__ pbk) {
  int t = threadIdx.x;
  int wave = t >> 6, lane = t & 63;
  int l15 = lane & 15, quad = lane >> 4;
  int cbase = blockIdx.x * 256 + wave * 64;
  int mstart = blockIdx.y * 512;
  // B-resident fragments for this wave's 64 codes
  bf16x8 bh[4][2], bm[4][2], bl[4][2];
  float nv[4];
#pragma unroll
  for (int nt = 0; nt < 4; ++nt) {
    int code = cbase + nt * 16 + l15;
    nv[nt] = n2[code];
#pragma unroll
    for (int ks = 0; ks < 2; ++ks) {
      size_t o = (size_t)code * 64 + ks * 32 + quad * 8;
      bh[nt][ks] = *(const bf16x8*)(eH + o);
      bm[nt][ks] = *(const bf16x8*)(eM + o);
      bl[nt][ks] = *(const bf16x8*)(eL + o);
    }
  }
  int g = blockIdx.x * 4 + wave;    // 128 partial groups
  bf16x8 ah[2], am[2], al[2], ah2[2], am2[2], al2[2];
  {
    size_t o0 = (size_t)(mstart + l15) * 64 + quad * 8;
    ah[0] = *(const bf16x8*)(pH + o0); ah[1] = *(const bf16x8*)(pH + o0 + 32);
    am[0] = *(const bf16x8*)(pM + o0); am[1] = *(const bf16x8*)(pM + o0 + 32);
    al[0] = *(const bf16x8*)(pL + o0); al[1] = *(const bf16x8*)(pL + o0 + 32);
  }
  for (int mt = 0; mt < 32; ++mt) {
    int m0 = mstart + mt * 16;
    if (mt + 1 < 32) {              // prefetch next m-tile's A frags
      size_t o0 = (size_t)(m0 + 16 + l15) * 64 + quad * 8;
      ah2[0] = *(const bf16x8*)(pH + o0); ah2[1] = *(const bf16x8*)(pH + o0 + 32);
      am2[0] = *(const bf16x8*)(pM + o0); am2[1] = *(const bf16x8*)(pM + o0 + 32);
      al2[0] = *(const bf16x8*)(pL + o0); al2[1] = *(const bf16x8*)(pL + o0 + 32);
    }
    float bd[4] = {FLT_MAX, FLT_MAX, FLT_MAX, FLT_MAX};
    int bk[4] = {0, 0, 0, 0};
#pragma unroll
    for (int nt = 0; nt < 4; ++nt) {
      f32x4 acc = {0.f, 0.f, 0.f, 0.f};
#pragma unroll
      for (int ks = 0; ks < 2; ++ks) {
        acc = MFMA16(am[ks], bm[nt][ks], acc);
        acc = MFMA16(ah[ks], bl[nt][ks], acc);
        acc = MFMA16(al[ks], bh[nt][ks], acc);
        acc = MFMA16(ah[ks], bm[nt][ks], acc);
        acc = MFMA16(am[ks], bh[nt][ks], acc);
        acc = MFMA16(ah[ks], bh[nt][ks], acc);
      }
      int code = cbase + nt * 16 + l15;
#pragma unroll
      for (int r = 0; r < 4; ++r) {
        float d = fmaf(-2.f, acc[r], nv[nt]);
        if (d < bd[r]) { bd[r] = d; bk[r] = code; }  // nt ascending => lowest k on tie
      }
    }
    // lexicographic (d,k) min across the 16 lanes of each quad
#pragma unroll
    for (int r = 0; r < 4; ++r) {
#pragma unroll
      for (int s = 1; s < 16; s <<= 1) {
        float od = __shfl_xor(bd[r], s);
        int ok = __shfl_xor(bk[r], s);
        if (od < bd[r] || (od == bd[r] && ok < bk[r])) { bd[r] = od; bk[r] = ok; }
      }
    }
    if (l15 == 0) {
#pragma unroll
      for (int r = 0; r < 4; ++r) {
        pbd[(size_t)g * 8192 + m0 + quad * 4 + r] = bd[r];
        pbk[(size_t)g * 8192 + m0 + quad * 4 + r] = bk[r];
      }
    }
#pragma unroll
    for (int ks = 0; ks < 2; ++ks) { ah[ks] = ah2[ks]; am[ks] = am2[ks]; al[ks] = al2[ks]; }
  }
}

// reduce the 128 partial groups per row -> classes (8192 rows)
__global__ __launch_bounds__(256) void k_vqfinal(const float* __restrict__ pbd,
                                                 const int* __restrict__ pbk,
                                                 int* __restrict__ classes) {
  int m = blockIdx.x * 256 + threadIdx.x;   // 32 blocks
  float bd = pbd[m]; int bk = pbk[m];
  for (int z = 1; z < 128; ++z) {
    float d = pbd[(size_t)z * 8192 + m]; int k = pbk[(size_t)z * 8192 + m];
    if (d < bd || (d == bd && k < bk)) { bd = d; bk = k; }
  }
  classes[m] = bk;
}

__global__ __launch_bounds__(256) void k_gather(const int* __restrict__ classes,
                                                const float* __restrict__ embeds,
                                                float* __restrict__ out) {
  int idx = blockIdx.x * 256 + threadIdx.x;
  int m = idx >> 6, e = idx & 63;
  out[idx] = embeds[(size_t)classes[m] * 64 + e];
}

// ---------------- decoder weight permutes (spatial flip + GEMM layout) -------
__global__ __launch_bounds__(256) void k_permW1(const float* __restrict__ w,
                                                float* __restrict__ wp) {
  int idx = blockIdx.x * 256 + threadIdx.x; // 2,097,152
  int cc = idx >> 12, n = idx & 4095;
  int ru = n >> 8, o = n & 255, r = ru >> 2, u = ru & 3;
  wp[idx] = w[((size_t)((3 - r) * 4 + (3 - u)) * 512 + cc) * 256 + o];
}
__global__ __launch_bounds__(256) void k_permW2(const float* __restrict__ w,
                                                float* __restrict__ wp) {
  int idx = blockIdx.x * 256 + threadIdx.x; // 524,288
  int cc = idx >> 11, n = idx & 2047;
  int ru = n >> 7, o = n & 127, r = ru >> 2, u = ru & 3;
  wp[idx] = w[((size_t)((3 - r) * 4 + (3 - u)) * 256 + cc) * 128 + o];
}

// ---------------- dec3: d2buf(permuted) -> out(256,64,64), +bias, no relu ----
__global__ __launch_bounds__(256) void k_dec3(const float* __restrict__ d2buf,
                                              const float* __restrict__ w3,
                                              const float* __restrict__ b3,
                                              float* __restrict__ out) {
  __shared__ float sx[16 * 129];
  __shared__ float wT[128 * 16];
  int b = blockIdx.x >> 4;          // 4096 blocks: (b, y_in)
  int y = blockIdx.x & 15;
  int t = threadIdx.x;
#pragma unroll
  for (int j = 0; j < 8; ++j) {
    int idx = t + j * 256;          // 2048
    int xx = idx >> 7, c = idx & 127;
    size_t m2 = ((size_t)b * 4 + (y >> 2)) * 4 + (xx >> 2);
    sx[xx * 129 + c] = d2buf[m2 * 2048 + ((y & 3) * 4 + (xx & 3)) * 128 + c];
  }
#pragma unroll
  for (int j = 0; j < 8; ++j) {
    int idx = t + j * 256;
    int c = idx >> 4, ru = idx & 15;
    int R = ru >> 2, U = ru & 3;
    wT[c * 16 + ru] = w3[((3 - R) * 4 + (3 - U)) * 128 + c];
  }
  __syncthreads();
  int xx = t >> 4, ru = t & 15;
  float a0 = 0, a1 = 0, a2 = 0, a3 = 0;
#pragma unroll 8
  for (int c = 0; c < 128; c += 4) {
    a0 = fmaf(sx[xx * 129 + c + 0], wT[(c + 0) * 16 + ru], a0);
    a1 = fmaf(sx[xx * 129 + c + 1], wT[(c + 1) * 16 + ru], a1);
    a2 = fmaf(sx[xx * 129 + c + 2], wT[(c + 2) * 16 + ru], a2);
    a3 = fmaf(sx[xx * 129 + c + 3], wT[(c + 3) * 16 + ru], a3);
  }
  float acc = (a0 + a1) + (a2 + a3) + b3[0];
  int R = ru >> 2, U = ru & 3;
  out[((size_t)b * 64 + 4 * y + R) * 64 + 4 * xx + U] = acc;
}

// =====================================================================
extern "C" void kernel_launch(void* const* d_in, const int* in_sizes, int n_in,
                              void* d_out, int out_size, void* d_ws, size_t ws_size,
                              hipStream_t stream) {
  const float* x        = (const float*)d_in[0];
  const float* enc_w1   = (const float*)d_in[1];
  const float* enc_b1   = (const float*)d_in[2];
  const float* enc_w2   = (const float*)d_in[3];
  const float* enc_b2   = (const float*)d_in[4];
  const float* enc_w3   = (const float*)d_in[5];
  const float* enc_b3   = (const float*)d_in[6];
  const float* fc_w     = (const float*)d_in[7];
  const float* fc_b     = (const float*)d_in[8];
  const float* ffc_w    = (const float*)d_in[9];
  const float* ffc_b    = (const float*)d_in[10];
  const float* embeds   = (const float*)d_in[11];
  const float* dec_fc_w = (const float*)d_in[12];
  const float* dec_fc_b = (const float*)d_in[13];
  const float* dec_w1   = (const float*)d_in[14];
  const float* dec_b1   = (const float*)d_in[15];
  const float* dec_w2   = (const float*)d_in[16];
  const float* dec_b2   = (const float*)d_in[17];
  const float* dec_w3   = (const float*)d_in[18];
  const float* dec_b3   = (const float*)d_in[19];
  float* outp = (float*)d_out;

  char* ws = (char*)d_ws;
  size_t off = 0;
  auto alloc = [&](size_t bytes) { size_t r = off; off = (off + bytes + 255) & ~(size_t)255; return r; };
  float* h1        = (float*)(ws + alloc(8388608ull * 4));   // 256*32*32*32
  float* h2        = (float*)(ws + alloc(4194304ull * 4));   // 256*16*16*64 (16MB)
  float* h3        = (float*)(ws + alloc(2097152ull * 4));   // 256*8*8*128 (8MB)
  float* fcpart    = (float*)(ws + alloc(8ull * 131072 * 4));
  float* hfc       = (float*)(ws + alloc(131072ull * 4));
  float* pred      = (float*)(ws + alloc(524288ull * 4));    // 8192 x 64
  float* n2buf     = (float*)(ws + alloc(8192ull * 4));
  int*   classes   = (int*)  (ws + alloc(8192ull * 4));
  float* collected = (float*)(ws + alloc(524288ull * 4));
  float* hdfc      = (float*)(ws + alloc(131072ull * 4));
  float* W1p       = (float*)(ws + alloc(2097152ull * 4));   // 512*4096
  float* d1out     = (float*)(ws + alloc(1048576ull * 4));   // 256*4096
  float* W2p       = (float*)(ws + alloc(524288ull * 4));    // 256*2048
  float* zeros     = (float*)(ws + alloc(1024));
  float* d2buf     = h1;        // 4096*2048, h1 dead after conv2
  float* dfcpart   = fcpart;    // fc epilogue done before dec_fc gemm
  // VQ split buffers alias h3 (dead after fc gemm): 6 x 1MB <= 8MB
  unsigned short* eH = (unsigned short*)h3;
  unsigned short* eM = eH + 524288;
  unsigned short* eL = eM + 524288;
  unsigned short* pH = eL + 524288;
  unsigned short* pM = pH + 524288;
  unsigned short* pL = pM + 524288;
  // VQ partials alias h2 (dead after conv3): 128*8192*4 = 4MB each <= 16MB
  float* pbd = h2;
  int*   pbk = (int*)((char*)h2 + 4194304ull);
  (void)ws_size; (void)in_sizes; (void)n_in; (void)out_size;

  hipMemsetAsync(zeros, 0, 1024, stream);

  k_conv1<<<8192, 256, 0, stream>>>(x, enc_w1, enc_b1, h1);
  k_conv2<<<2048, 256, 0, stream>>>(h1, enc_w2, enc_b2, zeros, h2);
  k_conv3<<<1024, 256, 0, stream>>>(h2, enc_w3, enc_b3, zeros, h3);

  // fc: (256x8192)@(8192x512), k-split 8
  k_gemm<<<dim3(16, 4, 8), 256, 0, stream>>>(h3, fc_w, fcpart, zeros, 256, 512, 8192, 0);
  k_sumrelu<<<512, 256, 0, stream>>>(fcpart, fc_b, hfc, 131072, 511, 8);
  // ffc: (256x512)@(512x2048) + bias + relu
  k_gemm<<<dim3(16, 16, 1), 256, 0, stream>>>(hfc, ffc_w, pred, ffc_b, 256, 2048, 512, 2047);

  // VQ: split embeds+pred to bf16 H/M/L (h3 dead now), then MFMA argmin
  k_split3<<<2048, 256, 0, stream>>>(embeds, eH, eM, eL, 524288);
  k_split3<<<2048, 256, 0, stream>>>(pred, pH, pM, pL, 524288);
  k_norm2<<<32, 256, 0, stream>>>(embeds, n2buf);
  k_vqmfma<<<dim3(32, 16), 256, 0, stream>>>(pH, pM, pL, eH, eM, eL, n2buf, pbd, pbk);
  k_vqfinal<<<32, 256, 0, stream>>>(pbd, pbk, classes);
  k_gather<<<2048, 256, 0, stream>>>(classes, embeds, collected);

  // dec_fc: (256x2048)@(2048x512), k-split 8
  k_gemm<<<dim3(16, 4, 8), 256, 0, stream>>>(collected, dec_fc_w, dfcpart, zeros, 256, 512, 2048, 0);
  k_sumrelu<<<512, 256, 0, stream>>>(dfcpart, dec_fc_b, hdfc, 131072, 511, 8);

  k_permW1<<<8192, 256, 0, stream>>>(dec_w1, W1p);
  k_permW2<<<2048, 256, 0, stream>>>(dec_w2, W2p);
  // dec1: (256x512)@(512x4096) -> d1out rows (b) cols (i*4+j)*256+c
  k_gemm<<<dim3(16, 32, 1), 256, 0, stream>>>(hdfc, W1p, d1out, dec_b1, 256, 4096, 512, 255);
  // dec2: (4096x256)@(256x2048) -> d2buf rows (b,i,j) cols (r*4+u)*128+o
  k_gemm<<<dim3(256, 16, 1), 256, 0, stream>>>(d1out, W2p, d2buf, dec_b2, 4096, 2048, 256, 127);
  // dec3 -> final output (no relu)
  k_dec3<<<4096, 256, 0, stream>>>(d2buf, dec_w3, dec_b3, outp);
}

// Round 5
// 622.379 us; speedup vs baseline: 12.2385x; 1.2088x over previous
//
#include <hip/hip_runtime.h>
#include <cfloat>

// =====================================================================
// VQ-VAE forward.
// R5: conv2/conv3 -> direct-fragment split-bf16 MFMA convs (padded split
// inputs, B-frag-packed weights); k_vqfinal parallelized (was 8192-thread
// latency-bound serial scan ~50us).
// Precision: 3-term bf16 split (6 MFMA products) == fp32 to ~2^-25 rel;
// R3 (fp32) vs R4 (split) showed identical absmax -> argmin bit-stable.
//
// conv_transpose (transpose_kernel=False) => flipped kernel:
//   out[4i+r, 4j+u, o] = sum_c in[i,j,c] * w[3-r, 3-u, c, o]
// Encoder convs: SAME pad = (1,1) -> padded inputs, in[2y+dy, 2x+dx].
// =====================================================================

typedef short bf16x8 __attribute__((ext_vector_type(8)));
typedef float f32x4 __attribute__((ext_vector_type(4)));
#define MFMA16(a, b, c) __builtin_amdgcn_mfma_f32_16x16x32_bf16(a, b, c, 0, 0, 0)

__device__ inline unsigned short f2bf(float x) {  // RNE, inputs finite
  unsigned u = __float_as_uint(x);
  u += 0x7fffu + ((u >> 16) & 1u);
  return (unsigned short)(u >> 16);
}
__device__ inline float bf2f(unsigned short h) {
  return __uint_as_float(((unsigned)h) << 16);
}
__device__ inline void split3v(float v, unsigned short& hb, unsigned short& mb,
                               unsigned short& lb) {
  hb = f2bf(v);
  float r1 = v - bf2f(hb);
  mb = f2bf(r1);
  lb = f2bf(r1 - bf2f(mb));
}

// ---------------- conv1: x(256,64,64,1) -> h1p split padded (256,34,34,32) ----
__global__ __launch_bounds__(256) void k_conv1(const float* __restrict__ x,
                                               const float* __restrict__ w,
                                               const float* __restrict__ bias,
                                               unsigned short* __restrict__ oH,
                                               unsigned short* __restrict__ oM,
                                               unsigned short* __restrict__ oL) {
  int b = blockIdx.x >> 5;          // 8192 blocks: (b, y)
  int y = blockIdx.x & 31;
  int t = threadIdx.x;
  int c = t & 31;
  int xg = t >> 5;                  // 0..7, 4 x-positions each
  float acc[4] = {0.f, 0.f, 0.f, 0.f};
  for (int dy = 0; dy < 4; ++dy) {
    int iy = 2 * y + dy - 1;
    if (iy < 0 || iy >= 64) continue;
    const float* xrow = x + ((size_t)b * 64 + iy) * 64;
    for (int dx = 0; dx < 4; ++dx) {
      float wv = w[(dy * 4 + dx) * 32 + c];
#pragma unroll
      for (int i = 0; i < 4; ++i) {
        int ix = 8 * xg + 2 * i + dx - 1;
        float v = (ix >= 0 && ix < 64) ? xrow[ix] : 0.f;
        acc[i] = fmaf(v, wv, acc[i]);
      }
    }
  }
  float bv = bias[c];
#pragma unroll
  for (int i = 0; i < 4; ++i) {
    float v = acc[i] + bv;
    v = v > 0.f ? v : 0.f;
    unsigned short hb, mb, lb;
    split3v(v, hb, mb, lb);
    size_t o = ((size_t)(b * 34 + y + 1) * 34 + (4 * xg + i + 1)) * 32 + c;
    oH[o] = hb; oM[o] = mb; oL[o] = lb;
  }
}

// ---------------- weight prep: split + pack into MFMA B-frag layout ----------
// Wp2[s][nt][lane][j]: ci=(lane>>4)*8+j, co=nt*16+(lane&15), s=dy*4+dx
__global__ __launch_bounds__(256) void k_wprep2(const float* __restrict__ w,
                                                unsigned short* __restrict__ H,
                                                unsigned short* __restrict__ M,
                                                unsigned short* __restrict__ L) {
  int idx = blockIdx.x * 256 + threadIdx.x;   // 32768
  int j = idx & 7, lane = (idx >> 3) & 63, nt = (idx >> 9) & 3, s = idx >> 11;
  int ci = ((lane >> 4) << 3) + j, co = (nt << 4) + (lane & 15);
  unsigned short hb, mb, lb;
  split3v(w[(s * 32 + ci) * 64 + co], hb, mb, lb);
  H[idx] = hb; M[idx] = mb; L[idx] = lb;
}
// Wp3[s][ch][nt][ks][lane][j]: ci=ks*32+(lane>>4)*8+j, co=ch*64+nt*16+(lane&15)
__global__ __launch_bounds__(256) void k_wprep3(const float* __restrict__ w,
                                                unsigned short* __restrict__ H,
                                                unsigned short* __restrict__ M,
                                                unsigned short* __restrict__ L) {
  int idx = blockIdx.x * 256 + threadIdx.x;   // 131072
  int j = idx & 7, lane = (idx >> 3) & 63, ks = (idx >> 9) & 1;
  int nt = (idx >> 10) & 3, ch = (idx >> 12) & 1, s = idx >> 13;
  int ci = ks * 32 + ((lane >> 4) << 3) + j;
  int co = ch * 64 + (nt << 4) + (lane & 15);
  unsigned short hb, mb, lb;
  split3v(w[(s * 64 + ci) * 128 + co], hb, mb, lb);
  H[idx] = hb; M[idx] = mb; L[idx] = lb;
}

// ---------------- conv2 MFMA: h1p(256,34,34,32) -> h2p split (256,18,18,64) --
// block = 64 pixels x 64 co (4 waves, each 16 pixels x all co).
__global__ __launch_bounds__(256) void k_conv2m(
    const unsigned short* __restrict__ aH, const unsigned short* __restrict__ aM,
    const unsigned short* __restrict__ aL, const unsigned short* __restrict__ wH,
    const unsigned short* __restrict__ wM, const unsigned short* __restrict__ wL,
    const float* __restrict__ bias, unsigned short* __restrict__ oH,
    unsigned short* __restrict__ oM, unsigned short* __restrict__ oL) {
  int t = threadIdx.x;
  int wave = t >> 6, lane = t & 63;
  int l15 = lane & 15, quad = lane >> 4;
  int m0 = blockIdx.x * 64 + wave * 16;     // 1024 blocks
  int p = m0 + l15;
  int b = p >> 8, y = (p >> 4) & 15, x = p & 15;
  f32x4 acc[4] = {};
  for (int s = 0; s < 16; ++s) {
    int dy = s >> 2, dx = s & 3;
    size_t aoff = ((size_t)(b * 34 + 2 * y + dy) * 34 + (2 * x + dx)) * 32 + quad * 8;
    bf16x8 ah = *(const bf16x8*)(aH + aoff);
    bf16x8 am = *(const bf16x8*)(aM + aoff);
    bf16x8 al = *(const bf16x8*)(aL + aoff);
#pragma unroll
    for (int nt = 0; nt < 4; ++nt) {
      size_t woff = ((size_t)(s * 4 + nt) * 64 + lane) * 8;
      bf16x8 bh = *(const bf16x8*)(wH + woff);
      bf16x8 bm = *(const bf16x8*)(wM + woff);
      bf16x8 bl = *(const bf16x8*)(wL + woff);
      acc[nt] = MFMA16(am, bm, acc[nt]);
      acc[nt] = MFMA16(ah, bl, acc[nt]);
      acc[nt] = MFMA16(al, bh, acc[nt]);
      acc[nt] = MFMA16(ah, bm, acc[nt]);
      acc[nt] = MFMA16(am, bh, acc[nt]);
      acc[nt] = MFMA16(ah, bh, acc[nt]);
    }
  }
#pragma unroll
  for (int r = 0; r < 4; ++r) {
    int pp = m0 + quad * 4 + r;
    int b2 = pp >> 8, yo = (pp >> 4) & 15, xo = pp & 15;
    size_t obase = ((size_t)(b2 * 18 + yo + 1) * 18 + (xo + 1)) * 64;
#pragma unroll
    for (int nt = 0; nt < 4; ++nt) {
      int co = nt * 16 + l15;
      float v = acc[nt][r] + bias[co];
      v = v > 0.f ? v : 0.f;
      unsigned short hb, mb, lb;
      split3v(v, hb, mb, lb);
      oH[obase + co] = hb; oM[obase + co] = mb; oL[obase + co] = lb;
    }
  }
}

// ---------------- conv3 MFMA: h2p(256,18,18,64) -> h3 fp32 (16384,128) -------
// block = 64 pixels x 128 co (4 waves: 2 pixel-groups x 2 co-halves).
__global__ __launch_bounds__(256) void k_conv3m(
    const unsigned short* __restrict__ aH, const unsigned short* __restrict__ aM,
    const unsigned short* __restrict__ aL, const unsigned short* __restrict__ wH,
    const unsigned short* __restrict__ wM, const unsigned short* __restrict__ wL,
    const float* __restrict__ bias, float* __restrict__ out) {
  int t = threadIdx.x;
  int wave = t >> 6, lane = t & 63;
  int l15 = lane & 15, quad = lane >> 4;
  int pg = wave >> 1, ch = wave & 1;
  int m0 = blockIdx.x * 64 + pg * 32;       // 256 blocks
  f32x4 acc[2][4] = {};
  for (int s = 0; s < 16; ++s) {
    int dy = s >> 2, dx = s & 3;
    bf16x8 ah[2][2], am[2][2], al[2][2];
#pragma unroll
    for (int mt = 0; mt < 2; ++mt) {
      int p = m0 + mt * 16 + l15;
      int b = p >> 6, y = (p >> 3) & 7, x = p & 7;
      size_t base = ((size_t)(b * 18 + 2 * y + dy) * 18 + (2 * x + dx)) * 64 + quad * 8;
#pragma unroll
      for (int ks = 0; ks < 2; ++ks) {
        ah[mt][ks] = *(const bf16x8*)(aH + base + ks * 32);
        am[mt][ks] = *(const bf16x8*)(aM + base + ks * 32);
        al[mt][ks] = *(const bf16x8*)(aL + base + ks * 32);
      }
    }
#pragma unroll
    for (int nt = 0; nt < 4; ++nt) {
#pragma unroll
      for (int ks = 0; ks < 2; ++ks) {
        size_t woff = ((size_t)((((s * 2 + ch) * 4 + nt) * 2 + ks) * 64 + lane)) * 8;
        bf16x8 bh = *(const bf16x8*)(wH + woff);
        bf16x8 bm = *(const bf16x8*)(wM + woff);
        bf16x8 bl = *(const bf16x8*)(wL + woff);
#pragma unroll
        for (int mt = 0; mt < 2; ++mt) {
          acc[mt][nt] = MFMA16(am[mt][ks], bm, acc[mt][nt]);
          acc[mt][nt] = MFMA16(ah[mt][ks], bl, acc[mt][nt]);
          acc[mt][nt] = MFMA16(al[mt][ks], bh, acc[mt][nt]);
          acc[mt][nt] = MFMA16(ah[mt][ks], bm, acc[mt][nt]);
          acc[mt][nt] = MFMA16(am[mt][ks], bh, acc[mt][nt]);
          acc[mt][nt] = MFMA16(ah[mt][ks], bh, acc[mt][nt]);
        }
      }
    }
  }
#pragma unroll
  for (int mt = 0; mt < 2; ++mt)
#pragma unroll
    for (int nt = 0; nt < 4; ++nt) {
      int co = ch * 64 + nt * 16 + l15;
      float bv = bias[co];
#pragma unroll
      for (int r = 0; r < 4; ++r) {
        int pp = m0 + mt * 16 + quad * 4 + r;
        float v = acc[mt][nt][r] + bv;
        out[(size_t)pp * 128 + co] = v > 0.f ? v : 0.f;
      }
    }
}

// ---------------- generic GEMM: C = A(MxK) * B(KxN), row-major (fp32) --------
__global__ __launch_bounds__(256) void k_gemm(const float* __restrict__ A,
                                              const float* __restrict__ Bm,
                                              float* __restrict__ C,
                                              const float* __restrict__ bias,
                                              int M, int N, int K, int bmask) {
  __shared__ float Bs[32 * 128];    // 16KB
  int S = gridDim.z;
  int Kc = K / S;
  int k0base = blockIdx.z * Kc;
  int m0 = blockIdx.x * 16;
  int n0 = blockIdx.y * 128;
  int t = threadIdx.x;
  int n2 = (t & 63) * 2;
  int mg = __builtin_amdgcn_readfirstlane((int)(threadIdx.x >> 6)); // 0..3
  const float* pa[4];
#pragma unroll
  for (int r = 0; r < 4; ++r) pa[r] = A + (size_t)(m0 + mg * 4 + r) * K;
  float2 acc[4] = {};
  for (int k0 = k0base; k0 < k0base + Kc; k0 += 32) {
    __syncthreads();
#pragma unroll
    for (int j = 0; j < 16; ++j) {
      int idx = t + j * 256;
      int row = idx >> 7, col = idx & 127;
      Bs[idx] = Bm[(size_t)(k0 + row) * N + n0 + col];
    }
    __syncthreads();
#pragma unroll
    for (int kk = 0; kk < 32; ++kk) {
      float2 bv = *(const float2*)&Bs[kk * 128 + n2];
#pragma unroll
      for (int r = 0; r < 4; ++r) {
        float av = pa[r][k0 + kk];
        acc[r].x = fmaf(av, bv.x, acc[r].x);
        acc[r].y = fmaf(av, bv.y, acc[r].y);
      }
    }
  }
  if (S == 1) {
    float b0 = bias[(n0 + n2) & bmask];
    float b1 = bias[(n0 + n2 + 1) & bmask];
#pragma unroll
    for (int r = 0; r < 4; ++r) {
      int m = m0 + mg * 4 + r;
      float2 o = acc[r];
      o.x += b0; o.y += b1;
      o.x = o.x > 0.f ? o.x : 0.f;
      o.y = o.y > 0.f ? o.y : 0.f;
      *(float2*)&C[(size_t)m * N + n0 + n2] = o;
    }
  } else {
    float* Cp = C + (size_t)blockIdx.z * M * N;
#pragma unroll
    for (int r = 0; r < 4; ++r) {
      int m = m0 + mg * 4 + r;
      *(float2*)&Cp[(size_t)m * N + n0 + n2] = acc[r];
    }
  }
}

// sum k-split partials + bias + relu
__global__ __launch_bounds__(256) void k_sumrelu(const float* __restrict__ part,
                                                 const float* __restrict__ bias,
                                                 float* __restrict__ out,
                                                 int MN, int nmask, int S) {
  int idx = blockIdx.x * 256 + threadIdx.x;
  float s = 0.f;
  for (int z = 0; z < S; ++z) s += part[(size_t)z * MN + idx];
  s += bias[idx & nmask];
  out[idx] = s > 0.f ? s : 0.f;
}

// ---------------- VQ ----------------
__global__ __launch_bounds__(256) void k_norm2(const float* __restrict__ e,
                                               float* __restrict__ n2) {
  int k = blockIdx.x * 256 + threadIdx.x;
  const float4* p = (const float4*)(e + (size_t)k * 64);
  float s0 = 0, s1 = 0, s2 = 0, s3 = 0;
#pragma unroll
  for (int j = 0; j < 16; ++j) {
    float4 v = p[j];
    s0 = fmaf(v.x, v.x, s0); s1 = fmaf(v.y, v.y, s1);
    s2 = fmaf(v.z, v.z, s2); s3 = fmaf(v.w, v.w, s3);
  }
  n2[k] = (s0 + s1) + (s2 + s3);
}

// fp32 -> 3-term bf16 split
__global__ __launch_bounds__(256) void k_split3(const float* __restrict__ in,
                                                unsigned short* __restrict__ h,
                                                unsigned short* __restrict__ m,
                                                unsigned short* __restrict__ l,
                                                int n) {
  int i = blockIdx.x * 256 + threadIdx.x;
  if (i >= n) return;
  unsigned short hb, mb, lb;
  split3v(in[i], hb, mb, lb);
  h[i] = hb; m[i] = mb; l[i] = lb;
}

// k_vqmfma: argmin_k(||e_k||^2 - 2 p.e_k) via 6-product split-bf16 MFMA.
// grid (32 code-blocks, 16 m-splits), block 256 = 4 waves.
__global__ __launch_bounds__(256) void k_vqmfma(
    const unsigned short* __restrict__ pH, const unsigned short* __restrict__ pM,
    const unsigned short* __restrict__ pL, const unsigned short* __restrict__ eH,
    const unsigned short* __restrict__ eM, const unsigned short* __restrict__ eL,
    const float* __restrict__ n2, float* __restrict__ pbd, int* __restrict__ pbk) {
  int t = threadIdx.x;
  int wave = t >> 6, lane = t & 63;
  int l15 = lane & 15, quad = lane >> 4;
  int cbase = blockIdx.x * 256 + wave * 64;
  int mstart = blockIdx.y * 512;
  bf16x8 bh[4][2], bm[4][2], bl[4][2];
  float nv[4];
#pragma unroll
  for (int nt = 0; nt < 4; ++nt) {
    int code = cbase + nt * 16 + l15;
    nv[nt] = n2[code];
#pragma unroll
    for (int ks = 0; ks < 2; ++ks) {
      size_t o = (size_t)code * 64 + ks * 32 + quad * 8;
      bh[nt][ks] = *(const bf16x8*)(eH + o);
      bm[nt][ks] = *(const bf16x8*)(eM + o);
      bl[nt][ks] = *(const bf16x8*)(eL + o);
    }
  }
  int g = blockIdx.x * 4 + wave;    // 128 partial groups
  bf16x8 ah[2], am[2], al[2], ah2[2], am2[2], al2[2];
  {
    size_t o0 = (size_t)(mstart + l15) * 64 + quad * 8;
    ah[0] = *(const bf16x8*)(pH + o0); ah[1] = *(const bf16x8*)(pH + o0 + 32);
    am[0] = *(const bf16x8*)(pM + o0); am[1] = *(const bf16x8*)(pM + o0 + 32);
    al[0] = *(const bf16x8*)(pL + o0); al[1] = *(const bf16x8*)(pL + o0 + 32);
  }
  for (int mt = 0; mt < 32; ++mt) {
    int m0 = mstart + mt * 16;
    if (mt + 1 < 32) {
      size_t o0 = (size_t)(m0 + 16 + l15) * 64 + quad * 8;
      ah2[0] = *(const bf16x8*)(pH + o0); ah2[1] = *(const bf16x8*)(pH + o0 + 32);
      am2[0] = *(const bf16x8*)(pM + o0); am2[1] = *(const bf16x8*)(pM + o0 + 32);
      al2[0] = *(const bf16x8*)(pL + o0); al2[1] = *(const bf16x8*)(pL + o0 + 32);
    }
    float bd[4] = {FLT_MAX, FLT_MAX, FLT_MAX, FLT_MAX};
    int bk[4] = {0, 0, 0, 0};
#pragma unroll
    for (int nt = 0; nt < 4; ++nt) {
      f32x4 acc = {0.f, 0.f, 0.f, 0.f};
#pragma unroll
      for (int ks = 0; ks < 2; ++ks) {
        acc = MFMA16(am[ks], bm[nt][ks], acc);
        acc = MFMA16(ah[ks], bl[nt][ks], acc);
        acc = MFMA16(al[ks], bh[nt][ks], acc);
        acc = MFMA16(ah[ks], bm[nt][ks], acc);
        acc = MFMA16(am[ks], bh[nt][ks], acc);
        acc = MFMA16(ah[ks], bh[nt][ks], acc);
      }
      int code = cbase + nt * 16 + l15;
#pragma unroll
      for (int r = 0; r < 4; ++r) {
        float d = fmaf(-2.f, acc[r], nv[nt]);
        if (d < bd[r]) { bd[r] = d; bk[r] = code; }
      }
    }
#pragma unroll
    for (int r = 0; r < 4; ++r) {
#pragma unroll
      for (int s = 1; s < 16; s <<= 1) {
        float od = __shfl_xor(bd[r], s);
        int ok = __shfl_xor(bk[r], s);
        if (od < bd[r] || (od == bd[r] && ok < bk[r])) { bd[r] = od; bk[r] = ok; }
      }
    }
    if (l15 == 0) {
#pragma unroll
      for (int r = 0; r < 4; ++r) {
        pbd[(size_t)g * 8192 + m0 + quad * 4 + r] = bd[r];
        pbk[(size_t)g * 8192 + m0 + quad * 4 + r] = bk[r];
      }
    }
#pragma unroll
    for (int ks = 0; ks < 2; ++ks) { ah[ks] = ah2[ks]; am[ks] = am2[ks]; al[ks] = al2[ks]; }
  }
}

// parallel reduce of 128 partial groups per row -> classes (8192 rows)
// 256 blocks; 8 threads per row, LDS tree. Lexicographic (d,k).
__global__ __launch_bounds__(256) void k_vqfinal2(const float* __restrict__ pbd,
                                                  const int* __restrict__ pbk,
                                                  int* __restrict__ classes) {
  __shared__ float rd[256];
  __shared__ int rk[256];
  int t = threadIdx.x;
  int rloc = t >> 3, zs = t & 7;
  int m = blockIdx.x * 32 + rloc;
  float bd = FLT_MAX; int bk = 0x7fffffff;
  for (int z = zs; z < 128; z += 8) {
    float d = pbd[(size_t)z * 8192 + m]; int k = pbk[(size_t)z * 8192 + m];
    if (d < bd || (d == bd && k < bk)) { bd = d; bk = k; }
  }
  rd[t] = bd; rk[t] = bk;
  __syncthreads();
  for (int off = 4; off > 0; off >>= 1) {
    if (zs < off) {
      float dv = rd[t + off]; int kv = rk[t + off];
      if (dv < rd[t] || (dv == rd[t] && kv < rk[t])) { rd[t] = dv; rk[t] = kv; }
    }
    __syncthreads();
  }
  if (zs == 0) classes[m] = rk[t];
}

__global__ __launch_bounds__(256) void k_gather(const int* __restrict__ classes,
                                                const float* __restrict__ embeds,
                                                float* __restrict__ out) {
  int idx = blockIdx.x * 256 + threadIdx.x;
  int m = idx >> 6, e = idx & 63;
  out[idx] = embeds[(size_t)classes[m] * 64 + e];
}

// ---------------- decoder weight permutes (spatial flip + GEMM layout) -------
__global__ __launch_bounds__(256) void k_permW1(const float* __restrict__ w,
                                                float* __restrict__ wp) {
  int idx = blockIdx.x * 256 + threadIdx.x; // 2,097,152
  int cc = idx >> 12, n = idx & 4095;
  int ru = n >> 8, o = n & 255, r = ru >> 2, u = ru & 3;
  wp[idx] = w[((size_t)((3 - r) * 4 + (3 - u)) * 512 + cc) * 256 + o];
}
__global__ __launch_bounds__(256) void k_permW2(const float* __restrict__ w,
                                                float* __restrict__ wp) {
  int idx = blockIdx.x * 256 + threadIdx.x; // 524,288
  int cc = idx >> 11, n = idx & 2047;
  int ru = n >> 7, o = n & 127, r = ru >> 2, u = ru & 3;
  wp[idx] = w[((size_t)((3 - r) * 4 + (3 - u)) * 256 + cc) * 128 + o];
}

// ---------------- dec3: d2buf(permuted) -> out(256,64,64), +bias, no relu ----
__global__ __launch_bounds__(256) void k_dec3(const float* __restrict__ d2buf,
                                              const float* __restrict__ w3,
                                              const float* __restrict__ b3,
                                              float* __restrict__ out) {
  __shared__ float sx[16 * 129];
  __shared__ float wT[128 * 16];
  int b = blockIdx.x >> 4;          // 4096 blocks: (b, y_in)
  int y = blockIdx.x & 15;
  int t = threadIdx.x;
#pragma unroll
  for (int j = 0; j < 8; ++j) {
    int idx = t + j * 256;          // 2048
    int xx = idx >> 7, c = idx & 127;
    size_t m2 = ((size_t)b * 4 + (y >> 2)) * 4 + (xx >> 2);
    sx[xx * 129 + c] = d2buf[m2 * 2048 + ((y & 3) * 4 + (xx & 3)) * 128 + c];
  }
#pragma unroll
  for (int j = 0; j < 8; ++j) {
    int idx = t + j * 256;
    int c = idx >> 4, ru = idx & 15;
    int R = ru >> 2, U = ru & 3;
    wT[c * 16 + ru] = w3[((3 - R) * 4 + (3 - U)) * 128 + c];
  }
  __syncthreads();
  int xx = t >> 4, ru = t & 15;
  float a0 = 0, a1 = 0, a2 = 0, a3 = 0;
#pragma unroll 8
  for (int c = 0; c < 128; c += 4) {
    a0 = fmaf(sx[xx * 129 + c + 0], wT[(c + 0) * 16 + ru], a0);
    a1 = fmaf(sx[xx * 129 + c + 1], wT[(c + 1) * 16 + ru], a1);
    a2 = fmaf(sx[xx * 129 + c + 2], wT[(c + 2) * 16 + ru], a2);
    a3 = fmaf(sx[xx * 129 + c + 3], wT[(c + 3) * 16 + ru], a3);
  }
  float acc = (a0 + a1) + (a2 + a3) + b3[0];
  int R = ru >> 2, U = ru & 3;
  out[((size_t)b * 64 + 4 * y + R) * 64 + 4 * xx + U] = acc;
}

// =====================================================================
extern "C" void kernel_launch(void* const* d_in, const int* in_sizes, int n_in,
                              void* d_out, int out_size, void* d_ws, size_t ws_size,
                              hipStream_t stream) {
  const float* x        = (const float*)d_in[0];
  const float* enc_w1   = (const float*)d_in[1];
  const float* enc_b1   = (const float*)d_in[2];
  const float* enc_w2   = (const float*)d_in[3];
  const float* enc_b2   = (const float*)d_in[4];
  const float* enc_w3   = (const float*)d_in[5];
  const float* enc_b3   = (const float*)d_in[6];
  const float* fc_w     = (const float*)d_in[7];
  const float* fc_b     = (const float*)d_in[8];
  const float* ffc_w    = (const float*)d_in[9];
  const float* ffc_b    = (const float*)d_in[10];
  const float* embeds   = (const float*)d_in[11];
  const float* dec_fc_w = (const float*)d_in[12];
  const float* dec_fc_b = (const float*)d_in[13];
  const float* dec_w1   = (const float*)d_in[14];
  const float* dec_b1   = (const float*)d_in[15];
  const float* dec_w2   = (const float*)d_in[16];
  const float* dec_b2   = (const float*)d_in[17];
  const float* dec_w3   = (const float*)d_in[18];
  const float* dec_b3   = (const float*)d_in[19];
  float* outp = (float*)d_out;

  char* ws = (char*)d_ws;
  size_t off = 0;
  auto alloc = [&](size_t bytes) { size_t r = off; off = (off + bytes + 255) & ~(size_t)255; return r; };

  // Region 1: h1p splits (3 x 18,939,904 B); later pbd/pbk/d2buf
  size_t R1 = alloc(3ull * 18939904);
  unsigned short* h1pH = (unsigned short*)(ws + R1);
  unsigned short* h1pM = h1pH + 9469952;
  unsigned short* h1pL = h1pM + 9469952;
  float* pbd   = (float*)(ws + R1);                    // 4 MB (after h1p dead)
  int*   pbk   = (int*)  (ws + R1 + 4194304);          // 4 MB
  float* d2buf = (float*)(ws + R1 + 8388608);          // 32 MB (dec2 output)

  // Region 2: h2p splits (3 x 10,616,832 B); later the small fp32 buffers
  size_t R2 = alloc(3ull * 10616832);
  unsigned short* h2pH = (unsigned short*)(ws + R2);
  unsigned short* h2pM = h2pH + 5308416;
  unsigned short* h2pL = h2pM + 5308416;
  float* fcpart    = (float*)(ws + R2);                // 4 MB
  float* hfc       = (float*)(ws + R2 + 4194304);      // 0.5 MB
  float* pred      = (float*)(ws + R2 + 4718592);      // 2 MB
  float* W1p       = (float*)(ws + R2 + 6815744);      // 8 MB
  float* d1out     = (float*)(ws + R2 + 15204352);     // 4 MB
  float* W2p       = (float*)(ws + R2 + 19398656);     // 2 MB
  float* hdfc      = (float*)(ws + R2 + 21495808);     // 0.5 MB
  float* collected = (float*)(ws + R2 + 22020096);     // 2 MB
  float* dfcpart   = fcpart;

  // h3 fp32 (8 MB); later VQ split buffers (6 x 1 MB)
  float* h3 = (float*)(ws + alloc(8388608));
  unsigned short* eH = (unsigned short*)h3;
  unsigned short* eM = eH + 524288;
  unsigned short* eL = eM + 524288;
  unsigned short* pH = eL + 524288;
  unsigned short* pM = pH + 524288;
  unsigned short* pL = pM + 524288;

  float* n2buf   = (float*)(ws + alloc(32768));
  int*   classes = (int*)  (ws + alloc(32768));
  unsigned short* Wp2H = (unsigned short*)(ws + alloc(3ull * 65536));
  unsigned short* Wp2M = Wp2H + 32768;
  unsigned short* Wp2L = Wp2M + 32768;
  unsigned short* Wp3H = (unsigned short*)(ws + alloc(3ull * 262144));
  unsigned short* Wp3M = Wp3H + 131072;
  unsigned short* Wp3L = Wp3M + 131072;
  float* zeros = (float*)(ws + alloc(1024));
  (void)ws_size; (void)in_sizes; (void)n_in; (void)out_size;

  // zero pads (borders of h1p/h2p must read as 0) + zeros buf
  hipMemsetAsync(zeros, 0, 1024, stream);
  hipMemsetAsync(h1pH, 0, 18939904, stream);
  hipMemsetAsync(h1pM, 0, 18939904, stream);
  hipMemsetAsync(h1pL, 0, 18939904, stream);
  hipMemsetAsync(h2pH, 0, 10616832, stream);
  hipMemsetAsync(h2pM, 0, 10616832, stream);
  hipMemsetAsync(h2pL, 0, 10616832, stream);

  k_wprep2<<<128, 256, 0, stream>>>(enc_w2, Wp2H, Wp2M, Wp2L);
  k_wprep3<<<512, 256, 0, stream>>>(enc_w3, Wp3H, Wp3M, Wp3L);

  k_conv1<<<8192, 256, 0, stream>>>(x, enc_w1, enc_b1, h1pH, h1pM, h1pL);
  k_conv2m<<<1024, 256, 0, stream>>>(h1pH, h1pM, h1pL, Wp2H, Wp2M, Wp2L,
                                     enc_b2, h2pH, h2pM, h2pL);
  k_conv3m<<<256, 256, 0, stream>>>(h2pH, h2pM, h2pL, Wp3H, Wp3M, Wp3L,
                                    enc_b3, h3);

  // fc: (256x8192)@(8192x512), k-split 8
  k_gemm<<<dim3(16, 4, 8), 256, 0, stream>>>(h3, fc_w, fcpart, zeros, 256, 512, 8192, 0);
  k_sumrelu<<<512, 256, 0, stream>>>(fcpart, fc_b, hfc, 131072, 511, 8);
  // ffc: (256x512)@(512x2048) + bias + relu
  k_gemm<<<dim3(16, 16, 1), 256, 0, stream>>>(hfc, ffc_w, pred, ffc_b, 256, 2048, 512, 2047);

  // VQ
  k_split3<<<2048, 256, 0, stream>>>(embeds, eH, eM, eL, 524288);
  k_split3<<<2048, 256, 0, stream>>>(pred, pH, pM, pL, 524288);
  k_norm2<<<32, 256, 0, stream>>>(embeds, n2buf);
  k_vqmfma<<<dim3(32, 16), 256, 0, stream>>>(pH, pM, pL, eH, eM, eL, n2buf, pbd, pbk);
  k_vqfinal2<<<256, 256, 0, stream>>>(pbd, pbk, classes);
  k_gather<<<2048, 256, 0, stream>>>(classes, embeds, collected);

  // dec_fc: (256x2048)@(2048x512), k-split 8
  k_gemm<<<dim3(16, 4, 8), 256, 0, stream>>>(collected, dec_fc_w, dfcpart, zeros, 256, 512, 2048, 0);
  k_sumrelu<<<512, 256, 0, stream>>>(dfcpart, dec_fc_b, hdfc, 131072, 511, 8);

  k_permW1<<<8192, 256, 0, stream>>>(dec_w1, W1p);
  k_permW2<<<2048, 256, 0, stream>>>(dec_w2, W2p);
  // dec1: (256x512)@(512x4096) -> d1out rows (b) cols (i*4+j)*256+c
  k_gemm<<<dim3(16, 32, 1), 256, 0, stream>>>(hdfc, W1p, d1out, dec_b1, 256, 4096, 512, 255);
  // dec2: (4096x256)@(256x2048) -> d2buf rows (b,i,j) cols (r*4+u)*128+o
  k_gemm<<<dim3(256, 16, 1), 256, 0, stream>>>(d1out, W2p, d2buf, dec_b2, 4096, 2048, 256, 127);
  // dec3 -> final output (no relu)
  k_dec3<<<4096, 256, 0, stream>>>(d2buf, dec_w3, dec_b3, outp);
}

// Round 6
// 562.479 us; speedup vs baseline: 13.5418x; 1.1065x over previous
//
#include <hip/hip_runtime.h>
#include <cfloat>

// =====================================================================
// VQ-VAE forward.
// R6: (1) k_vqmfma loop-swapped: pred rows A-resident, codes streamed as
// pre-packed B-frags -> no shuffles in hot loop (was 290 VALU-cyc epilogue
// per 230 MFMA-cyc tile). (2) All 5 dense GEMMs -> generic split-bf16 MFMA
// (k_mgemm): encoder NP=3 (argmin bit-stable), decoder NP=2 (1e-5 rel <<
// 2.5e-4 threshold). Producers emit split planes directly.
//
// conv_transpose (transpose_kernel=False) => flipped kernel:
//   out[4i+r, 4j+u, o] = sum_c in[i,j,c] * w[3-r, 3-u, c, o]
// Encoder convs: SAME pad = (1,1) -> padded split inputs.
// =====================================================================

typedef short bf16x8 __attribute__((ext_vector_type(8)));
typedef float f32x4 __attribute__((ext_vector_type(4)));
#define MFMA16(a, b, c) __builtin_amdgcn_mfma_f32_16x16x32_bf16(a, b, c, 0, 0, 0)

__device__ inline unsigned short f2bf(float x) {  // RNE, inputs finite
  unsigned u = __float_as_uint(x);
  u += 0x7fffu + ((u >> 16) & 1u);
  return (unsigned short)(u >> 16);
}
__device__ inline float bf2f(unsigned short h) {
  return __uint_as_float(((unsigned)h) << 16);
}
__device__ inline void split3v(float v, unsigned short& hb, unsigned short& mb,
                               unsigned short& lb) {
  hb = f2bf(v);
  float r1 = v - bf2f(hb);
  mb = f2bf(r1);
  lb = f2bf(r1 - bf2f(mb));
}

// ---------------- conv1: x(256,64,64,1) -> h1p split padded (256,34,34,32) ----
__global__ __launch_bounds__(256) void k_conv1(const float* __restrict__ x,
                                               const float* __restrict__ w,
                                               const float* __restrict__ bias,
                                               unsigned short* __restrict__ oH,
                                               unsigned short* __restrict__ oM,
                                               unsigned short* __restrict__ oL) {
  int b = blockIdx.x >> 5;          // 8192 blocks: (b, y)
  int y = blockIdx.x & 31;
  int t = threadIdx.x;
  int c = t & 31;
  int xg = t >> 5;                  // 0..7, 4 x-positions each
  float acc[4] = {0.f, 0.f, 0.f, 0.f};
  for (int dy = 0; dy < 4; ++dy) {
    int iy = 2 * y + dy - 1;
    if (iy < 0 || iy >= 64) continue;
    const float* xrow = x + ((size_t)b * 64 + iy) * 64;
    for (int dx = 0; dx < 4; ++dx) {
      float wv = w[(dy * 4 + dx) * 32 + c];
#pragma unroll
      for (int i = 0; i < 4; ++i) {
        int ix = 8 * xg + 2 * i + dx - 1;
        float v = (ix >= 0 && ix < 64) ? xrow[ix] : 0.f;
        acc[i] = fmaf(v, wv, acc[i]);
      }
    }
  }
  float bv = bias[c];
#pragma unroll
  for (int i = 0; i < 4; ++i) {
    float v = acc[i] + bv;
    v = v > 0.f ? v : 0.f;
    unsigned short hb, mb, lb;
    split3v(v, hb, mb, lb);
    size_t o = ((size_t)(b * 34 + y + 1) * 34 + (4 * xg + i + 1)) * 32 + c;
    oH[o] = hb; oM[o] = mb; oL[o] = lb;
  }
}

// ---------------- conv weight prep (unchanged from R5) ----------------
__global__ __launch_bounds__(256) void k_wprep2(const float* __restrict__ w,
                                                unsigned short* __restrict__ H,
                                                unsigned short* __restrict__ M,
                                                unsigned short* __restrict__ L) {
  int idx = blockIdx.x * 256 + threadIdx.x;   // 32768
  int j = idx & 7, lane = (idx >> 3) & 63, nt = (idx >> 9) & 3, s = idx >> 11;
  int ci = ((lane >> 4) << 3) + j, co = (nt << 4) + (lane & 15);
  unsigned short hb, mb, lb;
  split3v(w[(s * 32 + ci) * 64 + co], hb, mb, lb);
  H[idx] = hb; M[idx] = mb; L[idx] = lb;
}
__global__ __launch_bounds__(256) void k_wprep3(const float* __restrict__ w,
                                                unsigned short* __restrict__ H,
                                                unsigned short* __restrict__ M,
                                                unsigned short* __restrict__ L) {
  int idx = blockIdx.x * 256 + threadIdx.x;   // 131072
  int j = idx & 7, lane = (idx >> 3) & 63, ks = (idx >> 9) & 1;
  int nt = (idx >> 10) & 3, ch = (idx >> 12) & 1, s = idx >> 13;
  int ci = ks * 32 + ((lane >> 4) << 3) + j;
  int co = ch * 64 + (nt << 4) + (lane & 15);
  unsigned short hb, mb, lb;
  split3v(w[(s * 64 + ci) * 128 + co], hb, mb, lb);
  H[idx] = hb; M[idx] = mb; L[idx] = lb;
}

// ---------------- conv2 MFMA (unchanged from R5) ----------------
__global__ __launch_bounds__(256) void k_conv2m(
    const unsigned short* __restrict__ aH, const unsigned short* __restrict__ aM,
    const unsigned short* __restrict__ aL, const unsigned short* __restrict__ wH,
    const unsigned short* __restrict__ wM, const unsigned short* __restrict__ wL,
    const float* __restrict__ bias, unsigned short* __restrict__ oH,
    unsigned short* __restrict__ oM, unsigned short* __restrict__ oL) {
  int t = threadIdx.x;
  int wave = t >> 6, lane = t & 63;
  int l15 = lane & 15, quad = lane >> 4;
  int m0 = blockIdx.x * 64 + wave * 16;     // 1024 blocks
  int p = m0 + l15;
  int b = p >> 8, y = (p >> 4) & 15, x = p & 15;
  f32x4 acc[4] = {};
  for (int s = 0; s < 16; ++s) {
    int dy = s >> 2, dx = s & 3;
    size_t aoff = ((size_t)(b * 34 + 2 * y + dy) * 34 + (2 * x + dx)) * 32 + quad * 8;
    bf16x8 ah = *(const bf16x8*)(aH + aoff);
    bf16x8 am = *(const bf16x8*)(aM + aoff);
    bf16x8 al = *(const bf16x8*)(aL + aoff);
#pragma unroll
    for (int nt = 0; nt < 4; ++nt) {
      size_t woff = ((size_t)(s * 4 + nt) * 64 + lane) * 8;
      bf16x8 bh = *(const bf16x8*)(wH + woff);
      bf16x8 bm = *(const bf16x8*)(wM + woff);
      bf16x8 bl = *(const bf16x8*)(wL + woff);
      acc[nt] = MFMA16(am, bm, acc[nt]);
      acc[nt] = MFMA16(ah, bl, acc[nt]);
      acc[nt] = MFMA16(al, bh, acc[nt]);
      acc[nt] = MFMA16(ah, bm, acc[nt]);
      acc[nt] = MFMA16(am, bh, acc[nt]);
      acc[nt] = MFMA16(ah, bh, acc[nt]);
    }
  }
#pragma unroll
  for (int r = 0; r < 4; ++r) {
    int pp = m0 + quad * 4 + r;
    int b2 = pp >> 8, yo = (pp >> 4) & 15, xo = pp & 15;
    size_t obase = ((size_t)(b2 * 18 + yo + 1) * 18 + (xo + 1)) * 64;
#pragma unroll
    for (int nt = 0; nt < 4; ++nt) {
      int co = nt * 16 + l15;
      float v = acc[nt][r] + bias[co];
      v = v > 0.f ? v : 0.f;
      unsigned short hb, mb, lb;
      split3v(v, hb, mb, lb);
      oH[obase + co] = hb; oM[obase + co] = mb; oL[obase + co] = lb;
    }
  }
}

// ---------------- conv3 MFMA: h2p -> h3 SPLIT planes (16384,128) -------------
__global__ __launch_bounds__(256) void k_conv3m(
    const unsigned short* __restrict__ aH, const unsigned short* __restrict__ aM,
    const unsigned short* __restrict__ aL, const unsigned short* __restrict__ wH,
    const unsigned short* __restrict__ wM, const unsigned short* __restrict__ wL,
    const float* __restrict__ bias, unsigned short* __restrict__ oH,
    unsigned short* __restrict__ oM, unsigned short* __restrict__ oL) {
  int t = threadIdx.x;
  int wave = t >> 6, lane = t & 63;
  int l15 = lane & 15, quad = lane >> 4;
  int pg = wave >> 1, ch = wave & 1;
  int m0 = blockIdx.x * 64 + pg * 32;       // 256 blocks
  f32x4 acc[2][4] = {};
  for (int s = 0; s < 16; ++s) {
    int dy = s >> 2, dx = s & 3;
    bf16x8 ah[2][2], am[2][2], al[2][2];
#pragma unroll
    for (int mt = 0; mt < 2; ++mt) {
      int p = m0 + mt * 16 + l15;
      int b = p >> 6, y = (p >> 3) & 7, x = p & 7;
      size_t base = ((size_t)(b * 18 + 2 * y + dy) * 18 + (2 * x + dx)) * 64 + quad * 8;
#pragma unroll
      for (int ks = 0; ks < 2; ++ks) {
        ah[mt][ks] = *(const bf16x8*)(aH + base + ks * 32);
        am[mt][ks] = *(const bf16x8*)(aM + base + ks * 32);
        al[mt][ks] = *(const bf16x8*)(aL + base + ks * 32);
      }
    }
#pragma unroll
    for (int nt = 0; nt < 4; ++nt) {
#pragma unroll
      for (int ks = 0; ks < 2; ++ks) {
        size_t woff = ((size_t)((((s * 2 + ch) * 4 + nt) * 2 + ks) * 64 + lane)) * 8;
        bf16x8 bh = *(const bf16x8*)(wH + woff);
        bf16x8 bm = *(const bf16x8*)(wM + woff);
        bf16x8 bl = *(const bf16x8*)(wL + woff);
#pragma unroll
        for (int mt = 0; mt < 2; ++mt) {
          acc[mt][nt] = MFMA16(am[mt][ks], bm, acc[mt][nt]);
          acc[mt][nt] = MFMA16(ah[mt][ks], bl, acc[mt][nt]);
          acc[mt][nt] = MFMA16(al[mt][ks], bh, acc[mt][nt]);
          acc[mt][nt] = MFMA16(ah[mt][ks], bm, acc[mt][nt]);
          acc[mt][nt] = MFMA16(am[mt][ks], bh, acc[mt][nt]);
          acc[mt][nt] = MFMA16(ah[mt][ks], bh, acc[mt][nt]);
        }
      }
    }
  }
#pragma unroll
  for (int mt = 0; mt < 2; ++mt)
#pragma unroll
    for (int nt = 0; nt < 4; ++nt) {
      int co = ch * 64 + nt * 16 + l15;
      float bv = bias[co];
#pragma unroll
      for (int r = 0; r < 4; ++r) {
        int pp = m0 + mt * 16 + quad * 4 + r;
        float v = acc[mt][nt][r] + bv;
        v = v > 0.f ? v : 0.f;
        unsigned short hb, mb, lb;
        split3v(v, hb, mb, lb);
        size_t o = (size_t)pp * 128 + co;
        oH[o] = hb; oM[o] = mb; oL[o] = lb;
      }
    }
}

// ---------------- generic B-frag pack: w(KxN fp32) -> Bp[s][kt][ntg][512] ----
__global__ __launch_bounds__(256) void k_bprep(const float* __restrict__ w,
                                               unsigned short* __restrict__ Bp,
                                               int K, int N, int NP) {
  int idx = blockIdx.x * 256 + threadIdx.x;
  if (idx >= NP * K * N) return;
  int j = idx & 7, lane = (idx >> 3) & 63;
  int f = idx >> 9;
  int NT = N >> 4, KT = K >> 5;
  int ntg = f % NT; f /= NT;
  int kt = f % KT; int s = f / KT;
  int k = kt * 32 + ((lane >> 4) << 3) + j;
  int n = ntg * 16 + (lane & 15);
  unsigned short hb, mb, lb;
  split3v(w[(size_t)k * N + n], hb, mb, lb);
  Bp[idx] = s == 0 ? hb : (s == 1 ? mb : lb);
}

// ---------------- generic split-bf16 MFMA GEMM ----------------
// A: NP split planes, row-major MxK. Bp: packed frags. Wave: 16m x (16*NTW)n.
// S = gridDim.z k-split: S==1 -> bias+relu fp32 out; S>1 -> fp32 partials.
template <int NP, int NTW>
__global__ __launch_bounds__(256) void k_mgemm(
    const unsigned short* __restrict__ A0, const unsigned short* __restrict__ A1,
    const unsigned short* __restrict__ A2, const unsigned short* __restrict__ Bp,
    float* __restrict__ C, const float* __restrict__ bias,
    int M, int N, int K, int bmask) {
  int S = gridDim.z;
  int Kc = K / S;
  int t = threadIdx.x;
  int wave = t >> 6, lane = t & 63;
  int l15 = lane & 15, quad = lane >> 4;
  int m0 = blockIdx.x * 64 + wave * 16;
  int n0 = blockIdx.y * (16 * NTW);
  int KT = K >> 5, NT = N >> 4;
  int kt0 = (blockIdx.z * Kc) >> 5;
  int ktn = Kc >> 5;
  size_t sstride = (size_t)KT * NT * 512;
  const unsigned short* arow0 = A0 + (size_t)(m0 + l15) * K + quad * 8;
  const unsigned short* arow1 = A1 + (size_t)(m0 + l15) * K + quad * 8;
  const unsigned short* arow2 = nullptr;
  if constexpr (NP == 3) arow2 = A2 + (size_t)(m0 + l15) * K + quad * 8;
  f32x4 acc[NTW] = {};
  for (int kt = kt0; kt < kt0 + ktn; ++kt) {
    bf16x8 ah = *(const bf16x8*)(arow0 + kt * 32);
    bf16x8 am = *(const bf16x8*)(arow1 + kt * 32);
    bf16x8 al;
    if constexpr (NP == 3) al = *(const bf16x8*)(arow2 + kt * 32);
    const unsigned short* bbase =
        Bp + ((size_t)kt * NT + (n0 >> 4)) * 512 + lane * 8;
#pragma unroll
    for (int nt = 0; nt < NTW; ++nt) {
      const unsigned short* bp = bbase + nt * 512;
      bf16x8 bh = *(const bf16x8*)(bp);
      bf16x8 bm = *(const bf16x8*)(bp + sstride);
      if constexpr (NP == 3) {
        bf16x8 bl = *(const bf16x8*)(bp + 2 * sstride);
        acc[nt] = MFMA16(am, bm, acc[nt]);
        acc[nt] = MFMA16(ah, bl, acc[nt]);
        acc[nt] = MFMA16(al, bh, acc[nt]);
        acc[nt] = MFMA16(ah, bm, acc[nt]);
        acc[nt] = MFMA16(am, bh, acc[nt]);
        acc[nt] = MFMA16(ah, bh, acc[nt]);
      } else {
        acc[nt] = MFMA16(ah, bm, acc[nt]);
        acc[nt] = MFMA16(am, bh, acc[nt]);
        acc[nt] = MFMA16(ah, bh, acc[nt]);
      }
    }
  }
  if (S == 1) {
#pragma unroll
    for (int nt = 0; nt < NTW; ++nt) {
      int n = n0 + nt * 16 + l15;
      float bv = bias[n & bmask];
#pragma unroll
      for (int r = 0; r < 4; ++r) {
        int m = m0 + quad * 4 + r;
        float v = acc[nt][r] + bv;
        C[(size_t)m * N + n] = v > 0.f ? v : 0.f;
      }
    }
  } else {
    float* Cp = C + (size_t)blockIdx.z * M * N;
#pragma unroll
    for (int nt = 0; nt < NTW; ++nt) {
      int n = n0 + nt * 16 + l15;
#pragma unroll
      for (int r = 0; r < 4; ++r) {
        int m = m0 + quad * 4 + r;
        Cp[(size_t)m * N + n] = acc[nt][r];
      }
    }
  }
}

// sum k-split partials + bias + relu -> split planes (NPOUT = 2 or 3)
template <int NPOUT>
__global__ __launch_bounds__(256) void k_sumrelu3(
    const float* __restrict__ part, const float* __restrict__ bias,
    unsigned short* __restrict__ oH, unsigned short* __restrict__ oM,
    unsigned short* __restrict__ oL, int MN, int bmask, int S) {
  int idx = blockIdx.x * 256 + threadIdx.x;
  float s = 0.f;
  for (int z = 0; z < S; ++z) s += part[(size_t)z * MN + idx];
  s += bias[idx & bmask];
  s = s > 0.f ? s : 0.f;
  unsigned short hb = f2bf(s);
  float r1 = s - bf2f(hb);
  unsigned short mb = f2bf(r1);
  oH[idx] = hb; oM[idx] = mb;
  if constexpr (NPOUT == 3) oL[idx] = f2bf(r1 - bf2f(mb));
}

// ---------------- VQ ----------------
__global__ __launch_bounds__(256) void k_norm2(const float* __restrict__ e,
                                               float* __restrict__ n2) {
  int k = blockIdx.x * 256 + threadIdx.x;
  const float4* p = (const float4*)(e + (size_t)k * 64);
  float s0 = 0, s1 = 0, s2 = 0, s3 = 0;
#pragma unroll
  for (int j = 0; j < 16; ++j) {
    float4 v = p[j];
    s0 = fmaf(v.x, v.x, s0); s1 = fmaf(v.y, v.y, s1);
    s2 = fmaf(v.z, v.z, s2); s3 = fmaf(v.w, v.w, s3);
  }
  n2[k] = (s0 + s1) + (s2 + s3);
}

// embeds -> packed B-frags eB[kt][ks][nt][s][512] (3 splits)
__global__ __launch_bounds__(256) void k_eprep(const float* __restrict__ e,
                                               unsigned short* __restrict__ Bp) {
  int idx = blockIdx.x * 256 + threadIdx.x;   // 1,572,864
  int j = idx & 7, lane = (idx >> 3) & 63;
  int f = idx >> 9;
  int s = f % 3; f /= 3;
  int nt = f % 4; f /= 4;
  int ks = f % 2; int kt = f / 2;
  int code = kt * 64 + nt * 16 + (lane & 15);
  int k = ks * 32 + ((lane >> 4) << 3) + j;
  unsigned short hb, mb, lb;
  split3v(e[(size_t)code * 64 + k], hb, mb, lb);
  Bp[idx] = s == 0 ? hb : (s == 1 ? mb : lb);
}

// k_vqmfma2: pred rows A-resident, codes streamed. grid (128, 4), block 256.
// Per 64-code tile: 24 B loads + 48 MFMA + 64 VALU (no shuffles in loop).
// Final cross-lane lex (d,k) reduce once per wave.
__global__ __launch_bounds__(256) void k_vqmfma2(
    const unsigned short* __restrict__ pH, const unsigned short* __restrict__ pM,
    const unsigned short* __restrict__ pL, const unsigned short* __restrict__ eB,
    const float* __restrict__ n2, float* __restrict__ pbd, int* __restrict__ pbk) {
  int t = threadIdx.x;
  int wave = t >> 6, lane = t & 63;
  int l15 = lane & 15, quad = lane >> 4;
  int m0 = blockIdx.x * 64 + wave * 16;
  int z = blockIdx.y;
  size_t arow = (size_t)(m0 + l15) * 64 + quad * 8;
  bf16x8 ah[2], am[2], al[2];
#pragma unroll
  for (int ks = 0; ks < 2; ++ks) {
    ah[ks] = *(const bf16x8*)(pH + arow + ks * 32);
    am[ks] = *(const bf16x8*)(pM + arow + ks * 32);
    al[ks] = *(const bf16x8*)(pL + arow + ks * 32);
  }
  float bd[4] = {FLT_MAX, FLT_MAX, FLT_MAX, FLT_MAX};
  int bk[4] = {0, 0, 0, 0};
  for (int kt = z * 32; kt < z * 32 + 32; ++kt) {
    const unsigned short* bb = eB + (size_t)kt * 12288 + lane * 8;
    f32x4 acc[4] = {};
#pragma unroll
    for (int ks = 0; ks < 2; ++ks)
#pragma unroll
      for (int nt = 0; nt < 4; ++nt) {
        const unsigned short* bp = bb + ((ks * 4 + nt) * 3) * 512;
        bf16x8 bh = *(const bf16x8*)(bp);
        bf16x8 bm = *(const bf16x8*)(bp + 512);
        bf16x8 bl = *(const bf16x8*)(bp + 1024);
        acc[nt] = MFMA16(am[ks], bm, acc[nt]);
        acc[nt] = MFMA16(ah[ks], bl, acc[nt]);
        acc[nt] = MFMA16(al[ks], bh, acc[nt]);
        acc[nt] = MFMA16(ah[ks], bm, acc[nt]);
        acc[nt] = MFMA16(am[ks], bh, acc[nt]);
        acc[nt] = MFMA16(ah[ks], bh, acc[nt]);
      }
    int cb = kt * 64;
#pragma unroll
    for (int nt = 0; nt < 4; ++nt) {
      int code = cb + nt * 16 + l15;
      float nv = n2[code];
#pragma unroll
      for (int r = 0; r < 4; ++r) {
        float d = fmaf(-2.f, acc[nt][r], nv);
        if (d < bd[r]) { bd[r] = d; bk[r] = code; }  // ascending code order
      }
    }
  }
#pragma unroll
  for (int r = 0; r < 4; ++r) {
#pragma unroll
    for (int s = 1; s < 16; s <<= 1) {
      float od = __shfl_xor(bd[r], s);
      int ok = __shfl_xor(bk[r], s);
      if (od < bd[r] || (od == bd[r] && ok < bk[r])) { bd[r] = od; bk[r] = ok; }
    }
  }
  if (l15 == 0) {
#pragma unroll
    for (int r = 0; r < 4; ++r) {
      pbd[(size_t)z * 8192 + m0 + quad * 4 + r] = bd[r];
      pbk[(size_t)z * 8192 + m0 + quad * 4 + r] = bk[r];
    }
  }
}

// reduce 4 k-split groups per row -> classes (8192 rows)
__global__ __launch_bounds__(256) void k_vqfinal3(const float* __restrict__ pbd,
                                                  const int* __restrict__ pbk,
                                                  int* __restrict__ classes) {
  int m = blockIdx.x * 256 + threadIdx.x;   // 32 blocks
  float bd = pbd[m]; int bk = pbk[m];
#pragma unroll
  for (int z = 1; z < 4; ++z) {
    float d = pbd[(size_t)z * 8192 + m]; int k = pbk[(size_t)z * 8192 + m];
    if (d < bd || (d == bd && k < bk)) { bd = d; bk = k; }
  }
  classes[m] = bk;
}

// gather -> 2-plane split collected
__global__ __launch_bounds__(256) void k_gather2(const int* __restrict__ classes,
                                                 const float* __restrict__ embeds,
                                                 unsigned short* __restrict__ cH,
                                                 unsigned short* __restrict__ cM) {
  int idx = blockIdx.x * 256 + threadIdx.x;
  float v = embeds[(size_t)classes[idx >> 6] * 64 + (idx & 63)];
  unsigned short hb = f2bf(v);
  cH[idx] = hb;
  cM[idx] = f2bf(v - bf2f(hb));
}

// ---------------- decoder weight permutes (spatial flip) ----------------
__global__ __launch_bounds__(256) void k_permW1(const float* __restrict__ w,
                                                float* __restrict__ wp) {
  int idx = blockIdx.x * 256 + threadIdx.x; // 2,097,152
  int cc = idx >> 12, n = idx & 4095;
  int ru = n >> 8, o = n & 255, r = ru >> 2, u = ru & 3;
  wp[idx] = w[((size_t)((3 - r) * 4 + (3 - u)) * 512 + cc) * 256 + o];
}
__global__ __launch_bounds__(256) void k_permW2(const float* __restrict__ w,
                                                float* __restrict__ wp) {
  int idx = blockIdx.x * 256 + threadIdx.x; // 524,288
  int cc = idx >> 11, n = idx & 2047;
  int ru = n >> 7, o = n & 127, r = ru >> 2, u = ru & 3;
  wp[idx] = w[((size_t)((3 - r) * 4 + (3 - u)) * 256 + cc) * 128 + o];
}

// ---------------- dec3: d2buf(permuted) -> out(256,64,64), +bias, no relu ----
__global__ __launch_bounds__(256) void k_dec3(const float* __restrict__ d2buf,
                                              const float* __restrict__ w3,
                                              const float* __restrict__ b3,
                                              float* __restrict__ out) {
  __shared__ float sx[16 * 129];
  __shared__ float wT[128 * 16];
  int b = blockIdx.x >> 4;          // 4096 blocks: (b, y_in)
  int y = blockIdx.x & 15;
  int t = threadIdx.x;
#pragma unroll
  for (int j = 0; j < 8; ++j) {
    int idx = t + j * 256;          // 2048
    int xx = idx >> 7, c = idx & 127;
    size_t m2 = ((size_t)b * 4 + (y >> 2)) * 4 + (xx >> 2);
    sx[xx * 129 + c] = d2buf[m2 * 2048 + ((y & 3) * 4 + (xx & 3)) * 128 + c];
  }
#pragma unroll
  for (int j = 0; j < 8; ++j) {
    int idx = t + j * 256;
    int c = idx >> 4, ru = idx & 15;
    int R = ru >> 2, U = ru & 3;
    wT[c * 16 + ru] = w3[((3 - R) * 4 + (3 - U)) * 128 + c];
  }
  __syncthreads();
  int xx = t >> 4, ru = t & 15;
  float a0 = 0, a1 = 0, a2 = 0, a3 = 0;
#pragma unroll 8
  for (int c = 0; c < 128; c += 4) {
    a0 = fmaf(sx[xx * 129 + c + 0], wT[(c + 0) * 16 + ru], a0);
    a1 = fmaf(sx[xx * 129 + c + 1], wT[(c + 1) * 16 + ru], a1);
    a2 = fmaf(sx[xx * 129 + c + 2], wT[(c + 2) * 16 + ru], a2);
    a3 = fmaf(sx[xx * 129 + c + 3], wT[(c + 3) * 16 + ru], a3);
  }
  float acc = (a0 + a1) + (a2 + a3) + b3[0];
  int R = ru >> 2, U = ru & 3;
  out[((size_t)b * 64 + 4 * y + R) * 64 + 4 * xx + U] = acc;
}

// =====================================================================
extern "C" void kernel_launch(void* const* d_in, const int* in_sizes, int n_in,
                              void* d_out, int out_size, void* d_ws, size_t ws_size,
                              hipStream_t stream) {
  const float* x        = (const float*)d_in[0];
  const float* enc_w1   = (const float*)d_in[1];
  const float* enc_b1   = (const float*)d_in[2];
  const float* enc_w2   = (const float*)d_in[3];
  const float* enc_b2   = (const float*)d_in[4];
  const float* enc_w3   = (const float*)d_in[5];
  const float* enc_b3   = (const float*)d_in[6];
  const float* fc_w     = (const float*)d_in[7];
  const float* fc_b     = (const float*)d_in[8];
  const float* ffc_w    = (const float*)d_in[9];
  const float* ffc_b    = (const float*)d_in[10];
  const float* embeds   = (const float*)d_in[11];
  const float* dec_fc_w = (const float*)d_in[12];
  const float* dec_fc_b = (const float*)d_in[13];
  const float* dec_w1   = (const float*)d_in[14];
  const float* dec_b1   = (const float*)d_in[15];
  const float* dec_w2   = (const float*)d_in[16];
  const float* dec_b2   = (const float*)d_in[17];
  const float* dec_w3   = (const float*)d_in[18];
  const float* dec_b3   = (const float*)d_in[19];
  float* outp = (float*)d_out;

  char* ws = (char*)d_ws;
  size_t off = 0;
  auto alloc = [&](size_t bytes) { size_t r = off; off = (off + bytes + 255) & ~(size_t)255; return r; };

  // ---- Region A (57.15 MB): phase1 h1p splits; phase2 decoder/partials ----
  size_t RA = alloc(57147392);
  unsigned short* h1pH = (unsigned short*)(ws + RA);
  unsigned short* h1pM = (unsigned short*)(ws + RA + 18939904);
  unsigned short* h1pL = (unsigned short*)(ws + RA + 37879808);
  float* d2buf            = (float*)(ws + RA);                    // 33.55 MB
  float* partials         = (float*)(ws + RA + 33554432);         // 8.39 MB
  unsigned short* Bp_d1   = (unsigned short*)(ws + RA + 41943040);// 8.39 MB
  unsigned short* d1H     = (unsigned short*)(ws + RA + 50331648);
  unsigned short* d1M     = (unsigned short*)(ws + RA + 52428800);
  unsigned short* hdH     = (unsigned short*)(ws + RA + 54525952);
  unsigned short* hdM     = (unsigned short*)(ws + RA + 54788096);
  unsigned short* cH      = (unsigned short*)(ws + RA + 55050240);
  unsigned short* cM      = (unsigned short*)(ws + RA + 56098816);

  // ---- Region B (31.85 MB): phase1 h2p splits; phase2 Bp_fc/eB/pred/W1p ----
  size_t RB = alloc(31850496);
  unsigned short* h2pH = (unsigned short*)(ws + RB);
  unsigned short* h2pM = (unsigned short*)(ws + RB + 10616832);
  unsigned short* h2pL = (unsigned short*)(ws + RB + 21233664);
  unsigned short* Bp_fc = (unsigned short*)(ws + RB);             // 25.17 MB
  unsigned short* eB    = (unsigned short*)(ws + RB + 25165824);  // 3.15 MB
  unsigned short* pH    = (unsigned short*)(ws + RB + 28311552);
  unsigned short* pM    = (unsigned short*)(ws + RB + 29360128);
  unsigned short* pL    = (unsigned short*)(ws + RB + 30408704);
  float* W1p            = (float*)(ws + RB);                      // 8.39 MB after fc

  // ---- Region C (12.58 MB): phase1 h3 splits; phase2 Bp_ffc/hfc/Bp_dfc/... ----
  size_t RC = alloc(12582912);
  unsigned short* h3H = (unsigned short*)(ws + RC);
  unsigned short* h3M = (unsigned short*)(ws + RC + 4194304);
  unsigned short* h3L = (unsigned short*)(ws + RC + 8388608);
  unsigned short* Bp_ffc = (unsigned short*)(ws + RC);            // 6.29 MB
  unsigned short* hfcH   = (unsigned short*)(ws + RC + 6291456);
  unsigned short* hfcM   = (unsigned short*)(ws + RC + 6553600);
  unsigned short* hfcL   = (unsigned short*)(ws + RC + 6815744);
  unsigned short* Bp_dfc = (unsigned short*)(ws + RC);            // 4.19 MB (after ffc)
  float* W2p             = (float*)(ws + RC);                     // 2.10 MB (after dec_fc)
  unsigned short* Bp_d2  = (unsigned short*)(ws + RC + 4194304);  // 2.10 MB

  // ---- dedicated small ----
  float* n2buf   = (float*)(ws + alloc(32768));
  int*   classes = (int*)  (ws + alloc(32768));
  float* pbd     = (float*)(ws + alloc(131072));
  int*   pbk     = (int*)  (ws + alloc(131072));
  unsigned short* Wp2H = (unsigned short*)(ws + alloc(196608));
  unsigned short* Wp2M = Wp2H + 32768;
  unsigned short* Wp2L = Wp2M + 32768;
  unsigned short* Wp3H = (unsigned short*)(ws + alloc(786432));
  unsigned short* Wp3M = Wp3H + 131072;
  unsigned short* Wp3L = Wp3M + 131072;
  (void)ws_size; (void)in_sizes; (void)n_in; (void)out_size;

  // zero the padded conv inputs (planes are contiguous per region)
  hipMemsetAsync(h1pH, 0, 56819712, stream);
  hipMemsetAsync(h2pH, 0, 31850496, stream);

  k_wprep2<<<128, 256, 0, stream>>>(enc_w2, Wp2H, Wp2M, Wp2L);
  k_wprep3<<<512, 256, 0, stream>>>(enc_w3, Wp3H, Wp3M, Wp3L);

  k_conv1<<<8192, 256, 0, stream>>>(x, enc_w1, enc_b1, h1pH, h1pM, h1pL);
  k_conv2m<<<1024, 256, 0, stream>>>(h1pH, h1pM, h1pL, Wp2H, Wp2M, Wp2L,
                                     enc_b2, h2pH, h2pM, h2pL);
  k_conv3m<<<256, 256, 0, stream>>>(h2pH, h2pM, h2pL, Wp3H, Wp3M, Wp3L,
                                    enc_b3, h3H, h3M, h3L);

  // fc: (256x512) = h3(256x8192) @ fc_w, NP=3, S=16
  k_bprep<<<49152, 256, 0, stream>>>(fc_w, Bp_fc, 8192, 512, 3);
  k_eprep<<<6144, 256, 0, stream>>>(embeds, eB);
  k_norm2<<<32, 256, 0, stream>>>(embeds, n2buf);
  k_mgemm<3, 4><<<dim3(4, 8, 16), 256, 0, stream>>>(
      h3H, h3M, h3L, Bp_fc, partials, fc_b, 256, 512, 8192, 511);
  k_bprep<<<12288, 256, 0, stream>>>(ffc_w, Bp_ffc, 512, 2048, 3);
  k_sumrelu3<3><<<512, 256, 0, stream>>>(partials, fc_b, hfcH, hfcM, hfcL,
                                         131072, 511, 16);
  // ffc: (256x2048), NP=3, S=4 -> pred splits
  k_mgemm<3, 4><<<dim3(4, 32, 4), 256, 0, stream>>>(
      hfcH, hfcM, hfcL, Bp_ffc, partials, ffc_b, 256, 2048, 512, 2047);
  k_bprep<<<8192, 256, 0, stream>>>(dec_fc_w, Bp_dfc, 2048, 512, 2);
  k_sumrelu3<3><<<2048, 256, 0, stream>>>(partials, ffc_b, pH, pM, pL,
                                          524288, 2047, 4);

  // VQ
  k_vqmfma2<<<dim3(128, 4), 256, 0, stream>>>(pH, pM, pL, eB, n2buf, pbd, pbk);
  k_vqfinal3<<<32, 256, 0, stream>>>(pbd, pbk, classes);
  k_gather2<<<2048, 256, 0, stream>>>(classes, embeds, cH, cM);

  // dec_fc: (256x512), NP=2, S=16
  k_mgemm<2, 4><<<dim3(4, 8, 16), 256, 0, stream>>>(
      cH, cM, nullptr, Bp_dfc, partials, dec_fc_b, 256, 512, 2048, 511);
  k_sumrelu3<2><<<512, 256, 0, stream>>>(partials, dec_fc_b, hdH, hdM, nullptr,
                                         131072, 511, 16);

  // dec1: (256x4096), NP=2, S=2
  k_permW1<<<8192, 256, 0, stream>>>(dec_w1, W1p);
  k_bprep<<<16384, 256, 0, stream>>>(W1p, Bp_d1, 512, 4096, 2);
  k_mgemm<2, 4><<<dim3(4, 64, 2), 256, 0, stream>>>(
      hdH, hdM, nullptr, Bp_d1, partials, dec_b1, 256, 4096, 512, 255);
  k_sumrelu3<2><<<4096, 256, 0, stream>>>(partials, dec_b1, d1H, d1M, nullptr,
                                          1048576, 255, 2);

  // dec2: (4096x2048), NP=2, S=1 -> fp32 d2buf (+bias+relu)
  k_permW2<<<2048, 256, 0, stream>>>(dec_w2, W2p);
  k_bprep<<<4096, 256, 0, stream>>>(W2p, Bp_d2, 256, 2048, 2);
  k_mgemm<2, 8><<<dim3(64, 16, 1), 256, 0, stream>>>(
      d1H, d1M, nullptr, Bp_d2, d2buf, dec_b2, 4096, 2048, 256, 127);

  // dec3 -> final output (no relu)
  k_dec3<<<4096, 256, 0, stream>>>(d2buf, dec_w3, dec_b3, outp);
}

// Round 7
// 526.100 us; speedup vs baseline: 14.4782x; 1.0691x over previous
//
#include <hip/hip_runtime.h>
#include <cfloat>

// =====================================================================
// VQ-VAE forward.
// R7: (1) k_vqmfma: 32 m-rows/wave (2 A-sets resident) -> L2 intensity
// 5.3 -> 10.6 FLOP/B (R6 measured it L2-BW-bound at 71us). (2) decoder
// weight flip folded into B-frag pack (k_bprep_ct). (3) border-only
// zeroing instead of 88.7 MB full-plane memsets. (4) vqfinal+gather fused.
//
// conv_transpose (transpose_kernel=False) => flipped kernel:
//   out[4i+r, 4j+u, o] = sum_c in[i,j,c] * w[3-r, 3-u, c, o]
// Encoder convs: SAME pad = (1,1) -> padded split inputs.
// Precision: NP=3 split (6 MFMA products) ~= fp32 (2^-25 rel) for
// everything feeding the argmin; NP=2 (3 products, ~1e-5 rel) for the
// decoder (threshold 2.5e-4).
// =====================================================================

typedef short bf16x8 __attribute__((ext_vector_type(8)));
typedef float f32x4 __attribute__((ext_vector_type(4)));
#define MFMA16(a, b, c) __builtin_amdgcn_mfma_f32_16x16x32_bf16(a, b, c, 0, 0, 0)

__device__ inline unsigned short f2bf(float x) {  // RNE, inputs finite
  unsigned u = __float_as_uint(x);
  u += 0x7fffu + ((u >> 16) & 1u);
  return (unsigned short)(u >> 16);
}
__device__ inline float bf2f(unsigned short h) {
  return __uint_as_float(((unsigned)h) << 16);
}
__device__ inline void split3v(float v, unsigned short& hb, unsigned short& mb,
                               unsigned short& lb) {
  hb = f2bf(v);
  float r1 = v - bf2f(hb);
  mb = f2bf(r1);
  lb = f2bf(r1 - bf2f(mb));
}

// ---------------- border zero: pads of h1p/h2p (3 planes each) ---------------
// grid: (C/256*256 over b*c, 4W-4 border px, 3 planes)
__global__ __launch_bounds__(256) void k_zborder(unsigned short* __restrict__ base,
                                                 int W, size_t planeElems,
                                                 int logC) {
  int bc = blockIdx.x * 256 + threadIdx.x;
  int C = 1 << logC;
  int b = bc >> logC, c = bc & (C - 1);
  int i = blockIdx.y, row, col;
  if (i < W) { row = 0; col = i; }
  else if (i < 2 * W) { row = W - 1; col = i - W; }
  else { int j = i - 2 * W; row = 1 + (j >> 1); col = (j & 1) ? W - 1 : 0; }
  base[blockIdx.z * planeElems + ((size_t)(b * W + row) * W + col) * C + c] = 0;
}

// ---------------- conv1: x(256,64,64,1) -> h1p split padded (256,34,34,32) ----
__global__ __launch_bounds__(256) void k_conv1(const float* __restrict__ x,
                                               const float* __restrict__ w,
                                               const float* __restrict__ bias,
                                               unsigned short* __restrict__ oH,
                                               unsigned short* __restrict__ oM,
                                               unsigned short* __restrict__ oL) {
  int b = blockIdx.x >> 5;          // 8192 blocks: (b, y)
  int y = blockIdx.x & 31;
  int t = threadIdx.x;
  int c = t & 31;
  int xg = t >> 5;                  // 0..7, 4 x-positions each
  float acc[4] = {0.f, 0.f, 0.f, 0.f};
  for (int dy = 0; dy < 4; ++dy) {
    int iy = 2 * y + dy - 1;
    if (iy < 0 || iy >= 64) continue;
    const float* xrow = x + ((size_t)b * 64 + iy) * 64;
    for (int dx = 0; dx < 4; ++dx) {
      float wv = w[(dy * 4 + dx) * 32 + c];
#pragma unroll
      for (int i = 0; i < 4; ++i) {
        int ix = 8 * xg + 2 * i + dx - 1;
        float v = (ix >= 0 && ix < 64) ? xrow[ix] : 0.f;
        acc[i] = fmaf(v, wv, acc[i]);
      }
    }
  }
  float bv = bias[c];
#pragma unroll
  for (int i = 0; i < 4; ++i) {
    float v = acc[i] + bv;
    v = v > 0.f ? v : 0.f;
    unsigned short hb, mb, lb;
    split3v(v, hb, mb, lb);
    size_t o = ((size_t)(b * 34 + y + 1) * 34 + (4 * xg + i + 1)) * 32 + c;
    oH[o] = hb; oM[o] = mb; oL[o] = lb;
  }
}

// ---------------- conv weight prep ----------------
__global__ __launch_bounds__(256) void k_wprep2(const float* __restrict__ w,
                                                unsigned short* __restrict__ H,
                                                unsigned short* __restrict__ M,
                                                unsigned short* __restrict__ L) {
  int idx = blockIdx.x * 256 + threadIdx.x;   // 32768
  int j = idx & 7, lane = (idx >> 3) & 63, nt = (idx >> 9) & 3, s = idx >> 11;
  int ci = ((lane >> 4) << 3) + j, co = (nt << 4) + (lane & 15);
  unsigned short hb, mb, lb;
  split3v(w[(s * 32 + ci) * 64 + co], hb, mb, lb);
  H[idx] = hb; M[idx] = mb; L[idx] = lb;
}
__global__ __launch_bounds__(256) void k_wprep3(const float* __restrict__ w,
                                                unsigned short* __restrict__ H,
                                                unsigned short* __restrict__ M,
                                                unsigned short* __restrict__ L) {
  int idx = blockIdx.x * 256 + threadIdx.x;   // 131072
  int j = idx & 7, lane = (idx >> 3) & 63, ks = (idx >> 9) & 1;
  int nt = (idx >> 10) & 3, ch = (idx >> 12) & 1, s = idx >> 13;
  int ci = ks * 32 + ((lane >> 4) << 3) + j;
  int co = ch * 64 + (nt << 4) + (lane & 15);
  unsigned short hb, mb, lb;
  split3v(w[(s * 64 + ci) * 128 + co], hb, mb, lb);
  H[idx] = hb; M[idx] = mb; L[idx] = lb;
}

// ---------------- conv2 MFMA ----------------
__global__ __launch_bounds__(256) void k_conv2m(
    const unsigned short* __restrict__ aH, const unsigned short* __restrict__ aM,
    const unsigned short* __restrict__ aL, const unsigned short* __restrict__ wH,
    const unsigned short* __restrict__ wM, const unsigned short* __restrict__ wL,
    const float* __restrict__ bias, unsigned short* __restrict__ oH,
    unsigned short* __restrict__ oM, unsigned short* __restrict__ oL) {
  int t = threadIdx.x;
  int wave = t >> 6, lane = t & 63;
  int l15 = lane & 15, quad = lane >> 4;
  int m0 = blockIdx.x * 64 + wave * 16;     // 1024 blocks
  int p = m0 + l15;
  int b = p >> 8, y = (p >> 4) & 15, x = p & 15;
  f32x4 acc[4] = {};
  for (int s = 0; s < 16; ++s) {
    int dy = s >> 2, dx = s & 3;
    size_t aoff = ((size_t)(b * 34 + 2 * y + dy) * 34 + (2 * x + dx)) * 32 + quad * 8;
    bf16x8 ah = *(const bf16x8*)(aH + aoff);
    bf16x8 am = *(const bf16x8*)(aM + aoff);
    bf16x8 al = *(const bf16x8*)(aL + aoff);
#pragma unroll
    for (int nt = 0; nt < 4; ++nt) {
      size_t woff = ((size_t)(s * 4 + nt) * 64 + lane) * 8;
      bf16x8 bh = *(const bf16x8*)(wH + woff);
      bf16x8 bm = *(const bf16x8*)(wM + woff);
      bf16x8 bl = *(const bf16x8*)(wL + woff);
      acc[nt] = MFMA16(am, bm, acc[nt]);
      acc[nt] = MFMA16(ah, bl, acc[nt]);
      acc[nt] = MFMA16(al, bh, acc[nt]);
      acc[nt] = MFMA16(ah, bm, acc[nt]);
      acc[nt] = MFMA16(am, bh, acc[nt]);
      acc[nt] = MFMA16(ah, bh, acc[nt]);
    }
  }
#pragma unroll
  for (int r = 0; r < 4; ++r) {
    int pp = m0 + quad * 4 + r;
    int b2 = pp >> 8, yo = (pp >> 4) & 15, xo = pp & 15;
    size_t obase = ((size_t)(b2 * 18 + yo + 1) * 18 + (xo + 1)) * 64;
#pragma unroll
    for (int nt = 0; nt < 4; ++nt) {
      int co = nt * 16 + l15;
      float v = acc[nt][r] + bias[co];
      v = v > 0.f ? v : 0.f;
      unsigned short hb, mb, lb;
      split3v(v, hb, mb, lb);
      oH[obase + co] = hb; oM[obase + co] = mb; oL[obase + co] = lb;
    }
  }
}

// ---------------- conv3 MFMA: h2p -> h3 SPLIT planes (16384,128) -------------
__global__ __launch_bounds__(256) void k_conv3m(
    const unsigned short* __restrict__ aH, const unsigned short* __restrict__ aM,
    const unsigned short* __restrict__ aL, const unsigned short* __restrict__ wH,
    const unsigned short* __restrict__ wM, const unsigned short* __restrict__ wL,
    const float* __restrict__ bias, unsigned short* __restrict__ oH,
    unsigned short* __restrict__ oM, unsigned short* __restrict__ oL) {
  int t = threadIdx.x;
  int wave = t >> 6, lane = t & 63;
  int l15 = lane & 15, quad = lane >> 4;
  int pg = wave >> 1, ch = wave & 1;
  int m0 = blockIdx.x * 64 + pg * 32;       // 256 blocks
  f32x4 acc[2][4] = {};
  for (int s = 0; s < 16; ++s) {
    int dy = s >> 2, dx = s & 3;
    bf16x8 ah[2][2], am[2][2], al[2][2];
#pragma unroll
    for (int mt = 0; mt < 2; ++mt) {
      int p = m0 + mt * 16 + l15;
      int b = p >> 6, y = (p >> 3) & 7, x = p & 7;
      size_t base = ((size_t)(b * 18 + 2 * y + dy) * 18 + (2 * x + dx)) * 64 + quad * 8;
#pragma unroll
      for (int ks = 0; ks < 2; ++ks) {
        ah[mt][ks] = *(const bf16x8*)(aH + base + ks * 32);
        am[mt][ks] = *(const bf16x8*)(aM + base + ks * 32);
        al[mt][ks] = *(const bf16x8*)(aL + base + ks * 32);
      }
    }
#pragma unroll
    for (int nt = 0; nt < 4; ++nt) {
#pragma unroll
      for (int ks = 0; ks < 2; ++ks) {
        size_t woff = ((size_t)((((s * 2 + ch) * 4 + nt) * 2 + ks) * 64 + lane)) * 8;
        bf16x8 bh = *(const bf16x8*)(wH + woff);
        bf16x8 bm = *(const bf16x8*)(wM + woff);
        bf16x8 bl = *(const bf16x8*)(wL + woff);
#pragma unroll
        for (int mt = 0; mt < 2; ++mt) {
          acc[mt][nt] = MFMA16(am[mt][ks], bm, acc[mt][nt]);
          acc[mt][nt] = MFMA16(ah[mt][ks], bl, acc[mt][nt]);
          acc[mt][nt] = MFMA16(al[mt][ks], bh, acc[mt][nt]);
          acc[mt][nt] = MFMA16(ah[mt][ks], bm, acc[mt][nt]);
          acc[mt][nt] = MFMA16(am[mt][ks], bh, acc[mt][nt]);
          acc[mt][nt] = MFMA16(ah[mt][ks], bh, acc[mt][nt]);
        }
      }
    }
  }
#pragma unroll
  for (int mt = 0; mt < 2; ++mt)
#pragma unroll
    for (int nt = 0; nt < 4; ++nt) {
      int co = ch * 64 + nt * 16 + l15;
      float bv = bias[co];
#pragma unroll
      for (int r = 0; r < 4; ++r) {
        int pp = m0 + mt * 16 + quad * 4 + r;
        float v = acc[mt][nt][r] + bv;
        v = v > 0.f ? v : 0.f;
        unsigned short hb, mb, lb;
        split3v(v, hb, mb, lb);
        size_t o = (size_t)pp * 128 + co;
        oH[o] = hb; oM[o] = mb; oL[o] = lb;
      }
    }
}

// ---------------- generic B-frag pack: w(KxN fp32) -> Bp[s][kt][ntg][512] ----
__global__ __launch_bounds__(256) void k_bprep(const float* __restrict__ w,
                                               unsigned short* __restrict__ Bp,
                                               int K, int N, int NP) {
  int idx = blockIdx.x * 256 + threadIdx.x;
  if (idx >= NP * K * N) return;
  int j = idx & 7, lane = (idx >> 3) & 63;
  int f = idx >> 9;
  int NT = N >> 4, KT = K >> 5;
  int ntg = f % NT; f /= NT;
  int kt = f % KT; int s = f / KT;
  int k = kt * 32 + ((lane >> 4) << 3) + j;
  int n = ntg * 16 + (lane & 15);
  unsigned short hb, mb, lb;
  split3v(w[(size_t)k * N + n], hb, mb, lb);
  Bp[idx] = s == 0 ? hb : (s == 1 ? mb : lb);
}

// same, but reads conv-transpose weight w[16][K][CO] with spatial flip:
// logical W[k][n], n = ru*CO + o -> w[(3-r)*4+(3-u)][k][o]
__global__ __launch_bounds__(256) void k_bprep_ct(const float* __restrict__ w,
                                                  unsigned short* __restrict__ Bp,
                                                  int K, int N, int oshift,
                                                  int NP) {
  int idx = blockIdx.x * 256 + threadIdx.x;
  if (idx >= NP * K * N) return;
  int j = idx & 7, lane = (idx >> 3) & 63;
  int f = idx >> 9;
  int NT = N >> 4, KT = K >> 5;
  int ntg = f % NT; f /= NT;
  int kt = f % KT; int s = f / KT;
  int k = kt * 32 + ((lane >> 4) << 3) + j;
  int n = ntg * 16 + (lane & 15);
  int o = n & ((1 << oshift) - 1), ru = n >> oshift;
  int r = ru >> 2, u = ru & 3;
  int sf = (3 - r) * 4 + (3 - u);
  unsigned short hb, mb, lb;
  split3v(w[(((size_t)sf * K + k) << oshift) + o], hb, mb, lb);
  Bp[idx] = s == 0 ? hb : (s == 1 ? mb : lb);
}

// ---------------- generic split-bf16 MFMA GEMM ----------------
template <int NP, int NTW>
__global__ __launch_bounds__(256) void k_mgemm(
    const unsigned short* __restrict__ A0, const unsigned short* __restrict__ A1,
    const unsigned short* __restrict__ A2, const unsigned short* __restrict__ Bp,
    float* __restrict__ C, const float* __restrict__ bias,
    int M, int N, int K, int bmask) {
  int S = gridDim.z;
  int Kc = K / S;
  int t = threadIdx.x;
  int wave = t >> 6, lane = t & 63;
  int l15 = lane & 15, quad = lane >> 4;
  int m0 = blockIdx.x * 64 + wave * 16;
  int n0 = blockIdx.y * (16 * NTW);
  int KT = K >> 5, NT = N >> 4;
  int kt0 = (blockIdx.z * Kc) >> 5;
  int ktn = Kc >> 5;
  size_t sstride = (size_t)KT * NT * 512;
  const unsigned short* arow0 = A0 + (size_t)(m0 + l15) * K + quad * 8;
  const unsigned short* arow1 = A1 + (size_t)(m0 + l15) * K + quad * 8;
  const unsigned short* arow2 = nullptr;
  if constexpr (NP == 3) arow2 = A2 + (size_t)(m0 + l15) * K + quad * 8;
  f32x4 acc[NTW] = {};
  for (int kt = kt0; kt < kt0 + ktn; ++kt) {
    bf16x8 ah = *(const bf16x8*)(arow0 + kt * 32);
    bf16x8 am = *(const bf16x8*)(arow1 + kt * 32);
    bf16x8 al;
    if constexpr (NP == 3) al = *(const bf16x8*)(arow2 + kt * 32);
    const unsigned short* bbase =
        Bp + ((size_t)kt * NT + (n0 >> 4)) * 512 + lane * 8;
#pragma unroll
    for (int nt = 0; nt < NTW; ++nt) {
      const unsigned short* bp = bbase + nt * 512;
      bf16x8 bh = *(const bf16x8*)(bp);
      bf16x8 bm = *(const bf16x8*)(bp + sstride);
      if constexpr (NP == 3) {
        bf16x8 bl = *(const bf16x8*)(bp + 2 * sstride);
        acc[nt] = MFMA16(am, bm, acc[nt]);
        acc[nt] = MFMA16(ah, bl, acc[nt]);
        acc[nt] = MFMA16(al, bh, acc[nt]);
        acc[nt] = MFMA16(ah, bm, acc[nt]);
        acc[nt] = MFMA16(am, bh, acc[nt]);
        acc[nt] = MFMA16(ah, bh, acc[nt]);
      } else {
        acc[nt] = MFMA16(ah, bm, acc[nt]);
        acc[nt] = MFMA16(am, bh, acc[nt]);
        acc[nt] = MFMA16(ah, bh, acc[nt]);
      }
    }
  }
  if (S == 1) {
#pragma unroll
    for (int nt = 0; nt < NTW; ++nt) {
      int n = n0 + nt * 16 + l15;
      float bv = bias[n & bmask];
#pragma unroll
      for (int r = 0; r < 4; ++r) {
        int m = m0 + quad * 4 + r;
        float v = acc[nt][r] + bv;
        C[(size_t)m * N + n] = v > 0.f ? v : 0.f;
      }
    }
  } else {
    float* Cp = C + (size_t)blockIdx.z * M * N;
#pragma unroll
    for (int nt = 0; nt < NTW; ++nt) {
      int n = n0 + nt * 16 + l15;
#pragma unroll
      for (int r = 0; r < 4; ++r) {
        int m = m0 + quad * 4 + r;
        Cp[(size_t)m * N + n] = acc[nt][r];
      }
    }
  }
}

// sum k-split partials + bias + relu -> split planes
template <int NPOUT>
__global__ __launch_bounds__(256) void k_sumrelu3(
    const float* __restrict__ part, const float* __restrict__ bias,
    unsigned short* __restrict__ oH, unsigned short* __restrict__ oM,
    unsigned short* __restrict__ oL, int MN, int bmask, int S) {
  int idx = blockIdx.x * 256 + threadIdx.x;
  float s = 0.f;
  for (int z = 0; z < S; ++z) s += part[(size_t)z * MN + idx];
  s += bias[idx & bmask];
  s = s > 0.f ? s : 0.f;
  unsigned short hb = f2bf(s);
  float r1 = s - bf2f(hb);
  unsigned short mb = f2bf(r1);
  oH[idx] = hb; oM[idx] = mb;
  if constexpr (NPOUT == 3) oL[idx] = f2bf(r1 - bf2f(mb));
}

// ---------------- VQ ----------------
__global__ __launch_bounds__(256) void k_norm2(const float* __restrict__ e,
                                               float* __restrict__ n2) {
  int k = blockIdx.x * 256 + threadIdx.x;
  const float4* p = (const float4*)(e + (size_t)k * 64);
  float s0 = 0, s1 = 0, s2 = 0, s3 = 0;
#pragma unroll
  for (int j = 0; j < 16; ++j) {
    float4 v = p[j];
    s0 = fmaf(v.x, v.x, s0); s1 = fmaf(v.y, v.y, s1);
    s2 = fmaf(v.z, v.z, s2); s3 = fmaf(v.w, v.w, s3);
  }
  n2[k] = (s0 + s1) + (s2 + s3);
}

// embeds -> packed B-frags eB[kt][ks][nt][s][512] (3 splits)
__global__ __launch_bounds__(256) void k_eprep(const float* __restrict__ e,
                                               unsigned short* __restrict__ Bp) {
  int idx = blockIdx.x * 256 + threadIdx.x;   // 1,572,864
  int j = idx & 7, lane = (idx >> 3) & 63;
  int f = idx >> 9;
  int s = f % 3; f /= 3;
  int nt = f % 4; f /= 4;
  int ks = f % 2; int kt = f / 2;
  int code = kt * 64 + nt * 16 + (lane & 15);
  int k = ks * 32 + ((lane >> 4) << 3) + j;
  unsigned short hb, mb, lb;
  split3v(e[(size_t)code * 64 + k], hb, mb, lb);
  Bp[idx] = s == 0 ? hb : (s == 1 ? mb : lb);
}

// k_vqmfma3: 32 m-rows per wave (2 A-sets), codes streamed as B-frags.
// grid (64, 8), block 256. Per kt: 24 B loads feed 96 MFMAs (2x R6 intensity).
__global__ __launch_bounds__(256) void k_vqmfma3(
    const unsigned short* __restrict__ pH, const unsigned short* __restrict__ pM,
    const unsigned short* __restrict__ pL, const unsigned short* __restrict__ eB,
    const float* __restrict__ n2, float* __restrict__ pbd, int* __restrict__ pbk) {
  int t = threadIdx.x;
  int wave = t >> 6, lane = t & 63;
  int l15 = lane & 15, quad = lane >> 4;
  int m0 = blockIdx.x * 128 + wave * 32;
  int z = blockIdx.y;
  bf16x8 ah[2][2], am[2][2], al[2][2];   // [mt][ks]
#pragma unroll
  for (int mt = 0; mt < 2; ++mt) {
    size_t arow = (size_t)(m0 + mt * 16 + l15) * 64 + quad * 8;
#pragma unroll
    for (int ks = 0; ks < 2; ++ks) {
      ah[mt][ks] = *(const bf16x8*)(pH + arow + ks * 32);
      am[mt][ks] = *(const bf16x8*)(pM + arow + ks * 32);
      al[mt][ks] = *(const bf16x8*)(pL + arow + ks * 32);
    }
  }
  float bd[2][4]; int bk[2][4];
#pragma unroll
  for (int mt = 0; mt < 2; ++mt)
#pragma unroll
    for (int r = 0; r < 4; ++r) { bd[mt][r] = FLT_MAX; bk[mt][r] = 0; }
  for (int kt = z * 16; kt < z * 16 + 16; ++kt) {
    const unsigned short* bb = eB + (size_t)kt * 12288 + lane * 8;
    f32x4 acc[2][4] = {};
#pragma unroll
    for (int ks = 0; ks < 2; ++ks)
#pragma unroll
      for (int nt = 0; nt < 4; ++nt) {
        const unsigned short* bp = bb + ((ks * 4 + nt) * 3) * 512;
        bf16x8 bh = *(const bf16x8*)(bp);
        bf16x8 bm = *(const bf16x8*)(bp + 512);
        bf16x8 bl = *(const bf16x8*)(bp + 1024);
#pragma unroll
        for (int mt = 0; mt < 2; ++mt) {
          acc[mt][nt] = MFMA16(am[mt][ks], bm, acc[mt][nt]);
          acc[mt][nt] = MFMA16(ah[mt][ks], bl, acc[mt][nt]);
          acc[mt][nt] = MFMA16(al[mt][ks], bh, acc[mt][nt]);
          acc[mt][nt] = MFMA16(ah[mt][ks], bm, acc[mt][nt]);
          acc[mt][nt] = MFMA16(am[mt][ks], bh, acc[mt][nt]);
          acc[mt][nt] = MFMA16(ah[mt][ks], bh, acc[mt][nt]);
        }
      }
    int cb = kt * 64;
#pragma unroll
    for (int nt = 0; nt < 4; ++nt) {
      int code = cb + nt * 16 + l15;
      float nv = n2[code];
#pragma unroll
      for (int mt = 0; mt < 2; ++mt)
#pragma unroll
        for (int r = 0; r < 4; ++r) {
          float d = fmaf(-2.f, acc[mt][nt][r], nv);
          if (d < bd[mt][r]) { bd[mt][r] = d; bk[mt][r] = code; }
        }
    }
  }
#pragma unroll
  for (int mt = 0; mt < 2; ++mt)
#pragma unroll
    for (int r = 0; r < 4; ++r)
#pragma unroll
      for (int s = 1; s < 16; s <<= 1) {
        float od = __shfl_xor(bd[mt][r], s);
        int ok = __shfl_xor(bk[mt][r], s);
        if (od < bd[mt][r] || (od == bd[mt][r] && ok < bk[mt][r])) {
          bd[mt][r] = od; bk[mt][r] = ok;
        }
      }
  if (l15 == 0) {
#pragma unroll
    for (int mt = 0; mt < 2; ++mt)
#pragma unroll
      for (int r = 0; r < 4; ++r) {
        pbd[(size_t)z * 8192 + m0 + mt * 16 + quad * 4 + r] = bd[mt][r];
        pbk[(size_t)z * 8192 + m0 + mt * 16 + quad * 4 + r] = bk[mt][r];
      }
  }
}

// fused: reduce 8 z-groups per row (lex (d,k)) + gather -> 2-plane collected.
// z ranges cover ascending disjoint code blocks -> ascending-z reduce is lex.
__global__ __launch_bounds__(256) void k_vqgather(const float* __restrict__ pbd,
                                                  const int* __restrict__ pbk,
                                                  const float* __restrict__ embeds,
                                                  unsigned short* __restrict__ cH,
                                                  unsigned short* __restrict__ cM) {
  int idx = blockIdx.x * 256 + threadIdx.x;   // 524288, 2048 blocks
  int m = idx >> 6;
  float bd = pbd[m]; int bk = pbk[m];
#pragma unroll
  for (int z = 1; z < 8; ++z) {
    float d = pbd[(size_t)z * 8192 + m]; int k = pbk[(size_t)z * 8192 + m];
    if (d < bd || (d == bd && k < bk)) { bd = d; bk = k; }
  }
  float v = embeds[(size_t)bk * 64 + (idx & 63)];
  unsigned short hb = f2bf(v);
  cH[idx] = hb;
  cM[idx] = f2bf(v - bf2f(hb));
}

// ---------------- dec3: d2buf(permuted) -> out(256,64,64), +bias, no relu ----
__global__ __launch_bounds__(256) void k_dec3(const float* __restrict__ d2buf,
                                              const float* __restrict__ w3,
                                              const float* __restrict__ b3,
                                              float* __restrict__ out) {
  __shared__ float sx[16 * 129];
  __shared__ float wT[128 * 16];
  int b = blockIdx.x >> 4;          // 4096 blocks: (b, y_in)
  int y = blockIdx.x & 15;
  int t = threadIdx.x;
#pragma unroll
  for (int j = 0; j < 8; ++j) {
    int idx = t + j * 256;          // 2048
    int xx = idx >> 7, c = idx & 127;
    size_t m2 = ((size_t)b * 4 + (y >> 2)) * 4 + (xx >> 2);
    sx[xx * 129 + c] = d2buf[m2 * 2048 + ((y & 3) * 4 + (xx & 3)) * 128 + c];
  }
#pragma unroll
  for (int j = 0; j < 8; ++j) {
    int idx = t + j * 256;
    int c = idx >> 4, ru = idx & 15;
    int R = ru >> 2, U = ru & 3;
    wT[c * 16 + ru] = w3[((3 - R) * 4 + (3 - U)) * 128 + c];
  }
  __syncthreads();
  int xx = t >> 4, ru = t & 15;
  float a0 = 0, a1 = 0, a2 = 0, a3 = 0;
#pragma unroll 8
  for (int c = 0; c < 128; c += 4) {
    a0 = fmaf(sx[xx * 129 + c + 0], wT[(c + 0) * 16 + ru], a0);
    a1 = fmaf(sx[xx * 129 + c + 1], wT[(c + 1) * 16 + ru], a1);
    a2 = fmaf(sx[xx * 129 + c + 2], wT[(c + 2) * 16 + ru], a2);
    a3 = fmaf(sx[xx * 129 + c + 3], wT[(c + 3) * 16 + ru], a3);
  }
  float acc = (a0 + a1) + (a2 + a3) + b3[0];
  int R = ru >> 2, U = ru & 3;
  out[((size_t)b * 64 + 4 * y + R) * 64 + 4 * xx + U] = acc;
}

// =====================================================================
extern "C" void kernel_launch(void* const* d_in, const int* in_sizes, int n_in,
                              void* d_out, int out_size, void* d_ws, size_t ws_size,
                              hipStream_t stream) {
  const float* x        = (const float*)d_in[0];
  const float* enc_w1   = (const float*)d_in[1];
  const float* enc_b1   = (const float*)d_in[2];
  const float* enc_w2   = (const float*)d_in[3];
  const float* enc_b2   = (const float*)d_in[4];
  const float* enc_w3   = (const float*)d_in[5];
  const float* enc_b3   = (const float*)d_in[6];
  const float* fc_w     = (const float*)d_in[7];
  const float* fc_b     = (const float*)d_in[8];
  const float* ffc_w    = (const float*)d_in[9];
  const float* ffc_b    = (const float*)d_in[10];
  const float* embeds   = (const float*)d_in[11];
  const float* dec_fc_w = (const float*)d_in[12];
  const float* dec_fc_b = (const float*)d_in[13];
  const float* dec_w1   = (const float*)d_in[14];
  const float* dec_b1   = (const float*)d_in[15];
  const float* dec_w2   = (const float*)d_in[16];
  const float* dec_b2   = (const float*)d_in[17];
  const float* dec_w3   = (const float*)d_in[18];
  const float* dec_b3   = (const float*)d_in[19];
  float* outp = (float*)d_out;

  char* ws = (char*)d_ws;
  size_t off = 0;
  auto alloc = [&](size_t bytes) { size_t r = off; off = (off + bytes + 255) & ~(size_t)255; return r; };

  // ---- Region A (57.15 MB): phase1 h1p splits; phase2 decoder/partials ----
  size_t RA = alloc(57147392);
  unsigned short* h1pH = (unsigned short*)(ws + RA);
  unsigned short* h1pM = (unsigned short*)(ws + RA + 18939904);
  unsigned short* h1pL = (unsigned short*)(ws + RA + 37879808);
  float* d2buf            = (float*)(ws + RA);                    // 33.55 MB
  float* partials         = (float*)(ws + RA + 33554432);         // 8.39 MB
  unsigned short* Bp_d1   = (unsigned short*)(ws + RA + 41943040);// 8.39 MB
  unsigned short* d1H     = (unsigned short*)(ws + RA + 50331648);
  unsigned short* d1M     = (unsigned short*)(ws + RA + 52428800);
  unsigned short* hdH     = (unsigned short*)(ws + RA + 54525952);
  unsigned short* hdM     = (unsigned short*)(ws + RA + 54788096);
  unsigned short* cH      = (unsigned short*)(ws + RA + 55050240);
  unsigned short* cM      = (unsigned short*)(ws + RA + 56098816);

  // ---- Region B (31.85 MB): phase1 h2p splits; phase2 Bp_fc/eB/pred ----
  size_t RB = alloc(31850496);
  unsigned short* h2pH = (unsigned short*)(ws + RB);
  unsigned short* h2pM = (unsigned short*)(ws + RB + 10616832);
  unsigned short* h2pL = (unsigned short*)(ws + RB + 21233664);
  unsigned short* Bp_fc = (unsigned short*)(ws + RB);             // 25.17 MB
  unsigned short* eB    = (unsigned short*)(ws + RB + 25165824);  // 3.15 MB
  unsigned short* pH    = (unsigned short*)(ws + RB + 28311552);
  unsigned short* pM    = (unsigned short*)(ws + RB + 29360128);
  unsigned short* pL    = (unsigned short*)(ws + RB + 30408704);

  // ---- Region C (12.58 MB): phase1 h3 splits; phase2 Bp_ffc/hfc/Bp_dfc/Bp_d2
  size_t RC = alloc(12582912);
  unsigned short* h3H = (unsigned short*)(ws + RC);
  unsigned short* h3M = (unsigned short*)(ws + RC + 4194304);
  unsigned short* h3L = (unsigned short*)(ws + RC + 8388608);
  unsigned short* Bp_ffc = (unsigned short*)(ws + RC);            // 6.29 MB
  unsigned short* hfcH   = (unsigned short*)(ws + RC + 6291456);
  unsigned short* hfcM   = (unsigned short*)(ws + RC + 6553600);
  unsigned short* hfcL   = (unsigned short*)(ws + RC + 6815744);
  unsigned short* Bp_dfc = (unsigned short*)(ws + RC);            // 4.19 MB (after ffc)
  unsigned short* Bp_d2  = (unsigned short*)(ws + RC + 4194304);  // 2.10 MB

  // ---- dedicated small ----
  float* n2buf   = (float*)(ws + alloc(32768));
  float* pbd     = (float*)(ws + alloc(262144));
  int*   pbk     = (int*)  (ws + alloc(262144));
  unsigned short* Wp2H = (unsigned short*)(ws + alloc(196608));
  unsigned short* Wp2M = Wp2H + 32768;
  unsigned short* Wp2L = Wp2M + 32768;
  unsigned short* Wp3H = (unsigned short*)(ws + alloc(786432));
  unsigned short* Wp3M = Wp3H + 131072;
  unsigned short* Wp3L = Wp3M + 131072;
  (void)ws_size; (void)in_sizes; (void)n_in; (void)out_size;

  // zero only the pad borders (interiors are fully written by producers)
  k_zborder<<<dim3(32, 132, 3), 256, 0, stream>>>(h1pH, 34, 9469952, 5);
  k_zborder<<<dim3(64, 68, 3), 256, 0, stream>>>(h2pH, 18, 5308416, 6);

  k_wprep2<<<128, 256, 0, stream>>>(enc_w2, Wp2H, Wp2M, Wp2L);
  k_wprep3<<<512, 256, 0, stream>>>(enc_w3, Wp3H, Wp3M, Wp3L);

  k_conv1<<<8192, 256, 0, stream>>>(x, enc_w1, enc_b1, h1pH, h1pM, h1pL);
  k_conv2m<<<1024, 256, 0, stream>>>(h1pH, h1pM, h1pL, Wp2H, Wp2M, Wp2L,
                                     enc_b2, h2pH, h2pM, h2pL);
  k_conv3m<<<256, 256, 0, stream>>>(h2pH, h2pM, h2pL, Wp3H, Wp3M, Wp3L,
                                    enc_b3, h3H, h3M, h3L);

  // fc: (256x512) = h3(256x8192) @ fc_w, NP=3, S=16
  k_bprep<<<49152, 256, 0, stream>>>(fc_w, Bp_fc, 8192, 512, 3);
  k_eprep<<<6144, 256, 0, stream>>>(embeds, eB);
  k_norm2<<<32, 256, 0, stream>>>(embeds, n2buf);
  k_mgemm<3, 4><<<dim3(4, 8, 16), 256, 0, stream>>>(
      h3H, h3M, h3L, Bp_fc, partials, fc_b, 256, 512, 8192, 511);
  k_bprep<<<12288, 256, 0, stream>>>(ffc_w, Bp_ffc, 512, 2048, 3);
  k_sumrelu3<3><<<512, 256, 0, stream>>>(partials, fc_b, hfcH, hfcM, hfcL,
                                         131072, 511, 16);
  // ffc: (256x2048), NP=3, S=4 -> pred splits
  k_mgemm<3, 4><<<dim3(4, 32, 4), 256, 0, stream>>>(
      hfcH, hfcM, hfcL, Bp_ffc, partials, ffc_b, 256, 2048, 512, 2047);
  k_bprep<<<8192, 256, 0, stream>>>(dec_fc_w, Bp_dfc, 2048, 512, 2);
  k_sumrelu3<3><<<2048, 256, 0, stream>>>(partials, ffc_b, pH, pM, pL,
                                          524288, 2047, 4);

  // VQ
  k_vqmfma3<<<dim3(64, 8), 256, 0, stream>>>(pH, pM, pL, eB, n2buf, pbd, pbk);
  k_vqgather<<<2048, 256, 0, stream>>>(pbd, pbk, embeds, cH, cM);

  // dec_fc: (256x512), NP=2, S=16
  k_mgemm<2, 4><<<dim3(4, 8, 16), 256, 0, stream>>>(
      cH, cM, nullptr, Bp_dfc, partials, dec_fc_b, 256, 512, 2048, 511);
  k_sumrelu3<2><<<512, 256, 0, stream>>>(partials, dec_fc_b, hdH, hdM, nullptr,
                                         131072, 511, 16);

  // dec1: (256x4096), NP=2, S=2 (flip folded into pack)
  k_bprep_ct<<<16384, 256, 0, stream>>>(dec_w1, Bp_d1, 512, 4096, 8, 2);
  k_mgemm<2, 4><<<dim3(4, 64, 2), 256, 0, stream>>>(
      hdH, hdM, nullptr, Bp_d1, partials, dec_b1, 256, 4096, 512, 255);
  k_sumrelu3<2><<<4096, 256, 0, stream>>>(partials, dec_b1, d1H, d1M, nullptr,
                                          1048576, 255, 2);

  // dec2: (4096x2048), NP=2, S=1 -> fp32 d2buf (+bias+relu)
  k_bprep_ct<<<4096, 256, 0, stream>>>(dec_w2, Bp_d2, 256, 2048, 7, 2);
  k_mgemm<2, 8><<<dim3(64, 16, 1), 256, 0, stream>>>(
      d1H, d1M, nullptr, Bp_d2, d2buf, dec_b2, 4096, 2048, 256, 127);

  // dec3 -> final output (no relu)
  k_dec3<<<4096, 256, 0, stream>>>(d2buf, dec_w3, dec_b3, outp);
}

// Round 8
// 488.288 us; speedup vs baseline: 15.5993x; 1.0774x over previous
//
#include <hip/hip_runtime.h>
#include <cfloat>

// =====================================================================
// VQ-VAE forward.
// R8: (1) conv3m regridded (512,2): 16px x 64co per wave + s-split into
// fp32 partials (was 256 blocks = 1 wave/SIMD, latency-bound at 69us,
// MfmaUtil 13.7%); bias+relu+split via sumrelu3. (2) 8 input-only prep
// launches fused into one k_prep_early (launch/drain overhead ~4-8us per
// serial dispatch). (3) pow2 shift indexing in all bprep paths.
//
// conv_transpose (transpose_kernel=False) => flipped kernel:
//   out[4i+r, 4j+u, o] = sum_c in[i,j,c] * w[3-r, 3-u, c, o]
// Encoder convs: SAME pad = (1,1) -> padded split inputs.
// Precision: NP=3 split (6 MFMA products) ~= fp32 (2^-25 rel) for
// everything feeding the argmin; NP=2 (3 products, ~1e-5 rel) for the
// decoder (threshold 2.5e-4).
// =====================================================================

typedef short bf16x8 __attribute__((ext_vector_type(8)));
typedef float f32x4 __attribute__((ext_vector_type(4)));
#define MFMA16(a, b, c) __builtin_amdgcn_mfma_f32_16x16x32_bf16(a, b, c, 0, 0, 0)

__device__ inline unsigned short f2bf(float x) {  // RNE, inputs finite
  unsigned u = __float_as_uint(x);
  u += 0x7fffu + ((u >> 16) & 1u);
  return (unsigned short)(u >> 16);
}
__device__ inline float bf2f(unsigned short h) {
  return __uint_as_float(((unsigned)h) << 16);
}
__device__ inline void split3v(float v, unsigned short& hb, unsigned short& mb,
                               unsigned short& lb) {
  hb = f2bf(v);
  float r1 = v - bf2f(hb);
  mb = f2bf(r1);
  lb = f2bf(r1 - bf2f(mb));
}

// ---------------- fused input-only prep (one launch) ----------------
// segments (blocks): zborder h1p 12672 | zborder h2p 13056 | wprep2 128 |
// wprep3 512 | eprep 6144 | norm2 32 | bprep dec_fc 8192 | bprep_ct dec_w2 4096
#define PB0 12672
#define PB1 (PB0 + 13056)
#define PB2 (PB1 + 128)
#define PB3 (PB2 + 512)
#define PB4 (PB3 + 6144)
#define PB5 (PB4 + 32)
#define PB6 (PB5 + 8192)
#define PB7 (PB6 + 4096)
__global__ __launch_bounds__(256) void k_prep_early(
    const float* __restrict__ enc_w2, const float* __restrict__ enc_w3,
    const float* __restrict__ embeds, const float* __restrict__ dec_fc_w,
    const float* __restrict__ dec_w2, unsigned short* __restrict__ h1base,
    unsigned short* __restrict__ h2base, unsigned short* __restrict__ Wp2H,
    unsigned short* __restrict__ Wp2M, unsigned short* __restrict__ Wp2L,
    unsigned short* __restrict__ Wp3H, unsigned short* __restrict__ Wp3M,
    unsigned short* __restrict__ Wp3L, unsigned short* __restrict__ eB,
    float* __restrict__ n2, unsigned short* __restrict__ Bp_dfc,
    unsigned short* __restrict__ Bp_d2) {
  int blk = blockIdx.x;
  int t = threadIdx.x;
  if (blk < PB0) {                       // zborder h1p (W=34, C=32)
    int li = blk * 256 + t;
    int bc = li & 8191;
    int rest = li >> 13;                 // i + 132*plane
    int i = rest % 132, plane = rest / 132;
    int b = bc >> 5, c = bc & 31;
    int row, col;
    if (i < 34) { row = 0; col = i; }
    else if (i < 68) { row = 33; col = i - 34; }
    else { int j = i - 68; row = 1 + (j >> 1); col = (j & 1) ? 33 : 0; }
    h1base[(size_t)plane * 9469952 + ((size_t)(b * 34 + row) * 34 + col) * 32 + c] = 0;
  } else if (blk < PB1) {                // zborder h2p (W=18, C=64)
    int li = (blk - PB0) * 256 + t;
    int bc = li & 16383;
    int rest = li >> 14;
    int i = rest % 68, plane = rest / 68;
    int b = bc >> 6, c = bc & 63;
    int row, col;
    if (i < 18) { row = 0; col = i; }
    else if (i < 36) { row = 17; col = i - 18; }
    else { int j = i - 36; row = 1 + (j >> 1); col = (j & 1) ? 17 : 0; }
    h2base[(size_t)plane * 5308416 + ((size_t)(b * 18 + row) * 18 + col) * 64 + c] = 0;
  } else if (blk < PB2) {                // wprep2
    int idx = (blk - PB1) * 256 + t;     // 32768
    int j = idx & 7, lane = (idx >> 3) & 63, nt = (idx >> 9) & 3, s = idx >> 11;
    int ci = ((lane >> 4) << 3) + j, co = (nt << 4) + (lane & 15);
    unsigned short hb, mb, lb;
    split3v(enc_w2[(s * 32 + ci) * 64 + co], hb, mb, lb);
    Wp2H[idx] = hb; Wp2M[idx] = mb; Wp2L[idx] = lb;
  } else if (blk < PB3) {                // wprep3
    int idx = (blk - PB2) * 256 + t;     // 131072
    int j = idx & 7, lane = (idx >> 3) & 63, ks = (idx >> 9) & 1;
    int nt = (idx >> 10) & 3, ch = (idx >> 12) & 1, s = idx >> 13;
    int ci = ks * 32 + ((lane >> 4) << 3) + j;
    int co = ch * 64 + (nt << 4) + (lane & 15);
    unsigned short hb, mb, lb;
    split3v(enc_w3[(s * 64 + ci) * 128 + co], hb, mb, lb);
    Wp3H[idx] = hb; Wp3M[idx] = mb; Wp3L[idx] = lb;
  } else if (blk < PB4) {                // eprep
    int idx = (blk - PB3) * 256 + t;     // 1,572,864
    int j = idx & 7, lane = (idx >> 3) & 63;
    int f = idx >> 9;
    int s = f % 3; f /= 3;
    int nt = f & 3; f >>= 2;
    int ks = f & 1; int kt = f >> 1;
    int code = kt * 64 + nt * 16 + (lane & 15);
    int k = ks * 32 + ((lane >> 4) << 3) + j;
    unsigned short hb, mb, lb;
    split3v(embeds[(size_t)code * 64 + k], hb, mb, lb);
    eB[idx] = s == 0 ? hb : (s == 1 ? mb : lb);
  } else if (blk < PB5) {                // norm2
    int k = (blk - PB4) * 256 + t;       // 8192
    const float4* p = (const float4*)(embeds + (size_t)k * 64);
    float s0 = 0, s1 = 0, s2 = 0, s3 = 0;
#pragma unroll
    for (int j = 0; j < 16; ++j) {
      float4 v = p[j];
      s0 = fmaf(v.x, v.x, s0); s1 = fmaf(v.y, v.y, s1);
      s2 = fmaf(v.z, v.z, s2); s3 = fmaf(v.w, v.w, s3);
    }
    n2[k] = (s0 + s1) + (s2 + s3);
  } else if (blk < PB6) {                // bprep dec_fc (NP=2, K=2048, N=512)
    int idx = (blk - PB5) * 256 + t;     // 2,097,152
    int j = idx & 7, lane = (idx >> 3) & 63;
    int f = idx >> 9;
    int ntg = f & 31; f >>= 5;           // NT=32
    int kt = f & 63; int s = f >> 6;     // KT=64
    int k = kt * 32 + ((lane >> 4) << 3) + j;
    int n = ntg * 16 + (lane & 15);
    unsigned short hb, mb, lb;
    split3v(dec_fc_w[(size_t)k * 512 + n], hb, mb, lb);
    Bp_dfc[idx] = s == 0 ? hb : mb;
  } else if (blk < PB7) {                // bprep_ct dec_w2 (NP=2, K=256, N=2048, CO=128)
    int idx = (blk - PB6) * 256 + t;     // 1,048,576
    int j = idx & 7, lane = (idx >> 3) & 63;
    int f = idx >> 9;
    int ntg = f & 127; f >>= 7;          // NT=128
    int kt = f & 7; int s = f >> 3;      // KT=8
    int k = kt * 32 + ((lane >> 4) << 3) + j;
    int n = ntg * 16 + (lane & 15);
    int o = n & 127, ru = n >> 7;
    int r = ru >> 2, u = ru & 3;
    int sf = (3 - r) * 4 + (3 - u);
    unsigned short hb, mb, lb;
    split3v(dec_w2[(((size_t)sf * 256 + k) << 7) + o], hb, mb, lb);
    Bp_d2[idx] = s == 0 ? hb : mb;
  }
}

// ---------------- conv1: x(256,64,64,1) -> h1p split padded (256,34,34,32) ----
__global__ __launch_bounds__(256) void k_conv1(const float* __restrict__ x,
                                               const float* __restrict__ w,
                                               const float* __restrict__ bias,
                                               unsigned short* __restrict__ oH,
                                               unsigned short* __restrict__ oM,
                                               unsigned short* __restrict__ oL) {
  int b = blockIdx.x >> 5;          // 8192 blocks: (b, y)
  int y = blockIdx.x & 31;
  int t = threadIdx.x;
  int c = t & 31;
  int xg = t >> 5;                  // 0..7, 4 x-positions each
  float acc[4] = {0.f, 0.f, 0.f, 0.f};
  for (int dy = 0; dy < 4; ++dy) {
    int iy = 2 * y + dy - 1;
    if (iy < 0 || iy >= 64) continue;
    const float* xrow = x + ((size_t)b * 64 + iy) * 64;
    for (int dx = 0; dx < 4; ++dx) {
      float wv = w[(dy * 4 + dx) * 32 + c];
#pragma unroll
      for (int i = 0; i < 4; ++i) {
        int ix = 8 * xg + 2 * i + dx - 1;
        float v = (ix >= 0 && ix < 64) ? xrow[ix] : 0.f;
        acc[i] = fmaf(v, wv, acc[i]);
      }
    }
  }
  float bv = bias[c];
#pragma unroll
  for (int i = 0; i < 4; ++i) {
    float v = acc[i] + bv;
    v = v > 0.f ? v : 0.f;
    unsigned short hb, mb, lb;
    split3v(v, hb, mb, lb);
    size_t o = ((size_t)(b * 34 + y + 1) * 34 + (4 * xg + i + 1)) * 32 + c;
    oH[o] = hb; oM[o] = mb; oL[o] = lb;
  }
}

// ---------------- conv2 MFMA ----------------
__global__ __launch_bounds__(256) void k_conv2m(
    const unsigned short* __restrict__ aH, const unsigned short* __restrict__ aM,
    const unsigned short* __restrict__ aL, const unsigned short* __restrict__ wH,
    const unsigned short* __restrict__ wM, const unsigned short* __restrict__ wL,
    const float* __restrict__ bias, unsigned short* __restrict__ oH,
    unsigned short* __restrict__ oM, unsigned short* __restrict__ oL) {
  int t = threadIdx.x;
  int wave = t >> 6, lane = t & 63;
  int l15 = lane & 15, quad = lane >> 4;
  int m0 = blockIdx.x * 64 + wave * 16;     // 1024 blocks
  int p = m0 + l15;
  int b = p >> 8, y = (p >> 4) & 15, x = p & 15;
  f32x4 acc[4] = {};
  for (int s = 0; s < 16; ++s) {
    int dy = s >> 2, dx = s & 3;
    size_t aoff = ((size_t)(b * 34 + 2 * y + dy) * 34 + (2 * x + dx)) * 32 + quad * 8;
    bf16x8 ah = *(const bf16x8*)(aH + aoff);
    bf16x8 am = *(const bf16x8*)(aM + aoff);
    bf16x8 al = *(const bf16x8*)(aL + aoff);
#pragma unroll
    for (int nt = 0; nt < 4; ++nt) {
      size_t woff = ((size_t)(s * 4 + nt) * 64 + lane) * 8;
      bf16x8 bh = *(const bf16x8*)(wH + woff);
      bf16x8 bm = *(const bf16x8*)(wM + woff);
      bf16x8 bl = *(const bf16x8*)(wL + woff);
      acc[nt] = MFMA16(am, bm, acc[nt]);
      acc[nt] = MFMA16(ah, bl, acc[nt]);
      acc[nt] = MFMA16(al, bh, acc[nt]);
      acc[nt] = MFMA16(ah, bm, acc[nt]);
      acc[nt] = MFMA16(am, bh, acc[nt]);
      acc[nt] = MFMA16(ah, bh, acc[nt]);
    }
  }
#pragma unroll
  for (int r = 0; r < 4; ++r) {
    int pp = m0 + quad * 4 + r;
    int b2 = pp >> 8, yo = (pp >> 4) & 15, xo = pp & 15;
    size_t obase = ((size_t)(b2 * 18 + yo + 1) * 18 + (xo + 1)) * 64;
#pragma unroll
    for (int nt = 0; nt < 4; ++nt) {
      int co = nt * 16 + l15;
      float v = acc[nt][r] + bias[co];
      v = v > 0.f ? v : 0.f;
      unsigned short hb, mb, lb;
      split3v(v, hb, mb, lb);
      oH[obase + co] = hb; oM[obase + co] = mb; oL[obase + co] = lb;
    }
  }
}

// ---------------- conv3 MFMA -> fp32 partials [z][16384][128] ----------------
// grid (512, 2): 32 px x 128 co per block; wave = 16 px x 64 co; z = s-half.
__global__ __launch_bounds__(256) void k_conv3m(
    const unsigned short* __restrict__ aH, const unsigned short* __restrict__ aM,
    const unsigned short* __restrict__ aL, const unsigned short* __restrict__ wH,
    const unsigned short* __restrict__ wM, const unsigned short* __restrict__ wL,
    float* __restrict__ part) {
  int t = threadIdx.x;
  int wave = t >> 6, lane = t & 63;
  int l15 = lane & 15, quad = lane >> 4;
  int mtg = wave & 1, ch = wave >> 1;
  int m0 = blockIdx.x * 32 + mtg * 16;
  int z = blockIdx.y;
  int p = m0 + l15;
  int b = p >> 6, y = (p >> 3) & 7, x = p & 7;
  f32x4 acc[4] = {};
  for (int s = z * 8; s < z * 8 + 8; ++s) {
    int dy = s >> 2, dx = s & 3;
    size_t base = ((size_t)(b * 18 + 2 * y + dy) * 18 + (2 * x + dx)) * 64 + quad * 8;
    bf16x8 ah[2], am[2], al[2];
#pragma unroll
    for (int ks = 0; ks < 2; ++ks) {
      ah[ks] = *(const bf16x8*)(aH + base + ks * 32);
      am[ks] = *(const bf16x8*)(aM + base + ks * 32);
      al[ks] = *(const bf16x8*)(aL + base + ks * 32);
    }
#pragma unroll
    for (int nt = 0; nt < 4; ++nt) {
#pragma unroll
      for (int ks = 0; ks < 2; ++ks) {
        size_t woff = ((size_t)((((s * 2 + ch) * 4 + nt) * 2 + ks) * 64 + lane)) * 8;
        bf16x8 bh = *(const bf16x8*)(wH + woff);
        bf16x8 bm = *(const bf16x8*)(wM + woff);
        bf16x8 bl = *(const bf16x8*)(wL + woff);
        acc[nt] = MFMA16(am[ks], bm, acc[nt]);
        acc[nt] = MFMA16(ah[ks], bl, acc[nt]);
        acc[nt] = MFMA16(al[ks], bh, acc[nt]);
        acc[nt] = MFMA16(ah[ks], bm, acc[nt]);
        acc[nt] = MFMA16(am[ks], bh, acc[nt]);
        acc[nt] = MFMA16(ah[ks], bh, acc[nt]);
      }
    }
  }
  float* Cp = part + (size_t)z * 2097152;
#pragma unroll
  for (int nt = 0; nt < 4; ++nt) {
    int co = ch * 64 + nt * 16 + l15;
#pragma unroll
    for (int r = 0; r < 4; ++r) {
      int pp = m0 + quad * 4 + r;
      Cp[(size_t)pp * 128 + co] = acc[nt][r];
    }
  }
}

// ---------------- generic B-frag pack (pow2 shifts) ----------------
__global__ __launch_bounds__(256) void k_bprep(const float* __restrict__ w,
                                               unsigned short* __restrict__ Bp,
                                               int logNT, int logKT, int N) {
  int idx = blockIdx.x * 256 + threadIdx.x;
  int j = idx & 7, lane = (idx >> 3) & 63;
  int f = idx >> 9;
  int ntg = f & ((1 << logNT) - 1); f >>= logNT;
  int kt = f & ((1 << logKT) - 1); int s = f >> logKT;
  int k = kt * 32 + ((lane >> 4) << 3) + j;
  int n = ntg * 16 + (lane & 15);
  unsigned short hb, mb, lb;
  split3v(w[(size_t)k * N + n], hb, mb, lb);
  Bp[idx] = s == 0 ? hb : (s == 1 ? mb : lb);
}

// conv-transpose variant: w[16][K][CO] with spatial flip
__global__ __launch_bounds__(256) void k_bprep_ct(const float* __restrict__ w,
                                                  unsigned short* __restrict__ Bp,
                                                  int logNT, int logKT, int K,
                                                  int oshift) {
  int idx = blockIdx.x * 256 + threadIdx.x;
  int j = idx & 7, lane = (idx >> 3) & 63;
  int f = idx >> 9;
  int ntg = f & ((1 << logNT) - 1); f >>= logNT;
  int kt = f & ((1 << logKT) - 1); int s = f >> logKT;
  int k = kt * 32 + ((lane >> 4) << 3) + j;
  int n = ntg * 16 + (lane & 15);
  int o = n & ((1 << oshift) - 1), ru = n >> oshift;
  int r = ru >> 2, u = ru & 3;
  int sf = (3 - r) * 4 + (3 - u);
  unsigned short hb, mb, lb;
  split3v(w[(((size_t)sf * K + k) << oshift) + o], hb, mb, lb);
  Bp[idx] = s == 0 ? hb : (s == 1 ? mb : lb);
}

// ---------------- generic split-bf16 MFMA GEMM ----------------
template <int NP, int NTW>
__global__ __launch_bounds__(256) void k_mgemm(
    const unsigned short* __restrict__ A0, const unsigned short* __restrict__ A1,
    const unsigned short* __restrict__ A2, const unsigned short* __restrict__ Bp,
    float* __restrict__ C, const float* __restrict__ bias,
    int M, int N, int K, int bmask) {
  int S = gridDim.z;
  int Kc = K / S;
  int t = threadIdx.x;
  int wave = t >> 6, lane = t & 63;
  int l15 = lane & 15, quad = lane >> 4;
  int m0 = blockIdx.x * 64 + wave * 16;
  int n0 = blockIdx.y * (16 * NTW);
  int KT = K >> 5, NT = N >> 4;
  int kt0 = (blockIdx.z * Kc) >> 5;
  int ktn = Kc >> 5;
  size_t sstride = (size_t)KT * NT * 512;
  const unsigned short* arow0 = A0 + (size_t)(m0 + l15) * K + quad * 8;
  const unsigned short* arow1 = A1 + (size_t)(m0 + l15) * K + quad * 8;
  const unsigned short* arow2 = nullptr;
  if constexpr (NP == 3) arow2 = A2 + (size_t)(m0 + l15) * K + quad * 8;
  f32x4 acc[NTW] = {};
  for (int kt = kt0; kt < kt0 + ktn; ++kt) {
    bf16x8 ah = *(const bf16x8*)(arow0 + kt * 32);
    bf16x8 am = *(const bf16x8*)(arow1 + kt * 32);
    bf16x8 al;
    if constexpr (NP == 3) al = *(const bf16x8*)(arow2 + kt * 32);
    const unsigned short* bbase =
        Bp + ((size_t)kt * NT + (n0 >> 4)) * 512 + lane * 8;
#pragma unroll
    for (int nt = 0; nt < NTW; ++nt) {
      const unsigned short* bp = bbase + nt * 512;
      bf16x8 bh = *(const bf16x8*)(bp);
      bf16x8 bm = *(const bf16x8*)(bp + sstride);
      if constexpr (NP == 3) {
        bf16x8 bl = *(const bf16x8*)(bp + 2 * sstride);
        acc[nt] = MFMA16(am, bm, acc[nt]);
        acc[nt] = MFMA16(ah, bl, acc[nt]);
        acc[nt] = MFMA16(al, bh, acc[nt]);
        acc[nt] = MFMA16(ah, bm, acc[nt]);
        acc[nt] = MFMA16(am, bh, acc[nt]);
        acc[nt] = MFMA16(ah, bh, acc[nt]);
      } else {
        acc[nt] = MFMA16(ah, bm, acc[nt]);
        acc[nt] = MFMA16(am, bh, acc[nt]);
        acc[nt] = MFMA16(ah, bh, acc[nt]);
      }
    }
  }
  if (S == 1) {
#pragma unroll
    for (int nt = 0; nt < NTW; ++nt) {
      int n = n0 + nt * 16 + l15;
      float bv = bias[n & bmask];
#pragma unroll
      for (int r = 0; r < 4; ++r) {
        int m = m0 + quad * 4 + r;
        float v = acc[nt][r] + bv;
        C[(size_t)m * N + n] = v > 0.f ? v : 0.f;
      }
    }
  } else {
    float* Cp = C + (size_t)blockIdx.z * M * N;
#pragma unroll
    for (int nt = 0; nt < NTW; ++nt) {
      int n = n0 + nt * 16 + l15;
#pragma unroll
      for (int r = 0; r < 4; ++r) {
        int m = m0 + quad * 4 + r;
        Cp[(size_t)m * N + n] = acc[nt][r];
      }
    }
  }
}

// sum k-split partials + bias + relu -> split planes
template <int NPOUT>
__global__ __launch_bounds__(256) void k_sumrelu3(
    const float* __restrict__ part, const float* __restrict__ bias,
    unsigned short* __restrict__ oH, unsigned short* __restrict__ oM,
    unsigned short* __restrict__ oL, int MN, int bmask, int S) {
  int idx = blockIdx.x * 256 + threadIdx.x;
  float s = 0.f;
  for (int z = 0; z < S; ++z) s += part[(size_t)z * MN + idx];
  s += bias[idx & bmask];
  s = s > 0.f ? s : 0.f;
  unsigned short hb = f2bf(s);
  float r1 = s - bf2f(hb);
  unsigned short mb = f2bf(r1);
  oH[idx] = hb; oM[idx] = mb;
  if constexpr (NPOUT == 3) oL[idx] = f2bf(r1 - bf2f(mb));
}

// ---------------- VQ ----------------
// k_vqmfma3: 32 m-rows per wave (2 A-sets), codes streamed as B-frags.
__global__ __launch_bounds__(256) void k_vqmfma3(
    const unsigned short* __restrict__ pH, const unsigned short* __restrict__ pM,
    const unsigned short* __restrict__ pL, const unsigned short* __restrict__ eB,
    const float* __restrict__ n2, float* __restrict__ pbd, int* __restrict__ pbk) {
  int t = threadIdx.x;
  int wave = t >> 6, lane = t & 63;
  int l15 = lane & 15, quad = lane >> 4;
  int m0 = blockIdx.x * 128 + wave * 32;
  int z = blockIdx.y;
  bf16x8 ah[2][2], am[2][2], al[2][2];   // [mt][ks]
#pragma unroll
  for (int mt = 0; mt < 2; ++mt) {
    size_t arow = (size_t)(m0 + mt * 16 + l15) * 64 + quad * 8;
#pragma unroll
    for (int ks = 0; ks < 2; ++ks) {
      ah[mt][ks] = *(const bf16x8*)(pH + arow + ks * 32);
      am[mt][ks] = *(const bf16x8*)(pM + arow + ks * 32);
      al[mt][ks] = *(const bf16x8*)(pL + arow + ks * 32);
    }
  }
  float bd[2][4]; int bk[2][4];
#pragma unroll
  for (int mt = 0; mt < 2; ++mt)
#pragma unroll
    for (int r = 0; r < 4; ++r) { bd[mt][r] = FLT_MAX; bk[mt][r] = 0; }
  for (int kt = z * 16; kt < z * 16 + 16; ++kt) {
    const unsigned short* bb = eB + (size_t)kt * 12288 + lane * 8;
    f32x4 acc[2][4] = {};
#pragma unroll
    for (int ks = 0; ks < 2; ++ks)
#pragma unroll
      for (int nt = 0; nt < 4; ++nt) {
        const unsigned short* bp = bb + ((ks * 4 + nt) * 3) * 512;
        bf16x8 bh = *(const bf16x8*)(bp);
        bf16x8 bm = *(const bf16x8*)(bp + 512);
        bf16x8 bl = *(const bf16x8*)(bp + 1024);
#pragma unroll
        for (int mt = 0; mt < 2; ++mt) {
          acc[mt][nt] = MFMA16(am[mt][ks], bm, acc[mt][nt]);
          acc[mt][nt] = MFMA16(ah[mt][ks], bl, acc[mt][nt]);
          acc[mt][nt] = MFMA16(al[mt][ks], bh, acc[mt][nt]);
          acc[mt][nt] = MFMA16(ah[mt][ks], bm, acc[mt][nt]);
          acc[mt][nt] = MFMA16(am[mt][ks], bh, acc[mt][nt]);
          acc[mt][nt] = MFMA16(ah[mt][ks], bh, acc[mt][nt]);
        }
      }
    int cb = kt * 64;
#pragma unroll
    for (int nt = 0; nt < 4; ++nt) {
      int code = cb + nt * 16 + l15;
      float nv = n2[code];
#pragma unroll
      for (int mt = 0; mt < 2; ++mt)
#pragma unroll
        for (int r = 0; r < 4; ++r) {
          float d = fmaf(-2.f, acc[mt][nt][r], nv);
          if (d < bd[mt][r]) { bd[mt][r] = d; bk[mt][r] = code; }
        }
    }
  }
#pragma unroll
  for (int mt = 0; mt < 2; ++mt)
#pragma unroll
    for (int r = 0; r < 4; ++r)
#pragma unroll
      for (int s = 1; s < 16; s <<= 1) {
        float od = __shfl_xor(bd[mt][r], s);
        int ok = __shfl_xor(bk[mt][r], s);
        if (od < bd[mt][r] || (od == bd[mt][r] && ok < bk[mt][r])) {
          bd[mt][r] = od; bk[mt][r] = ok;
        }
      }
  if (l15 == 0) {
#pragma unroll
    for (int mt = 0; mt < 2; ++mt)
#pragma unroll
      for (int r = 0; r < 4; ++r) {
        pbd[(size_t)z * 8192 + m0 + mt * 16 + quad * 4 + r] = bd[mt][r];
        pbk[(size_t)z * 8192 + m0 + mt * 16 + quad * 4 + r] = bk[mt][r];
      }
  }
}

// fused: reduce 8 z-groups per row (lex (d,k)) + gather -> 2-plane collected.
__global__ __launch_bounds__(256) void k_vqgather(const float* __restrict__ pbd,
                                                  const int* __restrict__ pbk,
                                                  const float* __restrict__ embeds,
                                                  unsigned short* __restrict__ cH,
                                                  unsigned short* __restrict__ cM) {
  int idx = blockIdx.x * 256 + threadIdx.x;   // 524288, 2048 blocks
  int m = idx >> 6;
  float bd = pbd[m]; int bk = pbk[m];
#pragma unroll
  for (int z = 1; z < 8; ++z) {
    float d = pbd[(size_t)z * 8192 + m]; int k = pbk[(size_t)z * 8192 + m];
    if (d < bd || (d == bd && k < bk)) { bd = d; bk = k; }
  }
  float v = embeds[(size_t)bk * 64 + (idx & 63)];
  unsigned short hb = f2bf(v);
  cH[idx] = hb;
  cM[idx] = f2bf(v - bf2f(hb));
}

// ---------------- dec3: d2buf(permuted) -> out(256,64,64), +bias, no relu ----
__global__ __launch_bounds__(256) void k_dec3(const float* __restrict__ d2buf,
                                              const float* __restrict__ w3,
                                              const float* __restrict__ b3,
                                              float* __restrict__ out) {
  __shared__ float sx[16 * 129];
  __shared__ float wT[128 * 16];
  int b = blockIdx.x >> 4;          // 4096 blocks: (b, y_in)
  int y = blockIdx.x & 15;
  int t = threadIdx.x;
#pragma unroll
  for (int j = 0; j < 8; ++j) {
    int idx = t + j * 256;          // 2048
    int xx = idx >> 7, c = idx & 127;
    size_t m2 = ((size_t)b * 4 + (y >> 2)) * 4 + (xx >> 2);
    sx[xx * 129 + c] = d2buf[m2 * 2048 + ((y & 3) * 4 + (xx & 3)) * 128 + c];
  }
#pragma unroll
  for (int j = 0; j < 8; ++j) {
    int idx = t + j * 256;
    int c = idx >> 4, ru = idx & 15;
    int R = ru >> 2, U = ru & 3;
    wT[c * 16 + ru] = w3[((3 - R) * 4 + (3 - U)) * 128 + c];
  }
  __syncthreads();
  int xx = t >> 4, ru = t & 15;
  float a0 = 0, a1 = 0, a2 = 0, a3 = 0;
#pragma unroll 8
  for (int c = 0; c < 128; c += 4) {
    a0 = fmaf(sx[xx * 129 + c + 0], wT[(c + 0) * 16 + ru], a0);
    a1 = fmaf(sx[xx * 129 + c + 1], wT[(c + 1) * 16 + ru], a1);
    a2 = fmaf(sx[xx * 129 + c + 2], wT[(c + 2) * 16 + ru], a2);
    a3 = fmaf(sx[xx * 129 + c + 3], wT[(c + 3) * 16 + ru], a3);
  }
  float acc = (a0 + a1) + (a2 + a3) + b3[0];
  int R = ru >> 2, U = ru & 3;
  out[((size_t)b * 64 + 4 * y + R) * 64 + 4 * xx + U] = acc;
}

// =====================================================================
extern "C" void kernel_launch(void* const* d_in, const int* in_sizes, int n_in,
                              void* d_out, int out_size, void* d_ws, size_t ws_size,
                              hipStream_t stream) {
  const float* x        = (const float*)d_in[0];
  const float* enc_w1   = (const float*)d_in[1];
  const float* enc_b1   = (const float*)d_in[2];
  const float* enc_w2   = (const float*)d_in[3];
  const float* enc_b2   = (const float*)d_in[4];
  const float* enc_w3   = (const float*)d_in[5];
  const float* enc_b3   = (const float*)d_in[6];
  const float* fc_w     = (const float*)d_in[7];
  const float* fc_b     = (const float*)d_in[8];
  const float* ffc_w    = (const float*)d_in[9];
  const float* ffc_b    = (const float*)d_in[10];
  const float* embeds   = (const float*)d_in[11];
  const float* dec_fc_w = (const float*)d_in[12];
  const float* dec_fc_b = (const float*)d_in[13];
  const float* dec_w1   = (const float*)d_in[14];
  const float* dec_b1   = (const float*)d_in[15];
  const float* dec_w2   = (const float*)d_in[16];
  const float* dec_b2   = (const float*)d_in[17];
  const float* dec_w3   = (const float*)d_in[18];
  const float* dec_b3   = (const float*)d_in[19];
  float* outp = (float*)d_out;

  char* ws = (char*)d_ws;
  size_t off = 0;
  auto alloc = [&](size_t bytes) { size_t r = off; off = (off + bytes + 255) & ~(size_t)255; return r; };

  // ---- Region A (57.15 MB): phase1 h1p splits; phase2 decoder/partials ----
  size_t RA = alloc(57147392);
  unsigned short* h1pH = (unsigned short*)(ws + RA);
  unsigned short* h1pM = (unsigned short*)(ws + RA + 18939904);
  unsigned short* h1pL = (unsigned short*)(ws + RA + 37879808);
  float* d2buf            = (float*)(ws + RA);                    // 33.55 MB
  float* partials         = (float*)(ws + RA + 33554432);         // <=16.78 MB
  unsigned short* Bp_d1   = (unsigned short*)(ws + RA + 50331648 - 8388608); // 41.94..50.33
  unsigned short* d1H     = (unsigned short*)(ws + RA + 50331648);
  unsigned short* d1M     = (unsigned short*)(ws + RA + 52428800);
  unsigned short* hdH     = (unsigned short*)(ws + RA + 54525952);
  unsigned short* hdM     = (unsigned short*)(ws + RA + 54788096);
  unsigned short* cH      = (unsigned short*)(ws + RA + 55050240);
  unsigned short* cM      = (unsigned short*)(ws + RA + 56098816);

  // ---- Region B (31.85 MB): phase1 h2p splits; phase2 Bp_fc/pred ----
  size_t RB = alloc(31850496);
  unsigned short* h2pH = (unsigned short*)(ws + RB);
  unsigned short* h2pM = (unsigned short*)(ws + RB + 10616832);
  unsigned short* h2pL = (unsigned short*)(ws + RB + 21233664);
  unsigned short* Bp_fc = (unsigned short*)(ws + RB);             // 25.17 MB
  unsigned short* pH    = (unsigned short*)(ws + RB + 28311552);
  unsigned short* pM    = (unsigned short*)(ws + RB + 29360128);
  unsigned short* pL    = (unsigned short*)(ws + RB + 30408704);

  // ---- Region C (12.58 MB): phase1 h3 splits; phase2 Bp_ffc/hfc ----
  size_t RC = alloc(12582912);
  unsigned short* h3H = (unsigned short*)(ws + RC);
  unsigned short* h3M = (unsigned short*)(ws + RC + 4194304);
  unsigned short* h3L = (unsigned short*)(ws + RC + 8388608);
  unsigned short* Bp_ffc = (unsigned short*)(ws + RC);            // 6.29 MB (after fc)
  unsigned short* hfcH   = (unsigned short*)(ws + RC + 6291456);
  unsigned short* hfcM   = (unsigned short*)(ws + RC + 6553600);
  unsigned short* hfcL   = (unsigned short*)(ws + RC + 6815744);

  // ---- dedicated (lifetime spans whole run) ----
  unsigned short* eB     = (unsigned short*)(ws + alloc(3145728));
  unsigned short* Bp_dfc = (unsigned short*)(ws + alloc(4194304));
  unsigned short* Bp_d2  = (unsigned short*)(ws + alloc(2097152));
  float* n2buf   = (float*)(ws + alloc(32768));
  float* pbd     = (float*)(ws + alloc(262144));
  int*   pbk     = (int*)  (ws + alloc(262144));
  unsigned short* Wp2H = (unsigned short*)(ws + alloc(196608));
  unsigned short* Wp2M = Wp2H + 32768;
  unsigned short* Wp2L = Wp2M + 32768;
  unsigned short* Wp3H = (unsigned short*)(ws + alloc(786432));
  unsigned short* Wp3M = Wp3H + 131072;
  unsigned short* Wp3L = Wp3M + 131072;
  (void)ws_size; (void)in_sizes; (void)n_in; (void)out_size;

  // all input-only prep in one launch (borders, conv wpacks, eB, n2,
  // Bp_dfc, Bp_d2)
  k_prep_early<<<PB7, 256, 0, stream>>>(
      enc_w2, enc_w3, embeds, dec_fc_w, dec_w2, h1pH, h2pH,
      Wp2H, Wp2M, Wp2L, Wp3H, Wp3M, Wp3L, eB, n2buf, Bp_dfc, Bp_d2);

  k_conv1<<<8192, 256, 0, stream>>>(x, enc_w1, enc_b1, h1pH, h1pM, h1pL);
  k_conv2m<<<1024, 256, 0, stream>>>(h1pH, h1pM, h1pL, Wp2H, Wp2M, Wp2L,
                                     enc_b2, h2pH, h2pM, h2pL);
  k_conv3m<<<dim3(512, 2), 256, 0, stream>>>(h2pH, h2pM, h2pL,
                                             Wp3H, Wp3M, Wp3L, partials);
  k_sumrelu3<3><<<8192, 256, 0, stream>>>(partials, enc_b3, h3H, h3M, h3L,
                                          2097152, 127, 2);

  // fc: (256x512) = h3(256x8192) @ fc_w, NP=3, S=16
  k_bprep<<<49152, 256, 0, stream>>>(fc_w, Bp_fc, 5, 8, 512);
  k_mgemm<3, 4><<<dim3(4, 8, 16), 256, 0, stream>>>(
      h3H, h3M, h3L, Bp_fc, partials, fc_b, 256, 512, 8192, 511);
  k_bprep<<<12288, 256, 0, stream>>>(ffc_w, Bp_ffc, 7, 4, 2048);
  k_sumrelu3<3><<<512, 256, 0, stream>>>(partials, fc_b, hfcH, hfcM, hfcL,
                                         131072, 511, 16);
  // ffc: (256x2048), NP=3, S=4 -> pred splits
  k_mgemm<3, 4><<<dim3(4, 32, 4), 256, 0, stream>>>(
      hfcH, hfcM, hfcL, Bp_ffc, partials, ffc_b, 256, 2048, 512, 2047);
  k_sumrelu3<3><<<2048, 256, 0, stream>>>(partials, ffc_b, pH, pM, pL,
                                          524288, 2047, 4);

  // VQ
  k_vqmfma3<<<dim3(64, 8), 256, 0, stream>>>(pH, pM, pL, eB, n2buf, pbd, pbk);
  k_vqgather<<<2048, 256, 0, stream>>>(pbd, pbk, embeds, cH, cM);

  // dec_fc: (256x512), NP=2, S=16
  k_mgemm<2, 4><<<dim3(4, 8, 16), 256, 0, stream>>>(
      cH, cM, nullptr, Bp_dfc, partials, dec_fc_b, 256, 512, 2048, 511);
  k_sumrelu3<2><<<512, 256, 0, stream>>>(partials, dec_fc_b, hdH, hdM, nullptr,
                                         131072, 511, 16);

  // dec1: (256x4096), NP=2, S=2 (flip folded into pack)
  k_bprep_ct<<<16384, 256, 0, stream>>>(dec_w1, Bp_d1, 8, 4, 512, 8);
  k_mgemm<2, 4><<<dim3(4, 64, 2), 256, 0, stream>>>(
      hdH, hdM, nullptr, Bp_d1, partials, dec_b1, 256, 4096, 512, 255);
  k_sumrelu3<2><<<4096, 256, 0, stream>>>(partials, dec_b1, d1H, d1M, nullptr,
                                          1048576, 255, 2);

  // dec2: (4096x2048), NP=2, S=1 -> fp32 d2buf (+bias+relu)
  k_mgemm<2, 8><<<dim3(64, 16, 1), 256, 0, stream>>>(
      d1H, d1M, nullptr, Bp_d2, d2buf, dec_b2, 4096, 2048, 256, 127);

  // dec3 -> final output (no relu)
  k_dec3<<<4096, 256, 0, stream>>>(d2buf, dec_w3, dec_b3, outp);
}

// Round 9
// 467.782 us; speedup vs baseline: 16.2831x; 1.0438x over previous
//
#include <hip/hip_runtime.h>
#include <cfloat>

// =====================================================================
// VQ-VAE forward.
// R9: (1) conv2m/conv3m s-loops software-pipelined (#pragma unroll +
// __launch_bounds__(256,4) caps VGPR at 128 for 4 waves/SIMD) — R8 showed
// conv2m latency-stalled (MfmaUtil 16%, HBM 21%, VGPR=32 = no load window).
// (2) bprep kernels rewritten one-read-N-write. (3) more prep fusion:
// 21 -> 18 launches.
//
// conv_transpose (transpose_kernel=False) => flipped kernel:
//   out[4i+r, 4j+u, o] = sum_c in[i,j,c] * w[3-r, 3-u, c, o]
// Encoder convs: SAME pad = (1,1) -> padded split inputs.
// Precision: NP=3 split (6 MFMA products) ~= fp32 (2^-25 rel) for
// everything feeding the argmin; NP=2 (3 products, ~1e-5 rel) for the
// decoder (threshold 2.5e-4).
// =====================================================================

typedef short bf16x8 __attribute__((ext_vector_type(8)));
typedef float f32x4 __attribute__((ext_vector_type(4)));
#define MFMA16(a, b, c) __builtin_amdgcn_mfma_f32_16x16x32_bf16(a, b, c, 0, 0, 0)

__device__ inline unsigned short f2bf(float x) {  // RNE, inputs finite
  unsigned u = __float_as_uint(x);
  u += 0x7fffu + ((u >> 16) & 1u);
  return (unsigned short)(u >> 16);
}
__device__ inline float bf2f(unsigned short h) {
  return __uint_as_float(((unsigned)h) << 16);
}
__device__ inline void split3v(float v, unsigned short& hb, unsigned short& mb,
                               unsigned short& lb) {
  hb = f2bf(v);
  float r1 = v - bf2f(hb);
  mb = f2bf(r1);
  lb = f2bf(r1 - bf2f(mb));
}

// ---------------- fused input-only prep (one launch) ----------------
// segments: zborder h1p | zborder h2p | wprep2 | wprep3 | eprep | norm2 |
// bprep dec_fc (NP2) | bprep_ct dec_w2 (NP2)
#define PB0 12672
#define PB1 (PB0 + 13056)
#define PB2 (PB1 + 128)
#define PB3 (PB2 + 512)
#define PB4 (PB3 + 2048)
#define PB5 (PB4 + 32)
#define PB6 (PB5 + 4096)
#define PB7 (PB6 + 2048)
__global__ __launch_bounds__(256) void k_prep_early(
    const float* __restrict__ enc_w2, const float* __restrict__ enc_w3,
    const float* __restrict__ embeds, const float* __restrict__ dec_fc_w,
    const float* __restrict__ dec_w2, unsigned short* __restrict__ h1base,
    unsigned short* __restrict__ h2base, unsigned short* __restrict__ Wp2H,
    unsigned short* __restrict__ Wp2M, unsigned short* __restrict__ Wp2L,
    unsigned short* __restrict__ Wp3H, unsigned short* __restrict__ Wp3M,
    unsigned short* __restrict__ Wp3L, unsigned short* __restrict__ eB,
    float* __restrict__ n2, unsigned short* __restrict__ Bp_dfc,
    unsigned short* __restrict__ Bp_d2) {
  int blk = blockIdx.x;
  int t = threadIdx.x;
  if (blk < PB0) {                       // zborder h1p (W=34, C=32)
    int li = blk * 256 + t;
    int bc = li & 8191;
    int rest = li >> 13;                 // i + 132*plane
    int i = rest % 132, plane = rest / 132;
    int b = bc >> 5, c = bc & 31;
    int row, col;
    if (i < 34) { row = 0; col = i; }
    else if (i < 68) { row = 33; col = i - 34; }
    else { int j = i - 68; row = 1 + (j >> 1); col = (j & 1) ? 33 : 0; }
    h1base[(size_t)plane * 9469952 + ((size_t)(b * 34 + row) * 34 + col) * 32 + c] = 0;
  } else if (blk < PB1) {                // zborder h2p (W=18, C=64)
    int li = (blk - PB0) * 256 + t;
    int bc = li & 16383;
    int rest = li >> 14;
    int i = rest % 68, plane = rest / 68;
    int b = bc >> 6, c = bc & 63;
    int row, col;
    if (i < 18) { row = 0; col = i; }
    else if (i < 36) { row = 17; col = i - 18; }
    else { int j = i - 36; row = 1 + (j >> 1); col = (j & 1) ? 17 : 0; }
    h2base[(size_t)plane * 5308416 + ((size_t)(b * 18 + row) * 18 + col) * 64 + c] = 0;
  } else if (blk < PB2) {                // wprep2
    int idx = (blk - PB1) * 256 + t;     // 32768
    int j = idx & 7, lane = (idx >> 3) & 63, nt = (idx >> 9) & 3, s = idx >> 11;
    int ci = ((lane >> 4) << 3) + j, co = (nt << 4) + (lane & 15);
    unsigned short hb, mb, lb;
    split3v(enc_w2[(s * 32 + ci) * 64 + co], hb, mb, lb);
    Wp2H[idx] = hb; Wp2M[idx] = mb; Wp2L[idx] = lb;
  } else if (blk < PB3) {                // wprep3
    int idx = (blk - PB2) * 256 + t;     // 131072
    int j = idx & 7, lane = (idx >> 3) & 63, ks = (idx >> 9) & 1;
    int nt = (idx >> 10) & 3, ch = (idx >> 12) & 1, s = idx >> 13;
    int ci = ks * 32 + ((lane >> 4) << 3) + j;
    int co = ch * 64 + (nt << 4) + (lane & 15);
    unsigned short hb, mb, lb;
    split3v(enc_w3[(s * 64 + ci) * 128 + co], hb, mb, lb);
    Wp3H[idx] = hb; Wp3M[idx] = mb; Wp3L[idx] = lb;
  } else if (blk < PB4) {                // eprep (one read -> 3 writes)
    int idx = (blk - PB3) * 256 + t;     // 524,288
    int j = idx & 7, lane = (idx >> 3) & 63;
    int f = idx >> 9;                    // (kt*2+ks)*4+nt
    int nt = f & 3, ks = (f >> 2) & 1, kt = f >> 3;
    int code = kt * 64 + nt * 16 + (lane & 15);
    int k = ks * 32 + ((lane >> 4) << 3) + j;
    unsigned short hb, mb, lb;
    split3v(embeds[(size_t)code * 64 + k], hb, mb, lb);
    size_t base = (size_t)f * 1536 + lane * 8 + j;
    eB[base] = hb; eB[base + 512] = mb; eB[base + 1024] = lb;
  } else if (blk < PB5) {                // norm2
    int k = (blk - PB4) * 256 + t;       // 8192
    const float4* p = (const float4*)(embeds + (size_t)k * 64);
    float s0 = 0, s1 = 0, s2 = 0, s3 = 0;
#pragma unroll
    for (int j = 0; j < 16; ++j) {
      float4 v = p[j];
      s0 = fmaf(v.x, v.x, s0); s1 = fmaf(v.y, v.y, s1);
      s2 = fmaf(v.z, v.z, s2); s3 = fmaf(v.w, v.w, s3);
    }
    n2[k] = (s0 + s1) + (s2 + s3);
  } else if (blk < PB6) {                // bprep dec_fc NP=2 (K=2048,N=512)
    int idx = (blk - PB5) * 256 + t;     // 1,048,576
    int j = idx & 7, lane = (idx >> 3) & 63;
    int f = idx >> 9;
    int ntg = f & 31;                    // NT=32
    int kt = f >> 5;                     // KT=64
    int k = kt * 32 + ((lane >> 4) << 3) + j;
    int n = ntg * 16 + (lane & 15);
    unsigned short hb, mb, lb;
    split3v(dec_fc_w[(size_t)k * 512 + n], hb, mb, lb);
    Bp_dfc[idx] = hb; Bp_dfc[idx + 1048576] = mb;
  } else if (blk < PB7) {                // bprep_ct dec_w2 NP=2 (K=256,N=2048,CO=128)
    int idx = (blk - PB6) * 256 + t;     // 524,288
    int j = idx & 7, lane = (idx >> 3) & 63;
    int f = idx >> 9;
    int ntg = f & 127;                   // NT=128
    int kt = f >> 7;                     // KT=8
    int k = kt * 32 + ((lane >> 4) << 3) + j;
    int n = ntg * 16 + (lane & 15);
    int o = n & 127, ru = n >> 7;
    int r = ru >> 2, u = ru & 3;
    int sf = (3 - r) * 4 + (3 - u);
    unsigned short hb, mb, lb;
    split3v(dec_w2[(((size_t)sf * 256 + k) << 7) + o], hb, mb, lb);
    Bp_d2[idx] = hb; Bp_d2[idx + 524288] = mb;
  }
}

// ---------------- conv1: x(256,64,64,1) -> h1p split padded (256,34,34,32) ----
__global__ __launch_bounds__(256) void k_conv1(const float* __restrict__ x,
                                               const float* __restrict__ w,
                                               const float* __restrict__ bias,
                                               unsigned short* __restrict__ oH,
                                               unsigned short* __restrict__ oM,
                                               unsigned short* __restrict__ oL) {
  int b = blockIdx.x >> 5;          // 8192 blocks: (b, y)
  int y = blockIdx.x & 31;
  int t = threadIdx.x;
  int c = t & 31;
  int xg = t >> 5;                  // 0..7, 4 x-positions each
  float acc[4] = {0.f, 0.f, 0.f, 0.f};
  for (int dy = 0; dy < 4; ++dy) {
    int iy = 2 * y + dy - 1;
    if (iy < 0 || iy >= 64) continue;
    const float* xrow = x + ((size_t)b * 64 + iy) * 64;
    for (int dx = 0; dx < 4; ++dx) {
      float wv = w[(dy * 4 + dx) * 32 + c];
#pragma unroll
      for (int i = 0; i < 4; ++i) {
        int ix = 8 * xg + 2 * i + dx - 1;
        float v = (ix >= 0 && ix < 64) ? xrow[ix] : 0.f;
        acc[i] = fmaf(v, wv, acc[i]);
      }
    }
  }
  float bv = bias[c];
#pragma unroll
  for (int i = 0; i < 4; ++i) {
    float v = acc[i] + bv;
    v = v > 0.f ? v : 0.f;
    unsigned short hb, mb, lb;
    split3v(v, hb, mb, lb);
    size_t o = ((size_t)(b * 34 + y + 1) * 34 + (4 * xg + i + 1)) * 32 + c;
    oH[o] = hb; oM[o] = mb; oL[o] = lb;
  }
}

// ---------------- conv2 MFMA (pipelined s-loop) ----------------
__global__ __launch_bounds__(256, 4) void k_conv2m(
    const unsigned short* __restrict__ aH, const unsigned short* __restrict__ aM,
    const unsigned short* __restrict__ aL, const unsigned short* __restrict__ wH,
    const unsigned short* __restrict__ wM, const unsigned short* __restrict__ wL,
    const float* __restrict__ bias, unsigned short* __restrict__ oH,
    unsigned short* __restrict__ oM, unsigned short* __restrict__ oL) {
  int t = threadIdx.x;
  int wave = t >> 6, lane = t & 63;
  int l15 = lane & 15, quad = lane >> 4;
  int m0 = blockIdx.x * 64 + wave * 16;     // 1024 blocks
  int p = m0 + l15;
  int b = p >> 8, y = (p >> 4) & 15, x = p & 15;
  f32x4 acc[4] = {};
#pragma unroll 4
  for (int s = 0; s < 16; ++s) {
    int dy = s >> 2, dx = s & 3;
    size_t aoff = ((size_t)(b * 34 + 2 * y + dy) * 34 + (2 * x + dx)) * 32 + quad * 8;
    bf16x8 ah = *(const bf16x8*)(aH + aoff);
    bf16x8 am = *(const bf16x8*)(aM + aoff);
    bf16x8 al = *(const bf16x8*)(aL + aoff);
#pragma unroll
    for (int nt = 0; nt < 4; ++nt) {
      size_t woff = ((size_t)(s * 4 + nt) * 64 + lane) * 8;
      bf16x8 bh = *(const bf16x8*)(wH + woff);
      bf16x8 bm = *(const bf16x8*)(wM + woff);
      bf16x8 bl = *(const bf16x8*)(wL + woff);
      acc[nt] = MFMA16(am, bm, acc[nt]);
      acc[nt] = MFMA16(ah, bl, acc[nt]);
      acc[nt] = MFMA16(al, bh, acc[nt]);
      acc[nt] = MFMA16(ah, bm, acc[nt]);
      acc[nt] = MFMA16(am, bh, acc[nt]);
      acc[nt] = MFMA16(ah, bh, acc[nt]);
    }
  }
#pragma unroll
  for (int r = 0; r < 4; ++r) {
    int pp = m0 + quad * 4 + r;
    int b2 = pp >> 8, yo = (pp >> 4) & 15, xo = pp & 15;
    size_t obase = ((size_t)(b2 * 18 + yo + 1) * 18 + (xo + 1)) * 64;
#pragma unroll
    for (int nt = 0; nt < 4; ++nt) {
      int co = nt * 16 + l15;
      float v = acc[nt][r] + bias[co];
      v = v > 0.f ? v : 0.f;
      unsigned short hb, mb, lb;
      split3v(v, hb, mb, lb);
      oH[obase + co] = hb; oM[obase + co] = mb; oL[obase + co] = lb;
    }
  }
}

// ---------------- conv3 MFMA -> fp32 partials [z][16384][128] ----------------
// grid (512, 2): 32 px x 128 co per block; wave = 16 px x 64 co; z = s-half.
__global__ __launch_bounds__(256, 4) void k_conv3m(
    const unsigned short* __restrict__ aH, const unsigned short* __restrict__ aM,
    const unsigned short* __restrict__ aL, const unsigned short* __restrict__ wH,
    const unsigned short* __restrict__ wM, const unsigned short* __restrict__ wL,
    float* __restrict__ part) {
  int t = threadIdx.x;
  int wave = t >> 6, lane = t & 63;
  int l15 = lane & 15, quad = lane >> 4;
  int mtg = wave & 1, ch = wave >> 1;
  int m0 = blockIdx.x * 32 + mtg * 16;
  int z = blockIdx.y;
  int p = m0 + l15;
  int b = p >> 6, y = (p >> 3) & 7, x = p & 7;
  f32x4 acc[4] = {};
#pragma unroll 2
  for (int si = 0; si < 8; ++si) {
    int s = z * 8 + si;
    int dy = s >> 2, dx = s & 3;
    size_t base = ((size_t)(b * 18 + 2 * y + dy) * 18 + (2 * x + dx)) * 64 + quad * 8;
    bf16x8 ah[2], am[2], al[2];
#pragma unroll
    for (int ks = 0; ks < 2; ++ks) {
      ah[ks] = *(const bf16x8*)(aH + base + ks * 32);
      am[ks] = *(const bf16x8*)(aM + base + ks * 32);
      al[ks] = *(const bf16x8*)(aL + base + ks * 32);
    }
#pragma unroll
    for (int nt = 0; nt < 4; ++nt) {
#pragma unroll
      for (int ks = 0; ks < 2; ++ks) {
        size_t woff = ((size_t)((((s * 2 + ch) * 4 + nt) * 2 + ks) * 64 + lane)) * 8;
        bf16x8 bh = *(const bf16x8*)(wH + woff);
        bf16x8 bm = *(const bf16x8*)(wM + woff);
        bf16x8 bl = *(const bf16x8*)(wL + woff);
        acc[nt] = MFMA16(am[ks], bm, acc[nt]);
        acc[nt] = MFMA16(ah[ks], bl, acc[nt]);
        acc[nt] = MFMA16(al[ks], bh, acc[nt]);
        acc[nt] = MFMA16(ah[ks], bm, acc[nt]);
        acc[nt] = MFMA16(am[ks], bh, acc[nt]);
        acc[nt] = MFMA16(ah[ks], bh, acc[nt]);
      }
    }
  }
  float* Cp = part + (size_t)z * 2097152;
#pragma unroll
  for (int nt = 0; nt < 4; ++nt) {
    int co = ch * 64 + nt * 16 + l15;
#pragma unroll
    for (int r = 0; r < 4; ++r) {
      int pp = m0 + quad * 4 + r;
      Cp[(size_t)pp * 128 + co] = acc[nt][r];
    }
  }
}

// ---------------- fused: sumrelu(conv3) + bprep fc (NP=3) ----------------
#define FB0 8192
#define FB1 (FB0 + 16384)
__global__ __launch_bounds__(256) void k_prep_fc(
    const float* __restrict__ part, const float* __restrict__ enc_b3,
    unsigned short* __restrict__ h3H, unsigned short* __restrict__ h3M,
    unsigned short* __restrict__ h3L, const float* __restrict__ fc_w,
    unsigned short* __restrict__ Bp_fc) {
  int blk = blockIdx.x;
  int t = threadIdx.x;
  if (blk < FB0) {                       // sumrelu conv3: MN=2097152, S=2
    int idx = blk * 256 + t;
    float s = part[idx] + part[2097152 + idx] + enc_b3[idx & 127];
    s = s > 0.f ? s : 0.f;
    unsigned short hb, mb, lb;
    split3v(s, hb, mb, lb);
    h3H[idx] = hb; h3M[idx] = mb; h3L[idx] = lb;
  } else {                               // bprep fc: K=8192, N=512 (KT=256,NT=32)
    int idx = (blk - FB0) * 256 + t;     // 4,194,304
    int j = idx & 7, lane = (idx >> 3) & 63;
    int f = idx >> 9;
    int ntg = f & 31;
    int kt = f >> 5;
    int k = kt * 32 + ((lane >> 4) << 3) + j;
    int n = ntg * 16 + (lane & 15);
    unsigned short hb, mb, lb;
    split3v(fc_w[(size_t)k * 512 + n], hb, mb, lb);
    Bp_fc[idx] = hb; Bp_fc[idx + 4194304] = mb; Bp_fc[idx + 8388608] = lb;
  }
}

// ---------------- fused: bprep ffc (NP=3) + bprep_ct dec_w1 (NP=2) ----------
#define WB0 4096
#define WB1 (WB0 + 8192)
__global__ __launch_bounds__(256) void k_prep_w2(
    const float* __restrict__ ffc_w, unsigned short* __restrict__ Bp_ffc,
    const float* __restrict__ dec_w1, unsigned short* __restrict__ Bp_d1) {
  int blk = blockIdx.x;
  int t = threadIdx.x;
  if (blk < WB0) {                       // ffc: K=512, N=2048 (KT=16, NT=128)
    int idx = blk * 256 + t;             // 1,048,576
    int j = idx & 7, lane = (idx >> 3) & 63;
    int f = idx >> 9;
    int ntg = f & 127;
    int kt = f >> 7;
    int k = kt * 32 + ((lane >> 4) << 3) + j;
    int n = ntg * 16 + (lane & 15);
    unsigned short hb, mb, lb;
    split3v(ffc_w[(size_t)k * 2048 + n], hb, mb, lb);
    Bp_ffc[idx] = hb; Bp_ffc[idx + 1048576] = mb; Bp_ffc[idx + 2097152] = lb;
  } else {                               // dec_w1 ct: K=512, N=4096, CO=256
    int idx = (blk - WB0) * 256 + t;     // 2,097,152
    int j = idx & 7, lane = (idx >> 3) & 63;
    int f = idx >> 9;
    int ntg = f & 255;                   // NT=256
    int kt = f >> 8;                     // KT=16
    int k = kt * 32 + ((lane >> 4) << 3) + j;
    int n = ntg * 16 + (lane & 15);
    int o = n & 255, ru = n >> 8;
    int r = ru >> 2, u = ru & 3;
    int sf = (3 - r) * 4 + (3 - u);
    unsigned short hb, mb, lb;
    split3v(dec_w1[(((size_t)sf * 512 + k) << 8) + o], hb, mb, lb);
    Bp_d1[idx] = hb; Bp_d1[idx + 2097152] = mb;
  }
}

// ---------------- generic split-bf16 MFMA GEMM ----------------
template <int NP, int NTW>
__global__ __launch_bounds__(256) void k_mgemm(
    const unsigned short* __restrict__ A0, const unsigned short* __restrict__ A1,
    const unsigned short* __restrict__ A2, const unsigned short* __restrict__ Bp,
    float* __restrict__ C, const float* __restrict__ bias,
    int M, int N, int K, int bmask) {
  int S = gridDim.z;
  int Kc = K / S;
  int t = threadIdx.x;
  int wave = t >> 6, lane = t & 63;
  int l15 = lane & 15, quad = lane >> 4;
  int m0 = blockIdx.x * 64 + wave * 16;
  int n0 = blockIdx.y * (16 * NTW);
  int KT = K >> 5, NT = N >> 4;
  int kt0 = (blockIdx.z * Kc) >> 5;
  int ktn = Kc >> 5;
  size_t sstride = (size_t)KT * NT * 512;
  const unsigned short* arow0 = A0 + (size_t)(m0 + l15) * K + quad * 8;
  const unsigned short* arow1 = A1 + (size_t)(m0 + l15) * K + quad * 8;
  const unsigned short* arow2 = nullptr;
  if constexpr (NP == 3) arow2 = A2 + (size_t)(m0 + l15) * K + quad * 8;
  f32x4 acc[NTW] = {};
  for (int kt = kt0; kt < kt0 + ktn; ++kt) {
    bf16x8 ah = *(const bf16x8*)(arow0 + kt * 32);
    bf16x8 am = *(const bf16x8*)(arow1 + kt * 32);
    bf16x8 al;
    if constexpr (NP == 3) al = *(const bf16x8*)(arow2 + kt * 32);
    const unsigned short* bbase =
        Bp + ((size_t)kt * NT + (n0 >> 4)) * 512 + lane * 8;
#pragma unroll
    for (int nt = 0; nt < NTW; ++nt) {
      const unsigned short* bp = bbase + nt * 512;
      bf16x8 bh = *(const bf16x8*)(bp);
      bf16x8 bm = *(const bf16x8*)(bp + sstride);
      if constexpr (NP == 3) {
        bf16x8 bl = *(const bf16x8*)(bp + 2 * sstride);
        acc[nt] = MFMA16(am, bm, acc[nt]);
        acc[nt] = MFMA16(ah, bl, acc[nt]);
        acc[nt] = MFMA16(al, bh, acc[nt]);
        acc[nt] = MFMA16(ah, bm, acc[nt]);
        acc[nt] = MFMA16(am, bh, acc[nt]);
        acc[nt] = MFMA16(ah, bh, acc[nt]);
      } else {
        acc[nt] = MFMA16(ah, bm, acc[nt]);
        acc[nt] = MFMA16(am, bh, acc[nt]);
        acc[nt] = MFMA16(ah, bh, acc[nt]);
      }
    }
  }
  if (S == 1) {
#pragma unroll
    for (int nt = 0; nt < NTW; ++nt) {
      int n = n0 + nt * 16 + l15;
      float bv = bias[n & bmask];
#pragma unroll
      for (int r = 0; r < 4; ++r) {
        int m = m0 + quad * 4 + r;
        float v = acc[nt][r] + bv;
        C[(size_t)m * N + n] = v > 0.f ? v : 0.f;
      }
    }
  } else {
    float* Cp = C + (size_t)blockIdx.z * M * N;
#pragma unroll
    for (int nt = 0; nt < NTW; ++nt) {
      int n = n0 + nt * 16 + l15;
#pragma unroll
      for (int r = 0; r < 4; ++r) {
        int m = m0 + quad * 4 + r;
        Cp[(size_t)m * N + n] = acc[nt][r];
      }
    }
  }
}

// sum k-split partials + bias + relu -> split planes
template <int NPOUT>
__global__ __launch_bounds__(256) void k_sumrelu3(
    const float* __restrict__ part, const float* __restrict__ bias,
    unsigned short* __restrict__ oH, unsigned short* __restrict__ oM,
    unsigned short* __restrict__ oL, int MN, int bmask, int S) {
  int idx = blockIdx.x * 256 + threadIdx.x;
  float s = 0.f;
  for (int z = 0; z < S; ++z) s += part[(size_t)z * MN + idx];
  s += bias[idx & bmask];
  s = s > 0.f ? s : 0.f;
  unsigned short hb = f2bf(s);
  float r1 = s - bf2f(hb);
  unsigned short mb = f2bf(r1);
  oH[idx] = hb; oM[idx] = mb;
  if constexpr (NPOUT == 3) oL[idx] = f2bf(r1 - bf2f(mb));
}

// ---------------- VQ ----------------
// k_vqmfma3: 32 m-rows per wave (2 A-sets), codes streamed as B-frags.
__global__ __launch_bounds__(256) void k_vqmfma3(
    const unsigned short* __restrict__ pH, const unsigned short* __restrict__ pM,
    const unsigned short* __restrict__ pL, const unsigned short* __restrict__ eB,
    const float* __restrict__ n2, float* __restrict__ pbd, int* __restrict__ pbk) {
  int t = threadIdx.x;
  int wave = t >> 6, lane = t & 63;
  int l15 = lane & 15, quad = lane >> 4;
  int m0 = blockIdx.x * 128 + wave * 32;
  int z = blockIdx.y;
  bf16x8 ah[2][2], am[2][2], al[2][2];   // [mt][ks]
#pragma unroll
  for (int mt = 0; mt < 2; ++mt) {
    size_t arow = (size_t)(m0 + mt * 16 + l15) * 64 + quad * 8;
#pragma unroll
    for (int ks = 0; ks < 2; ++ks) {
      ah[mt][ks] = *(const bf16x8*)(pH + arow + ks * 32);
      am[mt][ks] = *(const bf16x8*)(pM + arow + ks * 32);
      al[mt][ks] = *(const bf16x8*)(pL + arow + ks * 32);
    }
  }
  float bd[2][4]; int bk[2][4];
#pragma unroll
  for (int mt = 0; mt < 2; ++mt)
#pragma unroll
    for (int r = 0; r < 4; ++r) { bd[mt][r] = FLT_MAX; bk[mt][r] = 0; }
  for (int kt = z * 16; kt < z * 16 + 16; ++kt) {
    const unsigned short* bb = eB + (size_t)kt * 12288 + lane * 8;
    f32x4 acc[2][4] = {};
#pragma unroll
    for (int ks = 0; ks < 2; ++ks)
#pragma unroll
      for (int nt = 0; nt < 4; ++nt) {
        const unsigned short* bp = bb + ((ks * 4 + nt) * 3) * 512;
        bf16x8 bh = *(const bf16x8*)(bp);
        bf16x8 bm = *(const bf16x8*)(bp + 512);
        bf16x8 bl = *(const bf16x8*)(bp + 1024);
#pragma unroll
        for (int mt = 0; mt < 2; ++mt) {
          acc[mt][nt] = MFMA16(am[mt][ks], bm, acc[mt][nt]);
          acc[mt][nt] = MFMA16(ah[mt][ks], bl, acc[mt][nt]);
          acc[mt][nt] = MFMA16(al[mt][ks], bh, acc[mt][nt]);
          acc[mt][nt] = MFMA16(ah[mt][ks], bm, acc[mt][nt]);
          acc[mt][nt] = MFMA16(am[mt][ks], bh, acc[mt][nt]);
          acc[mt][nt] = MFMA16(ah[mt][ks], bh, acc[mt][nt]);
        }
      }
    int cb = kt * 64;
#pragma unroll
    for (int nt = 0; nt < 4; ++nt) {
      int code = cb + nt * 16 + l15;
      float nv = n2[code];
#pragma unroll
      for (int mt = 0; mt < 2; ++mt)
#pragma unroll
        for (int r = 0; r < 4; ++r) {
          float d = fmaf(-2.f, acc[mt][nt][r], nv);
          if (d < bd[mt][r]) { bd[mt][r] = d; bk[mt][r] = code; }
        }
    }
  }
#pragma unroll
  for (int mt = 0; mt < 2; ++mt)
#pragma unroll
    for (int r = 0; r < 4; ++r)
#pragma unroll
      for (int s = 1; s < 16; s <<= 1) {
        float od = __shfl_xor(bd[mt][r], s);
        int ok = __shfl_xor(bk[mt][r], s);
        if (od < bd[mt][r] || (od == bd[mt][r] && ok < bk[mt][r])) {
          bd[mt][r] = od; bk[mt][r] = ok;
        }
      }
  if (l15 == 0) {
#pragma unroll
    for (int mt = 0; mt < 2; ++mt)
#pragma unroll
      for (int r = 0; r < 4; ++r) {
        pbd[(size_t)z * 8192 + m0 + mt * 16 + quad * 4 + r] = bd[mt][r];
        pbk[(size_t)z * 8192 + m0 + mt * 16 + quad * 4 + r] = bk[mt][r];
      }
  }
}

// fused: reduce 8 z-groups per row (lex (d,k)) + gather -> 2-plane collected.
__global__ __launch_bounds__(256) void k_vqgather(const float* __restrict__ pbd,
                                                  const int* __restrict__ pbk,
                                                  const float* __restrict__ embeds,
                                                  unsigned short* __restrict__ cH,
                                                  unsigned short* __restrict__ cM) {
  int idx = blockIdx.x * 256 + threadIdx.x;   // 524288, 2048 blocks
  int m = idx >> 6;
  float bd = pbd[m]; int bk = pbk[m];
#pragma unroll
  for (int z = 1; z < 8; ++z) {
    float d = pbd[(size_t)z * 8192 + m]; int k = pbk[(size_t)z * 8192 + m];
    if (d < bd || (d == bd && k < bk)) { bd = d; bk = k; }
  }
  float v = embeds[(size_t)bk * 64 + (idx & 63)];
  unsigned short hb = f2bf(v);
  cH[idx] = hb;
  cM[idx] = f2bf(v - bf2f(hb));
}

// ---------------- dec3: d2buf(permuted) -> out(256,64,64), +bias, no relu ----
__global__ __launch_bounds__(256) void k_dec3(const float* __restrict__ d2buf,
                                              const float* __restrict__ w3,
                                              const float* __restrict__ b3,
                                              float* __restrict__ out) {
  __shared__ float sx[16 * 129];
  __shared__ float wT[128 * 16];
  int b = blockIdx.x >> 4;          // 4096 blocks: (b, y_in)
  int y = blockIdx.x & 15;
  int t = threadIdx.x;
#pragma unroll
  for (int j = 0; j < 8; ++j) {
    int idx = t + j * 256;          // 2048
    int xx = idx >> 7, c = idx & 127;
    size_t m2 = ((size_t)b * 4 + (y >> 2)) * 4 + (xx >> 2);
    sx[xx * 129 + c] = d2buf[m2 * 2048 + ((y & 3) * 4 + (xx & 3)) * 128 + c];
  }
#pragma unroll
  for (int j = 0; j < 8; ++j) {
    int idx = t + j * 256;
    int c = idx >> 4, ru = idx & 15;
    int R = ru >> 2, U = ru & 3;
    wT[c * 16 + ru] = w3[((3 - R) * 4 + (3 - U)) * 128 + c];
  }
  __syncthreads();
  int xx = t >> 4, ru = t & 15;
  float a0 = 0, a1 = 0, a2 = 0, a3 = 0;
#pragma unroll 8
  for (int c = 0; c < 128; c += 4) {
    a0 = fmaf(sx[xx * 129 + c + 0], wT[(c + 0) * 16 + ru], a0);
    a1 = fmaf(sx[xx * 129 + c + 1], wT[(c + 1) * 16 + ru], a1);
    a2 = fmaf(sx[xx * 129 + c + 2], wT[(c + 2) * 16 + ru], a2);
    a3 = fmaf(sx[xx * 129 + c + 3], wT[(c + 3) * 16 + ru], a3);
  }
  float acc = (a0 + a1) + (a2 + a3) + b3[0];
  int R = ru >> 2, U = ru & 3;
  out[((size_t)b * 64 + 4 * y + R) * 64 + 4 * xx + U] = acc;
}

// =====================================================================
extern "C" void kernel_launch(void* const* d_in, const int* in_sizes, int n_in,
                              void* d_out, int out_size, void* d_ws, size_t ws_size,
                              hipStream_t stream) {
  const float* x        = (const float*)d_in[0];
  const float* enc_w1   = (const float*)d_in[1];
  const float* enc_b1   = (const float*)d_in[2];
  const float* enc_w2   = (const float*)d_in[3];
  const float* enc_b2   = (const float*)d_in[4];
  const float* enc_w3   = (const float*)d_in[5];
  const float* enc_b3   = (const float*)d_in[6];
  const float* fc_w     = (const float*)d_in[7];
  const float* fc_b     = (const float*)d_in[8];
  const float* ffc_w    = (const float*)d_in[9];
  const float* ffc_b    = (const float*)d_in[10];
  const float* embeds   = (const float*)d_in[11];
  const float* dec_fc_w = (const float*)d_in[12];
  const float* dec_fc_b = (const float*)d_in[13];
  const float* dec_w1   = (const float*)d_in[14];
  const float* dec_b1   = (const float*)d_in[15];
  const float* dec_w2   = (const float*)d_in[16];
  const float* dec_b2   = (const float*)d_in[17];
  const float* dec_w3   = (const float*)d_in[18];
  const float* dec_b3   = (const float*)d_in[19];
  float* outp = (float*)d_out;

  char* ws = (char*)d_ws;
  size_t off = 0;
  auto alloc = [&](size_t bytes) { size_t r = off; off = (off + bytes + 255) & ~(size_t)255; return r; };

  // ---- Region A (57.15 MB): phase1 h1p splits; phase2 decoder/partials ----
  size_t RA = alloc(57147392);
  unsigned short* h1pH = (unsigned short*)(ws + RA);
  unsigned short* h1pM = (unsigned short*)(ws + RA + 18939904);
  unsigned short* h1pL = (unsigned short*)(ws + RA + 37879808);
  float* d2buf            = (float*)(ws + RA);                    // 33.55 MB
  float* partials         = (float*)(ws + RA + 33554432);         // <=16.78 MB
  unsigned short* Bp_d1   = (unsigned short*)(ws + RA + 41943040);// 8.39 MB
  unsigned short* d1H     = (unsigned short*)(ws + RA + 50331648);
  unsigned short* d1M     = (unsigned short*)(ws + RA + 52428800);
  unsigned short* hdH     = (unsigned short*)(ws + RA + 54525952);
  unsigned short* hdM     = (unsigned short*)(ws + RA + 54788096);
  unsigned short* cH      = (unsigned short*)(ws + RA + 55050240);
  unsigned short* cM      = (unsigned short*)(ws + RA + 56098816);

  // ---- Region B (31.85 MB): phase1 h2p splits; phase2 Bp_fc/pred ----
  size_t RB = alloc(31850496);
  unsigned short* h2pH = (unsigned short*)(ws + RB);
  unsigned short* h2pM = (unsigned short*)(ws + RB + 10616832);
  unsigned short* h2pL = (unsigned short*)(ws + RB + 21233664);
  unsigned short* Bp_fc = (unsigned short*)(ws + RB);             // 25.17 MB
  unsigned short* pH    = (unsigned short*)(ws + RB + 28311552);
  unsigned short* pM    = (unsigned short*)(ws + RB + 29360128);
  unsigned short* pL    = (unsigned short*)(ws + RB + 30408704);

  // ---- Region C (12.58 MB): phase1 h3 splits; phase2 Bp_ffc/hfc ----
  size_t RC = alloc(12582912);
  unsigned short* h3H = (unsigned short*)(ws + RC);
  unsigned short* h3M = (unsigned short*)(ws + RC + 4194304);
  unsigned short* h3L = (unsigned short*)(ws + RC + 8388608);
  unsigned short* Bp_ffc = (unsigned short*)(ws + RC);            // 6.29 MB (after fc)
  unsigned short* hfcH   = (unsigned short*)(ws + RC + 6291456);
  unsigned short* hfcM   = (unsigned short*)(ws + RC + 6553600);
  unsigned short* hfcL   = (unsigned short*)(ws + RC + 6815744);

  // ---- dedicated (lifetime spans whole run) ----
  unsigned short* eB     = (unsigned short*)(ws + alloc(3145728));
  unsigned short* Bp_dfc = (unsigned short*)(ws + alloc(4194304));
  unsigned short* Bp_d2  = (unsigned short*)(ws + alloc(2097152));
  float* n2buf   = (float*)(ws + alloc(32768));
  float* pbd     = (float*)(ws + alloc(262144));
  int*   pbk     = (int*)  (ws + alloc(262144));
  unsigned short* Wp2H = (unsigned short*)(ws + alloc(196608));
  unsigned short* Wp2M = Wp2H + 32768;
  unsigned short* Wp2L = Wp2M + 32768;
  unsigned short* Wp3H = (unsigned short*)(ws + alloc(786432));
  unsigned short* Wp3M = Wp3H + 131072;
  unsigned short* Wp3L = Wp3M + 131072;
  (void)ws_size; (void)in_sizes; (void)n_in; (void)out_size;

  // all input-only prep in one launch
  k_prep_early<<<PB7, 256, 0, stream>>>(
      enc_w2, enc_w3, embeds, dec_fc_w, dec_w2, h1pH, h2pH,
      Wp2H, Wp2M, Wp2L, Wp3H, Wp3M, Wp3L, eB, n2buf, Bp_dfc, Bp_d2);

  k_conv1<<<8192, 256, 0, stream>>>(x, enc_w1, enc_b1, h1pH, h1pM, h1pL);
  k_conv2m<<<1024, 256, 0, stream>>>(h1pH, h1pM, h1pL, Wp2H, Wp2M, Wp2L,
                                     enc_b2, h2pH, h2pM, h2pL);
  k_conv3m<<<dim3(512, 2), 256, 0, stream>>>(h2pH, h2pM, h2pL,
                                             Wp3H, Wp3M, Wp3L, partials);
  // sumrelu(conv3) + bprep fc in one launch
  k_prep_fc<<<FB1, 256, 0, stream>>>(partials, enc_b3, h3H, h3M, h3L,
                                     fc_w, Bp_fc);

  // fc: (256x512) = h3(256x8192) @ fc_w, NP=3, S=16
  k_mgemm<3, 4><<<dim3(4, 8, 16), 256, 0, stream>>>(
      h3H, h3M, h3L, Bp_fc, partials, fc_b, 256, 512, 8192, 511);
  // bprep ffc + bprep_ct dec_w1 in one launch
  k_prep_w2<<<WB1, 256, 0, stream>>>(ffc_w, Bp_ffc, dec_w1, Bp_d1);
  k_sumrelu3<3><<<512, 256, 0, stream>>>(partials, fc_b, hfcH, hfcM, hfcL,
                                         131072, 511, 16);
  // ffc: (256x2048), NP=3, S=4 -> pred splits
  k_mgemm<3, 4><<<dim3(4, 32, 4), 256, 0, stream>>>(
      hfcH, hfcM, hfcL, Bp_ffc, partials, ffc_b, 256, 2048, 512, 2047);
  k_sumrelu3<3><<<2048, 256, 0, stream>>>(partials, ffc_b, pH, pM, pL,
                                          524288, 2047, 4);

  // VQ
  k_vqmfma3<<<dim3(64, 8), 256, 0, stream>>>(pH, pM, pL, eB, n2buf, pbd, pbk);
  k_vqgather<<<2048, 256, 0, stream>>>(pbd, pbk, embeds, cH, cM);

  // dec_fc: (256x512), NP=2, S=16
  k_mgemm<2, 4><<<dim3(4, 8, 16), 256, 0, stream>>>(
      cH, cM, nullptr, Bp_dfc, partials, dec_fc_b, 256, 512, 2048, 511);
  k_sumrelu3<2><<<512, 256, 0, stream>>>(partials, dec_fc_b, hdH, hdM, nullptr,
                                         131072, 511, 16);

  // dec1: (256x4096), NP=2, S=2
  k_mgemm<2, 4><<<dim3(4, 64, 2), 256, 0, stream>>>(
      hdH, hdM, nullptr, Bp_d1, partials, dec_b1, 256, 4096, 512, 255);
  k_sumrelu3<2><<<4096, 256, 0, stream>>>(partials, dec_b1, d1H, d1M, nullptr,
                                          1048576, 255, 2);

  // dec2: (4096x2048), NP=2, S=1 -> fp32 d2buf (+bias+relu)
  k_mgemm<2, 8><<<dim3(64, 16, 1), 256, 0, stream>>>(
      d1H, d1M, nullptr, Bp_d2, d2buf, dec_b2, 4096, 2048, 256, 127);

  // dec3 -> final output (no relu)
  k_dec3<<<4096, 256, 0, stream>>>(d2buf, dec_w3, dec_b3, outp);
}